// Round 1
// baseline (1960.509 us; speedup 1.0000x reference)
//
#include <hip/hip_runtime.h>
#include <hip/hip_bf16.h>
#include <math.h>

// Problem constants (B=8, N=1024, D=256, L=4, M=1024, H=8, dh=32, K=64 clusters)
#define BN 8192           // B*N rows
#define DMODEL 256
#define FFN 1024
#define NCLUST 64

typedef unsigned short u16;
typedef unsigned int u32;
typedef __attribute__((ext_vector_type(8))) short s16x8;      // 8 bf16 (4 VGPRs) MFMA frag
typedef __attribute__((ext_vector_type(8))) unsigned short u16x8;
typedef __attribute__((ext_vector_type(4))) unsigned short u16x4;
typedef __attribute__((ext_vector_type(4))) float f32x4;

__device__ __forceinline__ float bf2f(u16 v) {
    union { unsigned int u; float f; } w; w.u = ((unsigned int)v) << 16; return w.f;
}
__device__ __forceinline__ u16 f2bf(float f) {
    union { float f; unsigned int u; } w; w.f = f;
    unsigned int r = w.u + 0x7fffu + ((w.u >> 16) & 1u);
    return (u16)(r >> 16);
}

// ---------------- LayerNorm: one wave per row, float4 + shuffle reduce; now emits bf16 h/l ----------------
__global__ __launch_bounds__(256) void ln_wave(const float* __restrict__ x, const float* __restrict__ g,
                                               const float* __restrict__ b, u16* __restrict__ yh,
                                               u16* __restrict__ yl) {
    int t = threadIdx.x, w = t >> 6, l = t & 63;
    int row = blockIdx.x * 4 + w;
    const float* xr = x + (size_t)row * DMODEL;
    float4 v = *reinterpret_cast<const float4*>(xr + l * 4);
    float s = v.x + v.y + v.z + v.w;
    for (int off = 1; off < 64; off <<= 1) s += __shfl_xor(s, off);
    float mean = s * (1.0f / 256.0f);
    float4 dv = make_float4(v.x - mean, v.y - mean, v.z - mean, v.w - mean);
    float vs = dv.x * dv.x + dv.y * dv.y + dv.z * dv.z + dv.w * dv.w;
    for (int off = 1; off < 64; off <<= 1) vs += __shfl_xor(vs, off);
    float rs = rsqrtf(vs * (1.0f / 256.0f) + 1e-5f);
    float4 gg = *reinterpret_cast<const float4*>(g + l * 4);
    float4 bb = *reinterpret_cast<const float4*>(b + l * 4);
    float os[4] = {dv.x * rs * gg.x + bb.x, dv.y * rs * gg.y + bb.y,
                   dv.z * rs * gg.z + bb.z, dv.w * rs * gg.w + bb.w};
    u16x4 hv, lv;
#pragma unroll
    for (int j = 0; j < 4; j++) { u16 hh = f2bf(os[j]); hv[j] = hh; lv[j] = f2bf(os[j] - bf2f(hh)); }
    size_t o = (size_t)row * DMODEL + l * 4;
    *reinterpret_cast<u16x4*>(yh + o) = hv;
    *reinterpret_cast<u16x4*>(yl + o) = lv;
}

// ---------------- Weight convert v2: LDS tile transpose, coalesced both sides ----------------
// W[K][N] fp32 -> th[n][k], tl[n][k] bf16 (bit-identical to r12 wconv output).
__global__ __launch_bounds__(256) void wconv2(const float* __restrict__ W, u16* __restrict__ th,
                                              u16* __restrict__ tl, int K, int N) {
    __shared__ float T[64][65];
    int k0 = blockIdx.y * 64, n0 = blockIdx.x * 64;
    int t = threadIdx.x;
    int r = t >> 4, c4 = (t & 15) * 4;
#pragma unroll
    for (int i = 0; i < 4; i++) {
        float4 x = *reinterpret_cast<const float4*>(W + (size_t)(k0 + r + 16 * i) * N + n0 + c4);
        T[r + 16 * i][c4] = x.x; T[r + 16 * i][c4 + 1] = x.y;
        T[r + 16 * i][c4 + 2] = x.z; T[r + 16 * i][c4 + 3] = x.w;
    }
    __syncthreads();
#pragma unroll
    for (int i = 0; i < 4; i++) {
        int n = r + 16 * i;
        u16x4 h4, l4;
#pragma unroll
        for (int j = 0; j < 4; j++) {
            float v = T[c4 + j][n];
            u16 h = f2bf(v);
            h4[j] = h; l4[j] = f2bf(v - bf2f(h));
        }
        *reinterpret_cast<u16x4*>(th + (size_t)(n0 + n) * K + k0 + c4) = h4;
        *reinterpret_cast<u16x4*>(tl + (size_t)(n0 + n) * K + k0 + c4) = l4;
    }
}

// ---------------- MFMA GEMM (bf16x2), A pre-split to h/l u16 -> staging is pure copies ----------------
// Epilogue: optional bias/gelu/resid; writes fp32 Cf and/or bf16x2 (Ch,Cl).
__global__ __launch_bounds__(256) void gemm_bx(const u16* __restrict__ Ath, const u16* __restrict__ Atl,
                                               const u16* __restrict__ Bth, const u16* __restrict__ Btl,
                                               const float* __restrict__ bias, const float* __restrict__ resid,
                                               float* __restrict__ Cf, u16* __restrict__ Ch, u16* __restrict__ Cl,
                                               int M, int N, int K, int fuse_gelu) {
    __shared__ u16 Ah[128][56], Al[128][56];
    __shared__ u16 Bh[64][56],  Bl[64][56];
    int t = threadIdx.x;
    int m0 = blockIdx.y * 128, n0 = blockIdx.x * 64;
    int L = t & 63, w = t >> 6, fr = L & 15, quad = L >> 4;
    int sm = t >> 1, skh = (t & 1) * 16;
    int sn = t >> 2, skq = (t & 3) * 8;
    f32x4 acc[2][4];
#pragma unroll
    for (int i = 0; i < 2; i++)
#pragma unroll
        for (int j = 0; j < 4; j++) acc[i][j] = (f32x4){0.0f, 0.0f, 0.0f, 0.0f};

    for (int k0 = 0; k0 < K; k0 += 32) {
        __syncthreads();
        {   // A stage: 128x32 h+l, pure u16x8 copies (no conversion)
            size_t ga = (size_t)(m0 + sm) * K + k0 + skh;
            u16x8 h0 = *reinterpret_cast<const u16x8*>(Ath + ga);
            u16x8 h1 = *reinterpret_cast<const u16x8*>(Ath + ga + 8);
            u16x8 l0 = *reinterpret_cast<const u16x8*>(Atl + ga);
            u16x8 l1 = *reinterpret_cast<const u16x8*>(Atl + ga + 8);
            *reinterpret_cast<u16x8*>(&Ah[sm][skh])     = h0;
            *reinterpret_cast<u16x8*>(&Ah[sm][skh + 8]) = h1;
            *reinterpret_cast<u16x8*>(&Al[sm][skh])     = l0;
            *reinterpret_cast<u16x8*>(&Al[sm][skh + 8]) = l1;
        }
        {
            size_t go = (size_t)(n0 + sn) * K + k0 + skq;
            *reinterpret_cast<u16x8*>(&Bh[sn][skq]) = *reinterpret_cast<const u16x8*>(Bth + go);
            *reinterpret_cast<u16x8*>(&Bl[sn][skq]) = *reinterpret_cast<const u16x8*>(Btl + go);
        }
        __syncthreads();
        s16x8 ah[2], al[2];
#pragma unroll
        for (int mi = 0; mi < 2; mi++) {
            int row = w * 32 + mi * 16 + fr;
            ah[mi] = *reinterpret_cast<s16x8*>(&Ah[row][quad * 8]);
            al[mi] = *reinterpret_cast<s16x8*>(&Al[row][quad * 8]);
        }
#pragma unroll
        for (int ni = 0; ni < 4; ni++) {
            int rn = ni * 16 + fr;
            s16x8 bhf = *reinterpret_cast<s16x8*>(&Bh[rn][quad * 8]);
            s16x8 blf = *reinterpret_cast<s16x8*>(&Bl[rn][quad * 8]);
#pragma unroll
            for (int mi = 0; mi < 2; mi++) {
                acc[mi][ni] = __builtin_amdgcn_mfma_f32_16x16x32_bf16(ah[mi], bhf, acc[mi][ni], 0, 0, 0);
                acc[mi][ni] = __builtin_amdgcn_mfma_f32_16x16x32_bf16(ah[mi], blf, acc[mi][ni], 0, 0, 0);
                acc[mi][ni] = __builtin_amdgcn_mfma_f32_16x16x32_bf16(al[mi], bhf, acc[mi][ni], 0, 0, 0);
            }
        }
    }
#pragma unroll
    for (int mi = 0; mi < 2; mi++) {
#pragma unroll
        for (int ni = 0; ni < 4; ni++) {
#pragma unroll
            for (int r = 0; r < 4; r++) {
                int row = m0 + w * 32 + mi * 16 + quad * 4 + r;
                int col = n0 + ni * 16 + fr;
                float v = acc[mi][ni][r];
                if (bias) v += bias[col];
                if (fuse_gelu) v = 0.5f * v * (1.0f + erff(v * 0.70710678118654752f));
                if (resid) v += resid[(size_t)row * N + col];
                size_t o = (size_t)row * N + col;
                if (Cf) Cf[o] = v;
                if (Ch) { u16 hh = f2bf(v); Ch[o] = hh; Cl[o] = f2bf(v - bf2f(hh)); }
            }
        }
    }
}

// ---------------- Attention v7: MFMA flash, Q/K/V pre-split h/l (staging = pure copies) ----------------
// Fragment layouts identical to proven gemm (A rows / B^T rows / D col=lane&15,row=quad*4+r).
// P: D-layout -> wave-private LDS -> A-layout (same-wave LDS ordering, proven r9).
// Output written directly as bf16 h/l for the Wo GEMM (same split formula -> bit-identical).
__global__ __launch_bounds__(256) void attn7(const u16* __restrict__ qh, const u16* __restrict__ ql,
                                             const u16* __restrict__ kvh, const u16* __restrict__ kvl,
                                             u16* __restrict__ aoh, u16* __restrict__ aol) {
    int bh = blockIdx.x, b = bh >> 3, h = bh & 7;
    int qt = blockIdx.y;
    int t = threadIdx.x, L = t & 63, w = t >> 6;
    int fr = L & 15, quad = L >> 4;
    __shared__ u16 QH[64][40], QL[64][40];   // stride 40: b128 16B-aligned, 2-way banks
    __shared__ u16 KH[64][40], KL[64][40];
    __shared__ u16 VTH[32][72], VTL[32][72]; // V^T[d][kc], stride 72
    __shared__ u16 PH[4][16][72], PL[4][16][72];  // per-wave P tile
    const float scale = 0.17677669529663687f;  // 1/sqrt(32)

    {   // stage Q 64x32: thread -> row t>>2, dims (t&3)*8..+7 (u16x8 copies)
        int qr = t >> 2, d0 = (t & 3) * 8;
        size_t gq = (size_t)(b * 1024 + qt * 64 + qr) * DMODEL + h * 32 + d0;
        *reinterpret_cast<u16x8*>(&QH[qr][d0]) = *reinterpret_cast<const u16x8*>(qh + gq);
        *reinterpret_cast<u16x8*>(&QL[qr][d0]) = *reinterpret_cast<const u16x8*>(ql + gq);
    }
    __syncthreads();
    s16x8 aqh = *reinterpret_cast<s16x8*>(&QH[w * 16 + fr][quad * 8]);  // wave-row A-frags, hoisted
    s16x8 aql = *reinterpret_cast<s16x8*>(&QL[w * 16 + fr][quad * 8]);

    float m_i[4], l_i[4];
    f32x4 acc_o[2];
#pragma unroll
    for (int r = 0; r < 4; r++) { m_i[r] = -1e30f; l_i[r] = 0.0f; }
    acc_o[0] = (f32x4){0.0f, 0.0f, 0.0f, 0.0f};
    acc_o[1] = (f32x4){0.0f, 0.0f, 0.0f, 0.0f};

    for (int kt = 0; kt < 16; kt++) {
        __syncthreads();   // protect K/VT from prior-iteration readers
        {   // stage K rows: row t>>2, dims (t&3)*8..+7 (u16x8 copies)
            int kr = t >> 2, d0 = (t & 3) * 8;
            size_t gk = (size_t)(b * 1024 + kt * 64 + kr) * 512 + h * 32 + d0;
            *reinterpret_cast<u16x8*>(&KH[kr][d0]) = *reinterpret_cast<const u16x8*>(kvh + gk);
            *reinterpret_cast<u16x8*>(&KL[kr][d0]) = *reinterpret_cast<const u16x8*>(kvl + gk);
        }
        {   // stage V transposed: thread -> kc pair 2p,2p+1, dims (t&7)*4..+3 (pack-only, no f2bf)
            int vp = t >> 3, vd0 = (t & 7) * 4;
            size_t g0 = (size_t)(b * 1024 + kt * 64 + 2 * vp) * 512 + 256 + h * 32 + vd0;
            u16x4 h0 = *reinterpret_cast<const u16x4*>(kvh + g0);
            u16x4 h1 = *reinterpret_cast<const u16x4*>(kvh + g0 + 512);
            u16x4 l0 = *reinterpret_cast<const u16x4*>(kvl + g0);
            u16x4 l1 = *reinterpret_cast<const u16x4*>(kvl + g0 + 512);
#pragma unroll
            for (int i = 0; i < 4; i++) {
                int d = vd0 + i;
                *reinterpret_cast<u32*>(&VTH[d][2 * vp]) = (u32)h0[i] | ((u32)h1[i] << 16);
                *reinterpret_cast<u32*>(&VTL[d][2 * vp]) = (u32)l0[i] | ((u32)l1[i] << 16);
            }
        }
        __syncthreads();
        // S = Q K^T : 4 n-subtiles, bf16x2 (3 MFMA each)
        f32x4 s[4];
#pragma unroll
        for (int ni = 0; ni < 4; ni++) {
            s16x8 bkh = *reinterpret_cast<s16x8*>(&KH[ni * 16 + fr][quad * 8]);
            s16x8 bkl = *reinterpret_cast<s16x8*>(&KL[ni * 16 + fr][quad * 8]);
            f32x4 c = (f32x4){0.0f, 0.0f, 0.0f, 0.0f};
            c = __builtin_amdgcn_mfma_f32_16x16x32_bf16(aqh, bkh, c, 0, 0, 0);
            c = __builtin_amdgcn_mfma_f32_16x16x32_bf16(aqh, bkl, c, 0, 0, 0);
            c = __builtin_amdgcn_mfma_f32_16x16x32_bf16(aql, bkh, c, 0, 0, 0);
            s[ni] = c;
        }
        // online softmax: lane owns rows quad*4+r, cols ni*16+fr; row spans 16 lanes (same quad)
        float alpha[4];
#pragma unroll
        for (int r = 0; r < 4; r++) {
            float s0 = s[0][r] * scale, s1 = s[1][r] * scale;
            float s2 = s[2][r] * scale, s3 = s[3][r] * scale;
            float ml = fmaxf(fmaxf(s0, s1), fmaxf(s2, s3));
            for (int off = 1; off < 16; off <<= 1) ml = fmaxf(ml, __shfl_xor(ml, off));
            float mnew = fmaxf(m_i[r], ml);
            alpha[r] = __expf(m_i[r] - mnew);
            m_i[r] = mnew;
            float p0 = __expf(s0 - mnew), p1 = __expf(s1 - mnew);
            float p2 = __expf(s2 - mnew), p3 = __expf(s3 - mnew);
            float rs = p0 + p1 + p2 + p3;
            for (int off = 1; off < 16; off <<= 1) rs += __shfl_xor(rs, off);
            l_i[r] = l_i[r] * alpha[r] + rs;
            int row = quad * 4 + r;
            float ps[4] = {p0, p1, p2, p3};
#pragma unroll
            for (int ni = 0; ni < 4; ni++) {
                u16 ph = f2bf(ps[ni]);
                PH[w][row][ni * 16 + fr] = ph;
                PL[w][row][ni * 16 + fr] = f2bf(ps[ni] - bf2f(ph));
            }
        }
        acc_o[0][0] *= alpha[0]; acc_o[0][1] *= alpha[1]; acc_o[0][2] *= alpha[2]; acc_o[0][3] *= alpha[3];
        acc_o[1][0] *= alpha[0]; acc_o[1][1] *= alpha[1]; acc_o[1][2] *= alpha[2]; acc_o[1][3] *= alpha[3];
        // PV: O += P V ; P wave-private (same-wave LDS write->read ordering)
#pragma unroll
        for (int ks = 0; ks < 2; ks++) {
            s16x8 aph = *reinterpret_cast<s16x8*>(&PH[w][fr][ks * 32 + quad * 8]);
            s16x8 apl = *reinterpret_cast<s16x8*>(&PL[w][fr][ks * 32 + quad * 8]);
#pragma unroll
            for (int ns = 0; ns < 2; ns++) {
                s16x8 bvh = *reinterpret_cast<s16x8*>(&VTH[ns * 16 + fr][ks * 32 + quad * 8]);
                s16x8 bvl = *reinterpret_cast<s16x8*>(&VTL[ns * 16 + fr][ks * 32 + quad * 8]);
                acc_o[ns] = __builtin_amdgcn_mfma_f32_16x16x32_bf16(aph, bvh, acc_o[ns], 0, 0, 0);
                acc_o[ns] = __builtin_amdgcn_mfma_f32_16x16x32_bf16(aph, bvl, acc_o[ns], 0, 0, 0);
                acc_o[ns] = __builtin_amdgcn_mfma_f32_16x16x32_bf16(apl, bvh, acc_o[ns], 0, 0, 0);
            }
        }
    }
    // write O as bf16 h/l: row = quad*4+r of wave tile, col = ns*16+fr (same split as old Wo-gemm stage)
#pragma unroll
    for (int r = 0; r < 4; r++) {
        float invl = 1.0f / l_i[r];
        size_t rowbase = ((size_t)(b * 1024 + qt * 64 + w * 16 + quad * 4 + r)) * DMODEL + h * 32;
        float v0 = acc_o[0][r] * invl, v1 = acc_o[1][r] * invl;
        u16 h0 = f2bf(v0); aoh[rowbase + fr] = h0;      aol[rowbase + fr] = f2bf(v0 - bf2f(h0));
        u16 h1 = f2bf(v1); aoh[rowbase + 16 + fr] = h1; aol[rowbase + 16 + fr] = f2bf(v1 - bf2f(h1));
    }
}

// ---------------- K-means v2 (proven r10/r11) ----------------
__global__ __launch_bounds__(256) void km_zero0(float* __restrict__ sums, float* __restrict__ counts) {
    int i = blockIdx.x * 256 + threadIdx.x;
    if (i < NCLUST * DMODEL) sums[i] = 0.0f;
    if (i < NCLUST) counts[i] = 0.0f;
}

__global__ __launch_bounds__(64) void csq_k(const float* __restrict__ centers, float* __restrict__ csq) {
    int j = blockIdx.x, l = threadIdx.x;
    float4 c4 = *reinterpret_cast<const float4*>(centers + j * DMODEL + l * 4);
    float s = c4.x * c4.x + c4.y * c4.y + c4.z * c4.z + c4.w * c4.w;
    for (int off = 1; off < 64; off <<= 1) s += __shfl_xor(s, off);
    if (l == 0) csq[j] = s;
}

__global__ __launch_bounds__(256) void km_dist(const float* __restrict__ A, const float* __restrict__ Cn,
                                               float* __restrict__ dot) {
    __shared__ float As[16][68];
    __shared__ float Bs[16][64];
    int t = threadIdx.x, tx = t & 15, ty = t >> 4;
    int m0 = blockIdx.x * 64;
    int mr = t >> 2, kq = (t & 3) * 4;
    int jb = t & 63, kb = (t >> 6) * 4;
    float acc[4][4] = {};
    for (int k0 = 0; k0 < 256; k0 += 16) {
        __syncthreads();
        {
            float4 a4 = *reinterpret_cast<const float4*>(A + (size_t)(m0 + mr) * DMODEL + k0 + kq);
            As[kq][mr] = a4.x; As[kq + 1][mr] = a4.y; As[kq + 2][mr] = a4.z; As[kq + 3][mr] = a4.w;
        }
        {
            float4 c4 = *reinterpret_cast<const float4*>(Cn + (size_t)jb * DMODEL + k0 + kb);
            Bs[kb][jb] = c4.x; Bs[kb + 1][jb] = c4.y; Bs[kb + 2][jb] = c4.z; Bs[kb + 3][jb] = c4.w;
        }
        __syncthreads();
#pragma unroll
        for (int kk = 0; kk < 16; kk++) {
            float4 a4 = *reinterpret_cast<float4*>(&As[kk][ty * 4]);
            float4 b4 = *reinterpret_cast<float4*>(&Bs[kk][tx * 4]);
            float a[4] = {a4.x, a4.y, a4.z, a4.w};
            float bf[4] = {b4.x, b4.y, b4.z, b4.w};
#pragma unroll
            for (int i = 0; i < 4; i++)
#pragma unroll
                for (int j = 0; j < 4; j++) acc[i][j] += a[i] * bf[j];
        }
    }
#pragma unroll
    for (int i = 0; i < 4; i++)
#pragma unroll
        for (int j = 0; j < 4; j++)
            dot[(size_t)(m0 + ty * 4 + i) * NCLUST + tx * 4 + j] = acc[i][j];
}

__global__ __launch_bounds__(256) void km_argmin_segsum(const float* __restrict__ dot, const float* __restrict__ csq,
                                                        const float* __restrict__ xf, int* __restrict__ labels,
                                                        float* __restrict__ counts, float* __restrict__ sums,
                                                        int do_seg) {
    __shared__ float lsum[NCLUST][DMODEL];
    __shared__ int lab_s[128];
    int t = threadIdx.x, w = t >> 6, l = t & 63;
    int base = blockIdx.x * 128;
    float cs = csq[l];
    for (int p = 0; p < 32; p++) {
        int i = base + w * 32 + p;
        float val = cs - 2.0f * dot[(size_t)i * NCLUST + l];
        float best = val; int bi = l;
        for (int off = 1; off < 64; off <<= 1) {
            float ov = __shfl_xor(best, off);
            int oi = __shfl_xor(bi, off);
            if (ov < best || (ov == best && oi < bi)) { best = ov; bi = oi; }
        }
        if (l == 0) {
            labels[i] = bi;
            lab_s[w * 32 + p] = bi;
            if (do_seg) atomicAdd(&counts[bi], 1.0f);
        }
    }
    if (!do_seg) return;
    for (int j = 0; j < NCLUST; j++) lsum[j][t] = 0.0f;
    __syncthreads();
    for (int p = 0; p < 128; p++) {
        int lab = lab_s[p];
        lsum[lab][t] += xf[(size_t)(base + p) * DMODEL + t];
    }
    for (int j = 0; j < NCLUST; j++) atomicAdd(&sums[j * DMODEL + t], lsum[j][t]);
}

__global__ __launch_bounds__(256) void km_update_zero(float* __restrict__ centers, float* __restrict__ sums,
                                                      float* __restrict__ counts, float* __restrict__ csq) {
    __shared__ float red[256];
    int j = blockIdx.x, d = threadIdx.x;
    float c = counts[j];
    float cv = centers[j * DMODEL + d];
    if (c > 0.0f) cv = sums[j * DMODEL + d] / fmaxf(c, 1.0f);
    centers[j * DMODEL + d] = cv;
    red[d] = cv * cv;
    __syncthreads();
    for (int off = 128; off; off >>= 1) { if (d < off) red[d] += red[d + off]; __syncthreads(); }
    if (d == 0) { csq[j] = red[0]; counts[j] = 0.0f; }
    sums[j * DMODEL + d] = 0.0f;
}

__global__ __launch_bounds__(256) void nproj(const float* __restrict__ centers, const float* __restrict__ kW,
                                             const float* __restrict__ kb2, float* __restrict__ outc) {
    int idx = blockIdx.x * 256 + threadIdx.x;
    if (idx >= NCLUST * DMODEL) return;
    int row = idx >> 8, col = idx & 255;
    const float* cr = centers + row * DMODEL;
    float acc = 0.0f;
    for (int d = 0; d < DMODEL; d++) acc += cr[d] * kW[(size_t)d * DMODEL + col];
    outc[idx] = acc + kb2[col];
}

__global__ __launch_bounds__(256) void km_gather(const int* __restrict__ labels, const float* __restrict__ outc,
                                                 float* __restrict__ out) {
    int i = blockIdx.x, t = threadIdx.x;
    int lab = labels[i];
    out[(size_t)i * DMODEL + t] = outc[lab * DMODEL + t];
}

extern "C" void kernel_launch(void* const* d_in, const int* in_sizes, int n_in,
                              void* d_out, int out_size, void* d_ws, size_t ws_size,
                              hipStream_t stream) {
    const float* x_in  = (const float*)d_in[0];
    const float* ln1_g = (const float*)d_in[1];
    const float* ln1_b = (const float*)d_in[2];
    const float* Wq    = (const float*)d_in[3];
    const float* Wkv   = (const float*)d_in[4];
    const float* Wo    = (const float*)d_in[5];
    const float* bo    = (const float*)d_in[6];
    const float* ln2_g = (const float*)d_in[7];
    const float* ln2_b = (const float*)d_in[8];
    const float* W1    = (const float*)d_in[9];
    const float* b1    = (const float*)d_in[10];
    const float* W2    = (const float*)d_in[11];
    const float* b2    = (const float*)d_in[12];
    const float* kWp   = (const float*)d_in[13];
    const float* kbp   = (const float*)d_in[14];
    float* out = (float*)d_out;

    const size_t NEEDED = 53477376;
    if (ws_size < NEEDED) {
        hipMemsetAsync(d_out, 0, (size_t)out_size * sizeof(float), stream);
        return;   // signature: absmax ~0.707 => workspace too small
    }

    char* ws = (char*)d_ws;
    float* xf      = (float*)(ws);                 // 8 MB fp32 residual stream
    u16*   xnh     = (u16*)  (ws + 8388608);       // 4 MB  ln out h
    u16*   xnl     = (u16*)  (ws + 12582912);      // 4 MB  ln out l
    u16*   aoh     = xnh;                          // attn out aliases xn (xn dead after KV gemm)
    u16*   aol     = xnl;
    u16*   qh      = (u16*)  (ws + 16777216);      // 4 MB
    u16*   ql      = (u16*)  (ws + 20971520);      // 4 MB
    u16*   kvh     = (u16*)  (ws + 25165824);      // 8 MB
    u16*   kvl     = (u16*)  (ws + 33554432);      // 8 MB
    u16*   hbh     = (u16*)  (ws + 16777216);      // 16 MB (q/kv dead during FFN)
    u16*   hbl     = (u16*)  (ws + 33554432);      // 16 MB (ends exactly at 48 MB)
    float* dotb    = (float*)(ws + 16777216);      // 2 MB (kmeans time, layers dead)
    float* centers = (float*)(ws + 41943040);
    float* sums    = (float*)(ws + 42008576);
    float* counts  = (float*)(ws + 42074112);
    float* csqb    = (float*)(ws + 42074368);
    int*   labels  = (int*)  (ws + 42075136);
    float* outc    = (float*)(ws + 42107904);
    u16*   wr      = (u16*)  (ws + 50331648);
    u16 *wqh = wr,            *wql = wr + 65536;
    u16 *wkvh = wr + 131072,  *wkvl = wr + 262144;
    u16 *woh = wr + 393216,   *wol = wr + 458752;
    u16 *w1h = wr + 524288,   *w1l = wr + 786432;
    u16 *w2h = wr + 1048576,  *w2l = wr + 1310720;

    hipMemcpyAsync(xf, x_in, (size_t)BN * DMODEL * sizeof(float), hipMemcpyDeviceToDevice, stream);

    for (int l = 0; l < 4; l++) {
        wconv2<<<dim3(4, 4), 256, 0, stream>>>(Wq + (size_t)l * 65536, wqh, wql, 256, 256);
        wconv2<<<dim3(8, 4), 256, 0, stream>>>(Wkv + (size_t)l * 131072, wkvh, wkvl, 256, 512);
        wconv2<<<dim3(4, 4), 256, 0, stream>>>(Wo + (size_t)l * 65536, woh, wol, 256, 256);
        wconv2<<<dim3(16, 4), 256, 0, stream>>>(W1 + (size_t)l * 262144, w1h, w1l, 256, 1024);
        wconv2<<<dim3(4, 16), 256, 0, stream>>>(W2 + (size_t)l * 262144, w2h, w2l, 1024, 256);

        ln_wave<<<BN / 4, 256, 0, stream>>>(xf, ln1_g + l * 256, ln1_b + l * 256, xnh, xnl);
        gemm_bx<<<dim3(4, 64), 256, 0, stream>>>(xnh, xnl, wqh, wql, nullptr, nullptr,
                                                 nullptr, qh, ql, BN, 256, 256, 0);
        gemm_bx<<<dim3(8, 64), 256, 0, stream>>>(xnh, xnl, wkvh, wkvl, nullptr, nullptr,
                                                 nullptr, kvh, kvl, BN, 512, 256, 0);
        attn7<<<dim3(64, 16), 256, 0, stream>>>(qh, ql, kvh, kvl, aoh, aol);
        gemm_bx<<<dim3(4, 64), 256, 0, stream>>>(aoh, aol, woh, wol, bo + l * 256, xf,
                                                 xf, nullptr, nullptr, BN, 256, 256, 0);
        ln_wave<<<BN / 4, 256, 0, stream>>>(xf, ln2_g + l * 256, ln2_b + l * 256, xnh, xnl);
        gemm_bx<<<dim3(16, 64), 256, 0, stream>>>(xnh, xnl, w1h, w1l, b1 + l * 1024, nullptr,
                                                  nullptr, hbh, hbl, BN, 1024, 256, 1);
        gemm_bx<<<dim3(4, 64), 256, 0, stream>>>(hbh, hbl, w2h, w2l, b2 + l * 256, xf,
                                                 xf, nullptr, nullptr, BN, 256, 1024, 0);
    }

    hipMemcpyAsync(centers, xf, NCLUST * DMODEL * sizeof(float), hipMemcpyDeviceToDevice, stream);
    km_zero0<<<64, 256, 0, stream>>>(sums, counts);
    csq_k<<<64, 64, 0, stream>>>(centers, csqb);
    for (int it = 0; it < 10; it++) {
        km_dist<<<128, 256, 0, stream>>>(xf, centers, dotb);
        km_argmin_segsum<<<64, 256, 0, stream>>>(dotb, csqb, xf, labels, counts, sums, 1);
        km_update_zero<<<64, 256, 0, stream>>>(centers, sums, counts, csqb);
    }
    km_dist<<<128, 256, 0, stream>>>(xf, centers, dotb);
    km_argmin_segsum<<<64, 256, 0, stream>>>(dotb, csqb, xf, labels, counts, sums, 0);
    nproj<<<64, 256, 0, stream>>>(centers, kWp, kbp, outc);
    km_gather<<<BN, 256, 0, stream>>>(labels, outc, out);
}

// Round 2
// 1656.539 us; speedup vs baseline: 1.1835x; 1.1835x over previous
//
#include <hip/hip_runtime.h>
#include <hip/hip_bf16.h>
#include <math.h>

// Problem constants (B=8, N=1024, D=256, L=4, M=1024, H=8, dh=32, K=64 clusters)
#define BN 8192           // B*N rows
#define DMODEL 256
#define FFN 1024
#define NCLUST 64

typedef unsigned short u16;
typedef unsigned int u32;
typedef __attribute__((ext_vector_type(8))) short s16x8;      // 8 bf16 (4 VGPRs) MFMA frag
typedef __attribute__((ext_vector_type(8))) unsigned short u16x8;
typedef __attribute__((ext_vector_type(4))) unsigned short u16x4;
typedef __attribute__((ext_vector_type(4))) float f32x4;

__device__ __forceinline__ float bf2f(u16 v) {
    union { unsigned int u; float f; } w; w.u = ((unsigned int)v) << 16; return w.f;
}
__device__ __forceinline__ u16 f2bf(float f) {
    union { float f; unsigned int u; } w; w.f = f;
    unsigned int r = w.u + 0x7fffu + ((w.u >> 16) & 1u);
    return (u16)(r >> 16);
}

// XOR-swizzled LDS index helpers (u16 units). Rows are 32 / 64 u16 (64B / 128B), col is a
// multiple of 8 for b128 accesses; XOR spreads the 16B slots so ds_read_b128 across fr-lanes
// lands on 32 distinct banks (2-way max) instead of the 8-bank lattice of padded strides.
__device__ __forceinline__ int sw32(int row, int col) { return row * 32 + (col ^ (((row >> 1) & 3) << 3)); }
__device__ __forceinline__ int sw64(int row, int col) { return row * 64 + (col ^ ((row & 7) << 3)); }

// ---------------- LayerNorm: one wave per row, float4 + shuffle reduce; emits bf16 h/l ----------------
__global__ __launch_bounds__(256) void ln_wave(const float* __restrict__ x, const float* __restrict__ g,
                                               const float* __restrict__ b, u16* __restrict__ yh,
                                               u16* __restrict__ yl) {
    int t = threadIdx.x, w = t >> 6, l = t & 63;
    int row = blockIdx.x * 4 + w;
    const float* xr = x + (size_t)row * DMODEL;
    float4 v = *reinterpret_cast<const float4*>(xr + l * 4);
    float s = v.x + v.y + v.z + v.w;
    for (int off = 1; off < 64; off <<= 1) s += __shfl_xor(s, off);
    float mean = s * (1.0f / 256.0f);
    float4 dv = make_float4(v.x - mean, v.y - mean, v.z - mean, v.w - mean);
    float vs = dv.x * dv.x + dv.y * dv.y + dv.z * dv.z + dv.w * dv.w;
    for (int off = 1; off < 64; off <<= 1) vs += __shfl_xor(vs, off);
    float rs = rsqrtf(vs * (1.0f / 256.0f) + 1e-5f);
    float4 gg = *reinterpret_cast<const float4*>(g + l * 4);
    float4 bb = *reinterpret_cast<const float4*>(b + l * 4);
    float os[4] = {dv.x * rs * gg.x + bb.x, dv.y * rs * gg.y + bb.y,
                   dv.z * rs * gg.z + bb.z, dv.w * rs * gg.w + bb.w};
    u16x4 hv, lv;
#pragma unroll
    for (int j = 0; j < 4; j++) { u16 hh = f2bf(os[j]); hv[j] = hh; lv[j] = f2bf(os[j] - bf2f(hh)); }
    size_t o = (size_t)row * DMODEL + l * 4;
    *reinterpret_cast<u16x4*>(yh + o) = hv;
    *reinterpret_cast<u16x4*>(yl + o) = lv;
}

// ---------------- Weight convert v2: LDS tile transpose, coalesced both sides ----------------
// W[K][N] fp32 -> th[n][k], tl[n][k] bf16 (bit-identical to r12 wconv output).
__global__ __launch_bounds__(256) void wconv2(const float* __restrict__ W, u16* __restrict__ th,
                                              u16* __restrict__ tl, int K, int N) {
    __shared__ float T[64][65];
    int k0 = blockIdx.y * 64, n0 = blockIdx.x * 64;
    int t = threadIdx.x;
    int r = t >> 4, c4 = (t & 15) * 4;
#pragma unroll
    for (int i = 0; i < 4; i++) {
        float4 x = *reinterpret_cast<const float4*>(W + (size_t)(k0 + r + 16 * i) * N + n0 + c4);
        T[r + 16 * i][c4] = x.x; T[r + 16 * i][c4 + 1] = x.y;
        T[r + 16 * i][c4 + 2] = x.z; T[r + 16 * i][c4 + 3] = x.w;
    }
    __syncthreads();
#pragma unroll
    for (int i = 0; i < 4; i++) {
        int n = r + 16 * i;
        u16x4 h4, l4;
#pragma unroll
        for (int j = 0; j < 4; j++) {
            float v = T[c4 + j][n];
            u16 h = f2bf(v);
            h4[j] = h; l4[j] = f2bf(v - bf2f(h));
        }
        *reinterpret_cast<u16x4*>(th + (size_t)(n0 + n) * K + k0 + c4) = h4;
        *reinterpret_cast<u16x4*>(tl + (size_t)(n0 + n) * K + k0 + c4) = l4;
    }
}

// ---------------- MFMA GEMM (bf16x2), templated BM (128: 4 waves stacked in M; 64: 2x2 waves) ----
// A pre-split h/l -> staging is pure u16x8 copies into XOR-swizzled linear LDS tiles.
template<int BM, int NI>
__global__ __launch_bounds__(256) void gemm_t(const u16* __restrict__ Ath, const u16* __restrict__ Atl,
                                              const u16* __restrict__ Bth, const u16* __restrict__ Btl,
                                              const float* __restrict__ bias, const float* __restrict__ resid,
                                              float* __restrict__ Cf, u16* __restrict__ Ch, u16* __restrict__ Cl,
                                              int M, int N, int K, int fuse_gelu) {
    __shared__ u16 Ah[BM * 32], Al[BM * 32];
    __shared__ u16 Bh[64 * 32], Bl[64 * 32];
    int t = threadIdx.x;
    int m0 = blockIdx.y * BM, n0 = blockIdx.x * 64;
    int L = t & 63, w = t >> 6, fr = L & 15, quad = L >> 4;
    int wm, wn;
    if constexpr (BM == 128) { wm = w; wn = 0; } else { wm = w & 1; wn = w >> 1; }
    f32x4 acc[2][NI];
#pragma unroll
    for (int i = 0; i < 2; i++)
#pragma unroll
        for (int j = 0; j < NI; j++) acc[i][j] = (f32x4){0.0f, 0.0f, 0.0f, 0.0f};

    for (int k0 = 0; k0 < K; k0 += 32) {
        __syncthreads();
        if constexpr (BM == 128) {
            int sm = t >> 1, sk = (t & 1) * 16;
            size_t ga = (size_t)(m0 + sm) * K + k0 + sk;
            u16x8 h0 = *reinterpret_cast<const u16x8*>(Ath + ga);
            u16x8 h1 = *reinterpret_cast<const u16x8*>(Ath + ga + 8);
            u16x8 l0 = *reinterpret_cast<const u16x8*>(Atl + ga);
            u16x8 l1 = *reinterpret_cast<const u16x8*>(Atl + ga + 8);
            *reinterpret_cast<u16x8*>(&Ah[sw32(sm, sk)])     = h0;
            *reinterpret_cast<u16x8*>(&Ah[sw32(sm, sk + 8)]) = h1;
            *reinterpret_cast<u16x8*>(&Al[sw32(sm, sk)])     = l0;
            *reinterpret_cast<u16x8*>(&Al[sw32(sm, sk + 8)]) = l1;
        } else {
            int sm = t >> 2, sk = (t & 3) * 8;
            size_t ga = (size_t)(m0 + sm) * K + k0 + sk;
            *reinterpret_cast<u16x8*>(&Ah[sw32(sm, sk)]) = *reinterpret_cast<const u16x8*>(Ath + ga);
            *reinterpret_cast<u16x8*>(&Al[sw32(sm, sk)]) = *reinterpret_cast<const u16x8*>(Atl + ga);
        }
        {
            int sn = t >> 2, sk = (t & 3) * 8;
            size_t gb = (size_t)(n0 + sn) * K + k0 + sk;
            *reinterpret_cast<u16x8*>(&Bh[sw32(sn, sk)]) = *reinterpret_cast<const u16x8*>(Bth + gb);
            *reinterpret_cast<u16x8*>(&Bl[sw32(sn, sk)]) = *reinterpret_cast<const u16x8*>(Btl + gb);
        }
        __syncthreads();
        s16x8 ah[2], al[2];
#pragma unroll
        for (int mi = 0; mi < 2; mi++) {
            int row = wm * 32 + mi * 16 + fr;
            ah[mi] = *reinterpret_cast<s16x8*>(&Ah[sw32(row, quad * 8)]);
            al[mi] = *reinterpret_cast<s16x8*>(&Al[sw32(row, quad * 8)]);
        }
#pragma unroll
        for (int ni = 0; ni < NI; ni++) {
            int rn = wn * 32 + ni * 16 + fr;
            s16x8 bhf = *reinterpret_cast<s16x8*>(&Bh[sw32(rn, quad * 8)]);
            s16x8 blf = *reinterpret_cast<s16x8*>(&Bl[sw32(rn, quad * 8)]);
#pragma unroll
            for (int mi = 0; mi < 2; mi++) {
                acc[mi][ni] = __builtin_amdgcn_mfma_f32_16x16x32_bf16(ah[mi], bhf, acc[mi][ni], 0, 0, 0);
                acc[mi][ni] = __builtin_amdgcn_mfma_f32_16x16x32_bf16(ah[mi], blf, acc[mi][ni], 0, 0, 0);
                acc[mi][ni] = __builtin_amdgcn_mfma_f32_16x16x32_bf16(al[mi], bhf, acc[mi][ni], 0, 0, 0);
            }
        }
    }
#pragma unroll
    for (int mi = 0; mi < 2; mi++) {
#pragma unroll
        for (int ni = 0; ni < NI; ni++) {
#pragma unroll
            for (int r = 0; r < 4; r++) {
                int row = m0 + wm * 32 + mi * 16 + quad * 4 + r;
                int col = n0 + wn * 32 + ni * 16 + fr;
                float v = acc[mi][ni][r];
                if (bias) v += bias[col];
                if (fuse_gelu) v = 0.5f * v * (1.0f + erff(v * 0.70710678118654752f));
                if (resid) v += resid[(size_t)row * N + col];
                size_t o = (size_t)row * N + col;
                if (Cf) Cf[o] = v;
                if (Ch) { u16 hh = f2bf(v); Ch[o] = hh; Cl[o] = f2bf(v - bf2f(hh)); }
            }
        }
    }
}

// ---------------- Attention v8: fused-QKV input (row stride 768), XOR-swizzled LDS ----------------
// qkv row layout: [q(256) | k(256) | v(256)]; per head h the slice h*32..h*32+31 of each.
__global__ __launch_bounds__(256) void attn8(const u16* __restrict__ qkvh, const u16* __restrict__ qkvl,
                                             u16* __restrict__ aoh, u16* __restrict__ aol) {
    int bh = blockIdx.x, b = bh >> 3, h = bh & 7;
    int qt = blockIdx.y;
    int t = threadIdx.x, L = t & 63, w = t >> 6;
    int fr = L & 15, quad = L >> 4;
    __shared__ u16 QH[64 * 32], QL[64 * 32];       // sw32 layout
    __shared__ u16 KH[64 * 32], KL[64 * 32];
    __shared__ u16 VTH[32 * 64], VTL[32 * 64];     // V^T[d][kc], sw64 layout
    __shared__ u16 PH[4 * 16 * 64], PL[4 * 16 * 64];  // per-wave P tile, sw64 layout
    const float scale = 0.17677669529663687f;  // 1/sqrt(32)
    const int ROWS = 768;

    {   // stage Q 64x32: thread -> row t>>2, dims (t&3)*8..+7 (u16x8 copies)
        int qr = t >> 2, d0 = (t & 3) * 8;
        size_t gq = (size_t)(b * 1024 + qt * 64 + qr) * ROWS + h * 32 + d0;
        *reinterpret_cast<u16x8*>(&QH[sw32(qr, d0)]) = *reinterpret_cast<const u16x8*>(qkvh + gq);
        *reinterpret_cast<u16x8*>(&QL[sw32(qr, d0)]) = *reinterpret_cast<const u16x8*>(qkvl + gq);
    }
    __syncthreads();
    s16x8 aqh = *reinterpret_cast<s16x8*>(&QH[sw32(w * 16 + fr, quad * 8)]);  // hoisted A-frags
    s16x8 aql = *reinterpret_cast<s16x8*>(&QL[sw32(w * 16 + fr, quad * 8)]);

    float m_i[4], l_i[4];
    f32x4 acc_o[2];
#pragma unroll
    for (int r = 0; r < 4; r++) { m_i[r] = -1e30f; l_i[r] = 0.0f; }
    acc_o[0] = (f32x4){0.0f, 0.0f, 0.0f, 0.0f};
    acc_o[1] = (f32x4){0.0f, 0.0f, 0.0f, 0.0f};

    for (int kt = 0; kt < 16; kt++) {
        __syncthreads();   // protect K/VT from prior-iteration readers
        {   // stage K rows: row t>>2, dims (t&3)*8..+7
            int kr = t >> 2, d0 = (t & 3) * 8;
            size_t gk = (size_t)(b * 1024 + kt * 64 + kr) * ROWS + 256 + h * 32 + d0;
            *reinterpret_cast<u16x8*>(&KH[sw32(kr, d0)]) = *reinterpret_cast<const u16x8*>(qkvh + gk);
            *reinterpret_cast<u16x8*>(&KL[sw32(kr, d0)]) = *reinterpret_cast<const u16x8*>(qkvl + gk);
        }
        {   // stage V transposed: thread -> kc pair 2p,2p+1, dims (t&7)*4..+3 (pack-only)
            int vp = t >> 3, vd0 = (t & 7) * 4;
            size_t g0 = (size_t)(b * 1024 + kt * 64 + 2 * vp) * ROWS + 512 + h * 32 + vd0;
            u16x4 h0 = *reinterpret_cast<const u16x4*>(qkvh + g0);
            u16x4 h1 = *reinterpret_cast<const u16x4*>(qkvh + g0 + ROWS);
            u16x4 l0 = *reinterpret_cast<const u16x4*>(qkvl + g0);
            u16x4 l1 = *reinterpret_cast<const u16x4*>(qkvl + g0 + ROWS);
#pragma unroll
            for (int i = 0; i < 4; i++) {
                int d = vd0 + i;
                int idx = sw64(d, 2 * vp);
                *reinterpret_cast<u32*>(&VTH[idx]) = (u32)h0[i] | ((u32)h1[i] << 16);
                *reinterpret_cast<u32*>(&VTL[idx]) = (u32)l0[i] | ((u32)l1[i] << 16);
            }
        }
        __syncthreads();
        // S = Q K^T : 4 n-subtiles, bf16x2 (3 MFMA each)
        f32x4 s[4];
#pragma unroll
        for (int ni = 0; ni < 4; ni++) {
            s16x8 bkh = *reinterpret_cast<s16x8*>(&KH[sw32(ni * 16 + fr, quad * 8)]);
            s16x8 bkl = *reinterpret_cast<s16x8*>(&KL[sw32(ni * 16 + fr, quad * 8)]);
            f32x4 c = (f32x4){0.0f, 0.0f, 0.0f, 0.0f};
            c = __builtin_amdgcn_mfma_f32_16x16x32_bf16(aqh, bkh, c, 0, 0, 0);
            c = __builtin_amdgcn_mfma_f32_16x16x32_bf16(aqh, bkl, c, 0, 0, 0);
            c = __builtin_amdgcn_mfma_f32_16x16x32_bf16(aql, bkh, c, 0, 0, 0);
            s[ni] = c;
        }
        // online softmax: lane owns rows quad*4+r, cols ni*16+fr; row spans 16 lanes (same quad)
        float alpha[4];
#pragma unroll
        for (int r = 0; r < 4; r++) {
            float s0 = s[0][r] * scale, s1 = s[1][r] * scale;
            float s2 = s[2][r] * scale, s3 = s[3][r] * scale;
            float ml = fmaxf(fmaxf(s0, s1), fmaxf(s2, s3));
            for (int off = 1; off < 16; off <<= 1) ml = fmaxf(ml, __shfl_xor(ml, off));
            float mnew = fmaxf(m_i[r], ml);
            alpha[r] = __expf(m_i[r] - mnew);
            m_i[r] = mnew;
            float p0 = __expf(s0 - mnew), p1 = __expf(s1 - mnew);
            float p2 = __expf(s2 - mnew), p3 = __expf(s3 - mnew);
            float rs = p0 + p1 + p2 + p3;
            for (int off = 1; off < 16; off <<= 1) rs += __shfl_xor(rs, off);
            l_i[r] = l_i[r] * alpha[r] + rs;
            int row = quad * 4 + r;
            float ps[4] = {p0, p1, p2, p3};
#pragma unroll
            for (int ni = 0; ni < 4; ni++) {
                u16 ph = f2bf(ps[ni]);
                int idx = w * 1024 + sw64(row, ni * 16 + fr);
                PH[idx] = ph;
                PL[idx] = f2bf(ps[ni] - bf2f(ph));
            }
        }
        acc_o[0][0] *= alpha[0]; acc_o[0][1] *= alpha[1]; acc_o[0][2] *= alpha[2]; acc_o[0][3] *= alpha[3];
        acc_o[1][0] *= alpha[0]; acc_o[1][1] *= alpha[1]; acc_o[1][2] *= alpha[2]; acc_o[1][3] *= alpha[3];
        // PV: O += P V ; P wave-private (same-wave LDS write->read ordering)
#pragma unroll
        for (int ks = 0; ks < 2; ks++) {
            s16x8 aph = *reinterpret_cast<s16x8*>(&PH[w * 1024 + sw64(fr, ks * 32 + quad * 8)]);
            s16x8 apl = *reinterpret_cast<s16x8*>(&PL[w * 1024 + sw64(fr, ks * 32 + quad * 8)]);
#pragma unroll
            for (int ns = 0; ns < 2; ns++) {
                s16x8 bvh = *reinterpret_cast<s16x8*>(&VTH[sw64(ns * 16 + fr, ks * 32 + quad * 8)]);
                s16x8 bvl = *reinterpret_cast<s16x8*>(&VTL[sw64(ns * 16 + fr, ks * 32 + quad * 8)]);
                acc_o[ns] = __builtin_amdgcn_mfma_f32_16x16x32_bf16(aph, bvh, acc_o[ns], 0, 0, 0);
                acc_o[ns] = __builtin_amdgcn_mfma_f32_16x16x32_bf16(aph, bvl, acc_o[ns], 0, 0, 0);
                acc_o[ns] = __builtin_amdgcn_mfma_f32_16x16x32_bf16(apl, bvh, acc_o[ns], 0, 0, 0);
            }
        }
    }
    // write O as bf16 h/l (row stride DMODEL): row = quad*4+r of wave tile, col = ns*16+fr
#pragma unroll
    for (int r = 0; r < 4; r++) {
        float invl = 1.0f / l_i[r];
        size_t rowbase = ((size_t)(b * 1024 + qt * 64 + w * 16 + quad * 4 + r)) * DMODEL + h * 32;
        float v0 = acc_o[0][r] * invl, v1 = acc_o[1][r] * invl;
        u16 h0 = f2bf(v0); aoh[rowbase + fr] = h0;      aol[rowbase + fr] = f2bf(v0 - bf2f(h0));
        u16 h1 = f2bf(v1); aoh[rowbase + 16 + fr] = h1; aol[rowbase + 16 + fr] = f2bf(v1 - bf2f(h1));
    }
}

// ---------------- K-means v3: fused dist+argmin (256 blocks), chunked atomic-free segsum ---------
__global__ __launch_bounds__(64) void csq_k(const float* __restrict__ centers, float* __restrict__ csq) {
    int j = blockIdx.x, l = threadIdx.x;
    float4 c4 = *reinterpret_cast<const float4*>(centers + j * DMODEL + l * 4);
    float s = c4.x * c4.x + c4.y * c4.y + c4.z * c4.z + c4.w * c4.w;
    for (int off = 1; off < 64; off <<= 1) s += __shfl_xor(s, off);
    if (l == 0) csq[j] = s;
}

// 32 rows x 64 clusters per block; grid 256. Same fp32 dot order as the proven km_dist.
__global__ __launch_bounds__(256) void km_distmin(const float* __restrict__ A, const float* __restrict__ Cn,
                                                  const float* __restrict__ csq, int* __restrict__ labels) {
    __shared__ float As[16][33];
    __shared__ float Bs[16][64];
    int t = threadIdx.x, tx = t & 15, ty = t >> 4;
    int m0 = blockIdx.x * 32;
    int mr = t & 31, kq = (t >> 5) * 2;
    int jb = t & 63, kb = (t >> 6) * 4;
    float acc[2][4] = {};
    for (int k0 = 0; k0 < 256; k0 += 16) {
        __syncthreads();
        {
            float2 a2 = *reinterpret_cast<const float2*>(A + (size_t)(m0 + mr) * DMODEL + k0 + kq);
            As[kq][mr] = a2.x; As[kq + 1][mr] = a2.y;
        }
        {
            float4 c4 = *reinterpret_cast<const float4*>(Cn + (size_t)jb * DMODEL + k0 + kb);
            Bs[kb][jb] = c4.x; Bs[kb + 1][jb] = c4.y; Bs[kb + 2][jb] = c4.z; Bs[kb + 3][jb] = c4.w;
        }
        __syncthreads();
#pragma unroll
        for (int kk = 0; kk < 16; kk++) {
            float a[2] = {As[kk][ty * 2], As[kk][ty * 2 + 1]};
            float4 b4 = *reinterpret_cast<float4*>(&Bs[kk][tx * 4]);
            float bf[4] = {b4.x, b4.y, b4.z, b4.w};
#pragma unroll
            for (int i = 0; i < 2; i++)
#pragma unroll
                for (int j = 0; j < 4; j++) acc[i][j] += a[i] * bf[j];
        }
    }
    float4 cs4 = *reinterpret_cast<const float4*>(csq + tx * 4);
    float csv[4] = {cs4.x, cs4.y, cs4.z, cs4.w};
#pragma unroll
    for (int i = 0; i < 2; i++) {
        float best = csv[0] - 2.0f * acc[i][0]; int bi = tx * 4;
#pragma unroll
        for (int j = 1; j < 4; j++) {
            float v = csv[j] - 2.0f * acc[i][j];
            if (v < best) { best = v; bi = tx * 4 + j; }
        }
        for (int off = 1; off < 16; off <<= 1) {
            float ov = __shfl_xor(best, off);
            int oi = __shfl_xor(bi, off);
            if (ov < best || (ov == best && oi < bi)) { best = ov; bi = oi; }
        }
        if (tx == 0) labels[m0 + ty * 2 + i] = bi;
    }
}

// block (c, j): scan chunk c's 1024 labels, accumulate rows with lab==j. Uniform branch, no atomics.
__global__ __launch_bounds__(256) void km_segsum(const int* __restrict__ labels, const float* __restrict__ xf,
                                                 float* __restrict__ sums8, float* __restrict__ counts8) {
    int c = blockIdx.x, j = blockIdx.y, t = threadIdx.x;
    __shared__ int labs[1024];
    {
        int4 l4 = *reinterpret_cast<const int4*>(labels + c * 1024 + t * 4);
        labs[t * 4] = l4.x; labs[t * 4 + 1] = l4.y; labs[t * 4 + 2] = l4.z; labs[t * 4 + 3] = l4.w;
    }
    __syncthreads();
    float acc = 0.0f, cnt = 0.0f;
    const float* xb = xf + (size_t)c * 1024 * DMODEL;
    for (int i = 0; i < 1024; i++) {
        if (labs[i] == j) { acc += xb[(size_t)i * DMODEL + t]; cnt += 1.0f; }
    }
    sums8[((size_t)c * NCLUST + j) * DMODEL + t] = acc;
    if (t == 0) counts8[c * NCLUST + j] = cnt;
}

__global__ __launch_bounds__(256) void km_update(float* __restrict__ centers, const float* __restrict__ sums8,
                                                 const float* __restrict__ counts8, float* __restrict__ csq) {
    __shared__ float red[256];
    int j = blockIdx.x, d = threadIdx.x;
    float c = 0.0f;
#pragma unroll
    for (int cc = 0; cc < 8; cc++) c += counts8[cc * NCLUST + j];
    float sv = 0.0f;
#pragma unroll
    for (int cc = 0; cc < 8; cc++) sv += sums8[((size_t)cc * NCLUST + j) * DMODEL + d];
    float cv = centers[j * DMODEL + d];
    if (c > 0.0f) cv = sv / fmaxf(c, 1.0f);
    centers[j * DMODEL + d] = cv;
    red[d] = cv * cv;
    __syncthreads();
    for (int off = 128; off; off >>= 1) { if (d < off) red[d] += red[d + off]; __syncthreads(); }
    if (d == 0) csq[j] = red[0];
}

__global__ __launch_bounds__(256) void nproj(const float* __restrict__ centers, const float* __restrict__ kW,
                                             const float* __restrict__ kb2, float* __restrict__ outc) {
    int idx = blockIdx.x * 256 + threadIdx.x;
    if (idx >= NCLUST * DMODEL) return;
    int row = idx >> 8, col = idx & 255;
    const float* cr = centers + row * DMODEL;
    float acc = 0.0f;
    for (int d = 0; d < DMODEL; d++) acc += cr[d] * kW[(size_t)d * DMODEL + col];
    outc[idx] = acc + kb2[col];
}

__global__ __launch_bounds__(256) void km_gather(const int* __restrict__ labels, const float* __restrict__ outc,
                                                 float* __restrict__ out) {
    int i = blockIdx.x, t = threadIdx.x;
    int lab = labels[i];
    out[(size_t)i * DMODEL + t] = outc[lab * DMODEL + t];
}

extern "C" void kernel_launch(void* const* d_in, const int* in_sizes, int n_in,
                              void* d_out, int out_size, void* d_ws, size_t ws_size,
                              hipStream_t stream) {
    const float* x_in  = (const float*)d_in[0];
    const float* ln1_g = (const float*)d_in[1];
    const float* ln1_b = (const float*)d_in[2];
    const float* Wq    = (const float*)d_in[3];
    const float* Wkv   = (const float*)d_in[4];
    const float* Wo    = (const float*)d_in[5];
    const float* bo    = (const float*)d_in[6];
    const float* ln2_g = (const float*)d_in[7];
    const float* ln2_b = (const float*)d_in[8];
    const float* W1    = (const float*)d_in[9];
    const float* b1    = (const float*)d_in[10];
    const float* W2    = (const float*)d_in[11];
    const float* b2    = (const float*)d_in[12];
    const float* kWp   = (const float*)d_in[13];
    const float* kbp   = (const float*)d_in[14];
    float* out = (float*)d_out;

    const size_t NEEDED = 53477376;
    if (ws_size < NEEDED) {
        hipMemsetAsync(d_out, 0, (size_t)out_size * sizeof(float), stream);
        return;   // signature: absmax ~0.707 => workspace too small
    }

    char* ws = (char*)d_ws;
    float* xf      = (float*)(ws);                 // 8 MB fp32 residual stream
    u16*   xnh     = (u16*)  (ws + 8388608);       // 4 MB  ln out h
    u16*   xnl     = (u16*)  (ws + 12582912);      // 4 MB  ln out l
    u16*   aoh     = xnh;                          // attn out aliases xn (xn dead after QKV gemm)
    u16*   aol     = xnl;
    u16*   qkvh    = (u16*)  (ws + 16777216);      // 12 MB (8192x768 u16) -> ends 29360128
    u16*   qkvl    = (u16*)  (ws + 29360128);      // 12 MB -> ends 41943040
    u16*   hbh     = (u16*)  (ws + 16777216);      // 16 MB (qkv dead during FFN)
    u16*   hbl     = (u16*)  (ws + 33554432);      // 16 MB -> ends 50331648
    float* centers = (float*)(ws + 41943040);      // 64 KB
    float* csqb    = (float*)(ws + 42008576);      // 256 B
    float* counts8 = (float*)(ws + 42008832);      // 2 KB
    int*   labels  = (int*)  (ws + 42010880);      // 32 KB
    float* outc    = (float*)(ws + 42043648);      // 64 KB
    float* sums8   = (float*)(ws + 42109184);      // 512 KB -> ends 42633472
    u16*   wr      = (u16*)  (ws + 50331648);
    u16 *wqkvh = wr,          *wqkvl = wr + 196608;   // 768x256 each
    u16 *woh = wr + 393216,   *wol = wr + 458752;
    u16 *w1h = wr + 524288,   *w1l = wr + 786432;
    u16 *w2h = wr + 1048576,  *w2l = wr + 1310720;

    hipMemcpyAsync(xf, x_in, (size_t)BN * DMODEL * sizeof(float), hipMemcpyDeviceToDevice, stream);

    for (int l = 0; l < 4; l++) {
        // fused QKV weights: rows 0-255 = Wq cols, rows 256-767 = Wkv cols ([k|v])
        wconv2<<<dim3(4, 4), 256, 0, stream>>>(Wq + (size_t)l * 65536, wqkvh, wqkvl, 256, 256);
        wconv2<<<dim3(8, 4), 256, 0, stream>>>(Wkv + (size_t)l * 131072, wqkvh + 256 * 256, wqkvl + 256 * 256, 256, 512);
        wconv2<<<dim3(4, 4), 256, 0, stream>>>(Wo + (size_t)l * 65536, woh, wol, 256, 256);
        wconv2<<<dim3(16, 4), 256, 0, stream>>>(W1 + (size_t)l * 262144, w1h, w1l, 256, 1024);
        wconv2<<<dim3(4, 16), 256, 0, stream>>>(W2 + (size_t)l * 262144, w2h, w2l, 1024, 256);

        ln_wave<<<BN / 4, 256, 0, stream>>>(xf, ln1_g + l * 256, ln1_b + l * 256, xnh, xnl);
        gemm_t<128, 4><<<dim3(12, 64), 256, 0, stream>>>(xnh, xnl, wqkvh, wqkvl, nullptr, nullptr,
                                                         nullptr, qkvh, qkvl, BN, 768, 256, 0);
        attn8<<<dim3(64, 16), 256, 0, stream>>>(qkvh, qkvl, aoh, aol);
        gemm_t<64, 2><<<dim3(4, 128), 256, 0, stream>>>(aoh, aol, woh, wol, bo + l * 256, xf,
                                                        xf, nullptr, nullptr, BN, 256, 256, 0);
        ln_wave<<<BN / 4, 256, 0, stream>>>(xf, ln2_g + l * 256, ln2_b + l * 256, xnh, xnl);
        gemm_t<128, 4><<<dim3(16, 64), 256, 0, stream>>>(xnh, xnl, w1h, w1l, b1 + l * 1024, nullptr,
                                                         nullptr, hbh, hbl, BN, 1024, 256, 1);
        gemm_t<64, 2><<<dim3(4, 128), 256, 0, stream>>>(hbh, hbl, w2h, w2l, b2 + l * 256, xf,
                                                        xf, nullptr, nullptr, BN, 256, 1024, 0);
    }

    hipMemcpyAsync(centers, xf, NCLUST * DMODEL * sizeof(float), hipMemcpyDeviceToDevice, stream);
    csq_k<<<64, 64, 0, stream>>>(centers, csqb);
    for (int it = 0; it < 10; it++) {
        km_distmin<<<256, 256, 0, stream>>>(xf, centers, csqb, labels);
        km_segsum<<<dim3(8, NCLUST), 256, 0, stream>>>(labels, xf, sums8, counts8);
        km_update<<<64, 256, 0, stream>>>(centers, sums8, counts8, csqb);
    }
    km_distmin<<<256, 256, 0, stream>>>(xf, centers, csqb, labels);
    nproj<<<64, 256, 0, stream>>>(centers, kWp, kbp, outc);
    km_gather<<<BN, 256, 0, stream>>>(labels, outc, out);
}

// Round 3
// 1598.013 us; speedup vs baseline: 1.2268x; 1.0366x over previous
//
#include <hip/hip_runtime.h>
#include <hip/hip_bf16.h>
#include <math.h>

// Problem constants (B=8, N=1024, D=256, L=4, M=1024, H=8, dh=32, K=64 clusters)
#define BN 8192           // B*N rows
#define DMODEL 256
#define FFN 1024
#define NCLUST 64

typedef unsigned short u16;
typedef unsigned int u32;
typedef __attribute__((ext_vector_type(8))) short s16x8;      // 8 bf16 (4 VGPRs) MFMA frag
typedef __attribute__((ext_vector_type(8))) unsigned short u16x8;
typedef __attribute__((ext_vector_type(4))) unsigned short u16x4;
typedef __attribute__((ext_vector_type(4))) float f32x4;

__device__ __forceinline__ float bf2f(u16 v) {
    union { unsigned int u; float f; } w; w.u = ((unsigned int)v) << 16; return w.f;
}
__device__ __forceinline__ u16 f2bf(float f) {
    union { float f; unsigned int u; } w; w.f = f;
    unsigned int r = w.u + 0x7fffu + ((w.u >> 16) & 1u);
    return (u16)(r >> 16);
}

// async global->LDS, 16B per lane. LDS dest = wave-uniform base + lane*16 (linear);
// swizzled layouts are achieved by pre-swizzling the per-lane GLOBAL source column.
__device__ __forceinline__ void gl16(const u16* g, u16* l) {
    __builtin_amdgcn_global_load_lds((const __attribute__((address_space(1))) u32*)g,
                                     (__attribute__((address_space(3))) u32*)l, 16, 0, 0);
}

// XOR-swizzled LDS index helpers (u16 units). Rows are 32 / 64 u16 (64B / 128B); col is a
// multiple of 8 for b128 accesses; XOR spreads 16B slots across banks.
__device__ __forceinline__ int sw32(int row, int col) { return row * 32 + (col ^ (((row >> 1) & 3) << 3)); }
__device__ __forceinline__ int sw64(int row, int col) { return row * 64 + (col ^ ((row & 7) << 3)); }

// ---------------- LayerNorm: one wave per row, float4 + shuffle reduce; emits bf16 h/l ----------------
__global__ __launch_bounds__(256) void ln_wave(const float* __restrict__ x, const float* __restrict__ g,
                                               const float* __restrict__ b, u16* __restrict__ yh,
                                               u16* __restrict__ yl) {
    int t = threadIdx.x, w = t >> 6, l = t & 63;
    int row = blockIdx.x * 4 + w;
    const float* xr = x + (size_t)row * DMODEL;
    float4 v = *reinterpret_cast<const float4*>(xr + l * 4);
    float s = v.x + v.y + v.z + v.w;
    for (int off = 1; off < 64; off <<= 1) s += __shfl_xor(s, off);
    float mean = s * (1.0f / 256.0f);
    float4 dv = make_float4(v.x - mean, v.y - mean, v.z - mean, v.w - mean);
    float vs = dv.x * dv.x + dv.y * dv.y + dv.z * dv.z + dv.w * dv.w;
    for (int off = 1; off < 64; off <<= 1) vs += __shfl_xor(vs, off);
    float rs = rsqrtf(vs * (1.0f / 256.0f) + 1e-5f);
    float4 gg = *reinterpret_cast<const float4*>(g + l * 4);
    float4 bb = *reinterpret_cast<const float4*>(b + l * 4);
    float os[4] = {dv.x * rs * gg.x + bb.x, dv.y * rs * gg.y + bb.y,
                   dv.z * rs * gg.z + bb.z, dv.w * rs * gg.w + bb.w};
    u16x4 hv, lv;
#pragma unroll
    for (int j = 0; j < 4; j++) { u16 hh = f2bf(os[j]); hv[j] = hh; lv[j] = f2bf(os[j] - bf2f(hh)); }
    size_t o = (size_t)row * DMODEL + l * 4;
    *reinterpret_cast<u16x4*>(yh + o) = hv;
    *reinterpret_cast<u16x4*>(yl + o) = lv;
}

// ---------------- Weight convert: one fused launch per layer (5 weights, 192 blocks) --------------
// W[K][N] fp32 -> th[n][k], tl[n][k] bf16 (bit-identical math to proven wconv2).
__device__ __forceinline__ void wconv_body(const float* __restrict__ W, u16* __restrict__ th,
                                           u16* __restrict__ tl, int K, int N, int bx, int by) {
    __shared__ float T[64][65];
    int k0 = by * 64, n0 = bx * 64;
    int t = threadIdx.x;
    int r = t >> 4, c4 = (t & 15) * 4;
#pragma unroll
    for (int i = 0; i < 4; i++) {
        float4 x = *reinterpret_cast<const float4*>(W + (size_t)(k0 + r + 16 * i) * N + n0 + c4);
        T[r + 16 * i][c4] = x.x; T[r + 16 * i][c4 + 1] = x.y;
        T[r + 16 * i][c4 + 2] = x.z; T[r + 16 * i][c4 + 3] = x.w;
    }
    __syncthreads();
#pragma unroll
    for (int i = 0; i < 4; i++) {
        int n = r + 16 * i;
        u16x4 h4, l4;
#pragma unroll
        for (int j = 0; j < 4; j++) {
            float v = T[c4 + j][n];
            u16 h = f2bf(v);
            h4[j] = h; l4[j] = f2bf(v - bf2f(h));
        }
        *reinterpret_cast<u16x4*>(th + (size_t)(n0 + n) * K + k0 + c4) = h4;
        *reinterpret_cast<u16x4*>(tl + (size_t)(n0 + n) * K + k0 + c4) = l4;
    }
}

__global__ __launch_bounds__(256) void wconv_all(const float* __restrict__ Wq, const float* __restrict__ Wkv,
                                                 const float* __restrict__ Wo, const float* __restrict__ W1,
                                                 const float* __restrict__ W2,
                                                 u16* __restrict__ wqkvh, u16* __restrict__ wqkvl,
                                                 u16* __restrict__ woh, u16* __restrict__ wol,
                                                 u16* __restrict__ w1h, u16* __restrict__ w1l,
                                                 u16* __restrict__ w2h, u16* __restrict__ w2l) {
    int f = blockIdx.x;
    if (f < 16)       wconv_body(Wq,  wqkvh,               wqkvl,               256, 256,  f & 3,  f >> 2);
    else if (f < 48)  { int g = f - 16;  wconv_body(Wkv, wqkvh + 65536,       wqkvl + 65536,       256, 512,  g & 7,  g >> 3); }
    else if (f < 64)  { int g = f - 48;  wconv_body(Wo,  woh,                 wol,                 256, 256,  g & 3,  g >> 2); }
    else if (f < 128) { int g = f - 64;  wconv_body(W1,  w1h,                 w1l,                 256, 1024, g & 15, g >> 4); }
    else              { int g = f - 128; wconv_body(W2,  w2h,                 w2l,                 1024, 256, g & 3,  g >> 2); }
}

// ---------------- MFMA GEMM (bf16x2): global_load_lds staging, pre-swizzled source ----------------
// BM=128: 4 waves stacked in M, NI=4; BM=64: 2x2 waves, NI=2.
template<int BM, int NI>
__global__ __launch_bounds__(256) void gemm_t(const u16* __restrict__ Ath, const u16* __restrict__ Atl,
                                              const u16* __restrict__ Bth, const u16* __restrict__ Btl,
                                              const float* __restrict__ bias, const float* __restrict__ resid,
                                              float* __restrict__ Cf, u16* __restrict__ Ch, u16* __restrict__ Cl,
                                              int M, int N, int K, int fuse_gelu) {
    __shared__ u16 Ah[BM * 32], Al[BM * 32];
    __shared__ u16 Bh[64 * 32], Bl[64 * 32];
    constexpr int SEGS = (BM == 128) ? 6 : 4;   // 1KB segments per wave per K-step
    int t = threadIdx.x;
    int m0 = blockIdx.y * BM, n0 = blockIdx.x * 64;
    int L = t & 63, w = t >> 6, fr = L & 15, quad = L >> 4;
    int wm, wn;
    if constexpr (BM == 128) { wm = w; wn = 0; } else { wm = w & 1; wn = w >> 1; }

    // precompute per-seg global source (pre-swizzled col) + linear LDS dest
    const u16* gsrc[SEGS];
    u16* ldst[SEGS];
    {
        int lr = L >> 2, lc = (L & 3) * 8;
#pragma unroll
        for (int i = 0; i < SEGS; i++) {
            int s = w * SEGS + i;
            const u16* gb; u16* lb; int r;
            if constexpr (BM == 128) {
                if (s < 8)       { gb = Ath + (size_t)m0 * K; lb = Ah; r = s * 16; }
                else if (s < 16) { gb = Atl + (size_t)m0 * K; lb = Al; r = (s - 8) * 16; }
                else if (s < 20) { gb = Bth + (size_t)n0 * K; lb = Bh; r = (s - 16) * 16; }
                else             { gb = Btl + (size_t)n0 * K; lb = Bl; r = (s - 20) * 16; }
            } else {
                if (s < 4)       { gb = Ath + (size_t)m0 * K; lb = Ah; r = s * 16; }
                else if (s < 8)  { gb = Atl + (size_t)m0 * K; lb = Al; r = (s - 4) * 16; }
                else if (s < 12) { gb = Bth + (size_t)n0 * K; lb = Bh; r = (s - 8) * 16; }
                else             { gb = Btl + (size_t)n0 * K; lb = Bl; r = (s - 12) * 16; }
            }
            int row = r + lr;
            int scol = lc ^ (((row >> 1) & 3) << 3);
            gsrc[i] = gb + (size_t)row * K + scol;
            ldst[i] = lb + r * 32;
        }
    }

    f32x4 acc[2][NI];
#pragma unroll
    for (int i = 0; i < 2; i++)
#pragma unroll
        for (int j = 0; j < NI; j++) acc[i][j] = (f32x4){0.0f, 0.0f, 0.0f, 0.0f};

    for (int k0 = 0; k0 < K; k0 += 32) {
        __syncthreads();
#pragma unroll
        for (int i = 0; i < SEGS; i++) gl16(gsrc[i] + k0, ldst[i]);
        __syncthreads();   // drains vmcnt -> LDS tiles complete
        s16x8 ah[2], al[2];
#pragma unroll
        for (int mi = 0; mi < 2; mi++) {
            int row = wm * 32 + mi * 16 + fr;
            ah[mi] = *reinterpret_cast<s16x8*>(&Ah[sw32(row, quad * 8)]);
            al[mi] = *reinterpret_cast<s16x8*>(&Al[sw32(row, quad * 8)]);
        }
#pragma unroll
        for (int ni = 0; ni < NI; ni++) {
            int rn = wn * 32 + ni * 16 + fr;
            s16x8 bhf = *reinterpret_cast<s16x8*>(&Bh[sw32(rn, quad * 8)]);
            s16x8 blf = *reinterpret_cast<s16x8*>(&Bl[sw32(rn, quad * 8)]);
#pragma unroll
            for (int mi = 0; mi < 2; mi++) {
                acc[mi][ni] = __builtin_amdgcn_mfma_f32_16x16x32_bf16(ah[mi], bhf, acc[mi][ni], 0, 0, 0);
                acc[mi][ni] = __builtin_amdgcn_mfma_f32_16x16x32_bf16(ah[mi], blf, acc[mi][ni], 0, 0, 0);
                acc[mi][ni] = __builtin_amdgcn_mfma_f32_16x16x32_bf16(al[mi], bhf, acc[mi][ni], 0, 0, 0);
            }
        }
    }
#pragma unroll
    for (int mi = 0; mi < 2; mi++) {
#pragma unroll
        for (int ni = 0; ni < NI; ni++) {
#pragma unroll
            for (int r = 0; r < 4; r++) {
                int row = m0 + wm * 32 + mi * 16 + quad * 4 + r;
                int col = n0 + wn * 32 + ni * 16 + fr;
                float v = acc[mi][ni][r];
                if (bias) v += bias[col];
                if (fuse_gelu) v = 0.5f * v * (1.0f + erff(v * 0.70710678118654752f));
                if (resid) v += resid[(size_t)row * N + col];
                size_t o = (size_t)row * N + col;
                if (Cf) Cf[o] = v;
                if (Ch) { u16 hh = f2bf(v); Ch[o] = hh; Cl[o] = f2bf(v - bf2f(hh)); }
            }
        }
    }
}

// ---------------- Attention v9: fused-QKV input, XOR-swizzled LDS, async K staging ----------------
// qkv row layout: [q(256) | k(256) | v(256)]; per head h the slice h*32..h*32+31 of each.
__global__ __launch_bounds__(256) void attn9(const u16* __restrict__ qkvh, const u16* __restrict__ qkvl,
                                             u16* __restrict__ aoh, u16* __restrict__ aol) {
    int bh = blockIdx.x, b = bh >> 3, h = bh & 7;
    int qt = blockIdx.y;
    int t = threadIdx.x, L = t & 63, w = t >> 6;
    int fr = L & 15, quad = L >> 4;
    __shared__ u16 QH[64 * 32], QL[64 * 32];       // sw32 layout
    __shared__ u16 KH[64 * 32], KL[64 * 32];
    __shared__ u16 VTH[32 * 64], VTL[32 * 64];     // V^T[d][kc], sw64 layout
    __shared__ u16 PH[4 * 16 * 64], PL[4 * 16 * 64];  // per-wave P tile, sw64 layout
    const float scale = 0.17677669529663687f;  // 1/sqrt(32)
    const int ROWS = 768;

    // K staging via gload_lds: 8 segs (KH 4, KL 4), 2 per wave, precomputed addresses
    const u16* ksrc[2];
    u16* kdst[2];
    {
        int lr = L >> 2, lc = (L & 3) * 8;
#pragma unroll
        for (int i = 0; i < 2; i++) {
            int s = w * 2 + i;
            const u16* gb = (s < 4) ? qkvh : qkvl;
            u16* lb = (s < 4) ? KH : KL;
            int r = (s & 3) * 16;
            int row = r + lr;
            int scol = lc ^ (((row >> 1) & 3) << 3);
            ksrc[i] = gb + ((size_t)(b * 1024) + row) * ROWS + 256 + h * 32 + scol;
            kdst[i] = lb + r * 32;
        }
    }

    {   // stage Q 64x32: thread -> row t>>2, dims (t&3)*8..+7 (u16x8 copies)
        int qr = t >> 2, d0 = (t & 3) * 8;
        size_t gq = (size_t)(b * 1024 + qt * 64 + qr) * ROWS + h * 32 + d0;
        *reinterpret_cast<u16x8*>(&QH[sw32(qr, d0)]) = *reinterpret_cast<const u16x8*>(qkvh + gq);
        *reinterpret_cast<u16x8*>(&QL[sw32(qr, d0)]) = *reinterpret_cast<const u16x8*>(qkvl + gq);
    }
    __syncthreads();
    s16x8 aqh = *reinterpret_cast<s16x8*>(&QH[sw32(w * 16 + fr, quad * 8)]);  // hoisted A-frags
    s16x8 aql = *reinterpret_cast<s16x8*>(&QL[sw32(w * 16 + fr, quad * 8)]);

    float m_i[4], l_i[4];
    f32x4 acc_o[2];
#pragma unroll
    for (int r = 0; r < 4; r++) { m_i[r] = -1e30f; l_i[r] = 0.0f; }
    acc_o[0] = (f32x4){0.0f, 0.0f, 0.0f, 0.0f};
    acc_o[1] = (f32x4){0.0f, 0.0f, 0.0f, 0.0f};

    for (int kt = 0; kt < 16; kt++) {
        __syncthreads();   // protect K/VT from prior-iteration readers
        {   // async K stage (2 x 1KB per wave)
            size_t koff = (size_t)kt * 64 * ROWS;
            gl16(ksrc[0] + koff, kdst[0]);
            gl16(ksrc[1] + koff, kdst[1]);
        }
        {   // stage V transposed: thread -> kc pair 2p,2p+1, dims (t&7)*4..+3 (pack-only)
            int vp = t >> 3, vd0 = (t & 7) * 4;
            size_t g0 = (size_t)(b * 1024 + kt * 64 + 2 * vp) * ROWS + 512 + h * 32 + vd0;
            u16x4 h0 = *reinterpret_cast<const u16x4*>(qkvh + g0);
            u16x4 h1 = *reinterpret_cast<const u16x4*>(qkvh + g0 + ROWS);
            u16x4 l0 = *reinterpret_cast<const u16x4*>(qkvl + g0);
            u16x4 l1 = *reinterpret_cast<const u16x4*>(qkvl + g0 + ROWS);
#pragma unroll
            for (int i = 0; i < 4; i++) {
                int d = vd0 + i;
                int idx = sw64(d, 2 * vp);
                *reinterpret_cast<u32*>(&VTH[idx]) = (u32)h0[i] | ((u32)h1[i] << 16);
                *reinterpret_cast<u32*>(&VTL[idx]) = (u32)l0[i] | ((u32)l1[i] << 16);
            }
        }
        __syncthreads();
        // S = Q K^T : 4 n-subtiles, bf16x2 (3 MFMA each)
        f32x4 s[4];
#pragma unroll
        for (int ni = 0; ni < 4; ni++) {
            s16x8 bkh = *reinterpret_cast<s16x8*>(&KH[sw32(ni * 16 + fr, quad * 8)]);
            s16x8 bkl = *reinterpret_cast<s16x8*>(&KL[sw32(ni * 16 + fr, quad * 8)]);
            f32x4 c = (f32x4){0.0f, 0.0f, 0.0f, 0.0f};
            c = __builtin_amdgcn_mfma_f32_16x16x32_bf16(aqh, bkh, c, 0, 0, 0);
            c = __builtin_amdgcn_mfma_f32_16x16x32_bf16(aqh, bkl, c, 0, 0, 0);
            c = __builtin_amdgcn_mfma_f32_16x16x32_bf16(aql, bkh, c, 0, 0, 0);
            s[ni] = c;
        }
        // online softmax: lane owns rows quad*4+r, cols ni*16+fr; row spans 16 lanes (same quad)
        float alpha[4];
#pragma unroll
        for (int r = 0; r < 4; r++) {
            float s0 = s[0][r] * scale, s1 = s[1][r] * scale;
            float s2 = s[2][r] * scale, s3 = s[3][r] * scale;
            float ml = fmaxf(fmaxf(s0, s1), fmaxf(s2, s3));
            for (int off = 1; off < 16; off <<= 1) ml = fmaxf(ml, __shfl_xor(ml, off));
            float mnew = fmaxf(m_i[r], ml);
            alpha[r] = __expf(m_i[r] - mnew);
            m_i[r] = mnew;
            float p0 = __expf(s0 - mnew), p1 = __expf(s1 - mnew);
            float p2 = __expf(s2 - mnew), p3 = __expf(s3 - mnew);
            float rs = p0 + p1 + p2 + p3;
            for (int off = 1; off < 16; off <<= 1) rs += __shfl_xor(rs, off);
            l_i[r] = l_i[r] * alpha[r] + rs;
            int row = quad * 4 + r;
            float ps[4] = {p0, p1, p2, p3};
#pragma unroll
            for (int ni = 0; ni < 4; ni++) {
                u16 ph = f2bf(ps[ni]);
                int idx = w * 1024 + sw64(row, ni * 16 + fr);
                PH[idx] = ph;
                PL[idx] = f2bf(ps[ni] - bf2f(ph));
            }
        }
        acc_o[0][0] *= alpha[0]; acc_o[0][1] *= alpha[1]; acc_o[0][2] *= alpha[2]; acc_o[0][3] *= alpha[3];
        acc_o[1][0] *= alpha[0]; acc_o[1][1] *= alpha[1]; acc_o[1][2] *= alpha[2]; acc_o[1][3] *= alpha[3];
        // PV: O += P V ; P wave-private (same-wave LDS write->read ordering)
#pragma unroll
        for (int ks = 0; ks < 2; ks++) {
            s16x8 aph = *reinterpret_cast<s16x8*>(&PH[w * 1024 + sw64(fr, ks * 32 + quad * 8)]);
            s16x8 apl = *reinterpret_cast<s16x8*>(&PL[w * 1024 + sw64(fr, ks * 32 + quad * 8)]);
#pragma unroll
            for (int ns = 0; ns < 2; ns++) {
                s16x8 bvh = *reinterpret_cast<s16x8*>(&VTH[sw64(ns * 16 + fr, ks * 32 + quad * 8)]);
                s16x8 bvl = *reinterpret_cast<s16x8*>(&VTL[sw64(ns * 16 + fr, ks * 32 + quad * 8)]);
                acc_o[ns] = __builtin_amdgcn_mfma_f32_16x16x32_bf16(aph, bvh, acc_o[ns], 0, 0, 0);
                acc_o[ns] = __builtin_amdgcn_mfma_f32_16x16x32_bf16(aph, bvl, acc_o[ns], 0, 0, 0);
                acc_o[ns] = __builtin_amdgcn_mfma_f32_16x16x32_bf16(apl, bvh, acc_o[ns], 0, 0, 0);
            }
        }
    }
    // write O as bf16 h/l (row stride DMODEL): row = quad*4+r of wave tile, col = ns*16+fr
#pragma unroll
    for (int r = 0; r < 4; r++) {
        float invl = 1.0f / l_i[r];
        size_t rowbase = ((size_t)(b * 1024 + qt * 64 + w * 16 + quad * 4 + r)) * DMODEL + h * 32;
        float v0 = acc_o[0][r] * invl, v1 = acc_o[1][r] * invl;
        u16 h0 = f2bf(v0); aoh[rowbase + fr] = h0;      aol[rowbase + fr] = f2bf(v0 - bf2f(h0));
        u16 h1 = f2bf(v1); aoh[rowbase + 16 + fr] = h1; aol[rowbase + 16 + fr] = f2bf(v1 - bf2f(h1));
    }
}

// ---------------- K-means v3: fused dist+argmin (256 blocks), chunked atomic-free segsum ---------
__global__ __launch_bounds__(64) void csq_k(const float* __restrict__ centers, float* __restrict__ csq) {
    int j = blockIdx.x, l = threadIdx.x;
    float4 c4 = *reinterpret_cast<const float4*>(centers + j * DMODEL + l * 4);
    float s = c4.x * c4.x + c4.y * c4.y + c4.z * c4.z + c4.w * c4.w;
    for (int off = 1; off < 64; off <<= 1) s += __shfl_xor(s, off);
    if (l == 0) csq[j] = s;
}

// 32 rows x 64 clusters per block; grid 256. Same fp32 dot order as the proven km_dist.
__global__ __launch_bounds__(256) void km_distmin(const float* __restrict__ A, const float* __restrict__ Cn,
                                                  const float* __restrict__ csq, int* __restrict__ labels) {
    __shared__ float As[16][34];
    __shared__ float Bs[16][64];
    int t = threadIdx.x, tx = t & 15, ty = t >> 4;
    int m0 = blockIdx.x * 32;
    int mr = t & 31, kq = (t >> 5) * 2;
    int jb = t & 63, kb = (t >> 6) * 4;
    float acc[2][4] = {};
    for (int k0 = 0; k0 < 256; k0 += 16) {
        __syncthreads();
        {
            float2 a2 = *reinterpret_cast<const float2*>(A + (size_t)(m0 + mr) * DMODEL + k0 + kq);
            As[kq][mr] = a2.x; As[kq + 1][mr] = a2.y;
        }
        {
            float4 c4 = *reinterpret_cast<const float4*>(Cn + (size_t)jb * DMODEL + k0 + kb);
            Bs[kb][jb] = c4.x; Bs[kb + 1][jb] = c4.y; Bs[kb + 2][jb] = c4.z; Bs[kb + 3][jb] = c4.w;
        }
        __syncthreads();
#pragma unroll
        for (int kk = 0; kk < 16; kk++) {
            float2 a2v = *reinterpret_cast<float2*>(&As[kk][ty * 2]);
            float4 b4 = *reinterpret_cast<float4*>(&Bs[kk][tx * 4]);
            float a[2] = {a2v.x, a2v.y};
            float bf[4] = {b4.x, b4.y, b4.z, b4.w};
#pragma unroll
            for (int i = 0; i < 2; i++)
#pragma unroll
                for (int j = 0; j < 4; j++) acc[i][j] += a[i] * bf[j];
        }
    }
    float4 cs4 = *reinterpret_cast<const float4*>(csq + tx * 4);
    float csv[4] = {cs4.x, cs4.y, cs4.z, cs4.w};
#pragma unroll
    for (int i = 0; i < 2; i++) {
        float best = csv[0] - 2.0f * acc[i][0]; int bi = tx * 4;
#pragma unroll
        for (int j = 1; j < 4; j++) {
            float v = csv[j] - 2.0f * acc[i][j];
            if (v < best) { best = v; bi = tx * 4 + j; }
        }
        for (int off = 1; off < 16; off <<= 1) {
            float ov = __shfl_xor(best, off);
            int oi = __shfl_xor(bi, off);
            if (ov < best || (ov == best && oi < bi)) { best = ov; bi = oi; }
        }
        if (tx == 0) labels[m0 + ty * 2 + i] = bi;
    }
}

// block (c, j): scan chunk c's 1024 labels, accumulate rows with lab==j. Uniform branch, no atomics.
__global__ __launch_bounds__(256) void km_segsum(const int* __restrict__ labels, const float* __restrict__ xf,
                                                 float* __restrict__ sums8, float* __restrict__ counts8) {
    int c = blockIdx.x, j = blockIdx.y, t = threadIdx.x;
    __shared__ int labs[1024];
    {
        int4 l4 = *reinterpret_cast<const int4*>(labels + c * 1024 + t * 4);
        labs[t * 4] = l4.x; labs[t * 4 + 1] = l4.y; labs[t * 4 + 2] = l4.z; labs[t * 4 + 3] = l4.w;
    }
    __syncthreads();
    float acc = 0.0f, cnt = 0.0f;
    const float* xb = xf + (size_t)c * 1024 * DMODEL;
    for (int i = 0; i < 1024; i++) {
        if (labs[i] == j) { acc += xb[(size_t)i * DMODEL + t]; cnt += 1.0f; }
    }
    sums8[((size_t)c * NCLUST + j) * DMODEL + t] = acc;
    if (t == 0) counts8[c * NCLUST + j] = cnt;
}

__global__ __launch_bounds__(256) void km_update(float* __restrict__ centers, const float* __restrict__ sums8,
                                                 const float* __restrict__ counts8, float* __restrict__ csq) {
    __shared__ float red[256];
    int j = blockIdx.x, d = threadIdx.x;
    float c = 0.0f;
#pragma unroll
    for (int cc = 0; cc < 8; cc++) c += counts8[cc * NCLUST + j];
    float sv = 0.0f;
#pragma unroll
    for (int cc = 0; cc < 8; cc++) sv += sums8[((size_t)cc * NCLUST + j) * DMODEL + d];
    float cv = centers[j * DMODEL + d];
    if (c > 0.0f) cv = sv / fmaxf(c, 1.0f);
    centers[j * DMODEL + d] = cv;
    red[d] = cv * cv;
    __syncthreads();
    for (int off = 128; off; off >>= 1) { if (d < off) red[d] += red[d + off]; __syncthreads(); }
    if (d == 0) csq[j] = red[0];
}

__global__ __launch_bounds__(256) void nproj(const float* __restrict__ centers, const float* __restrict__ kW,
                                             const float* __restrict__ kb2, float* __restrict__ outc) {
    int idx = blockIdx.x * 256 + threadIdx.x;
    if (idx >= NCLUST * DMODEL) return;
    int row = idx >> 8, col = idx & 255;
    const float* cr = centers + row * DMODEL;
    float acc = 0.0f;
    for (int d = 0; d < DMODEL; d++) acc += cr[d] * kW[(size_t)d * DMODEL + col];
    outc[idx] = acc + kb2[col];
}

__global__ __launch_bounds__(256) void km_gather(const int* __restrict__ labels, const float* __restrict__ outc,
                                                 float* __restrict__ out) {
    int i = blockIdx.x, t = threadIdx.x;
    int lab = labels[i];
    out[(size_t)i * DMODEL + t] = outc[lab * DMODEL + t];
}

extern "C" void kernel_launch(void* const* d_in, const int* in_sizes, int n_in,
                              void* d_out, int out_size, void* d_ws, size_t ws_size,
                              hipStream_t stream) {
    const float* x_in  = (const float*)d_in[0];
    const float* ln1_g = (const float*)d_in[1];
    const float* ln1_b = (const float*)d_in[2];
    const float* Wq    = (const float*)d_in[3];
    const float* Wkv   = (const float*)d_in[4];
    const float* Wo    = (const float*)d_in[5];
    const float* bo    = (const float*)d_in[6];
    const float* ln2_g = (const float*)d_in[7];
    const float* ln2_b = (const float*)d_in[8];
    const float* W1    = (const float*)d_in[9];
    const float* b1    = (const float*)d_in[10];
    const float* W2    = (const float*)d_in[11];
    const float* b2    = (const float*)d_in[12];
    const float* kWp   = (const float*)d_in[13];
    const float* kbp   = (const float*)d_in[14];
    float* out = (float*)d_out;

    const size_t NEEDED = 53477376;
    if (ws_size < NEEDED) {
        hipMemsetAsync(d_out, 0, (size_t)out_size * sizeof(float), stream);
        return;   // signature: absmax ~0.707 => workspace too small
    }

    char* ws = (char*)d_ws;
    float* xf      = (float*)(ws);                 // 8 MB fp32 residual stream
    u16*   xnh     = (u16*)  (ws + 8388608);       // 4 MB  ln out h
    u16*   xnl     = (u16*)  (ws + 12582912);      // 4 MB  ln out l
    u16*   aoh     = xnh;                          // attn out aliases xn (xn dead after QKV gemm)
    u16*   aol     = xnl;
    u16*   qkvh    = (u16*)  (ws + 16777216);      // 12 MB (8192x768 u16) -> ends 29360128
    u16*   qkvl    = (u16*)  (ws + 29360128);      // 12 MB -> ends 41943040
    u16*   hbh     = (u16*)  (ws + 16777216);      // 16 MB (qkv dead during FFN)
    u16*   hbl     = (u16*)  (ws + 33554432);      // 16 MB -> ends 50331648
    float* centers = (float*)(ws + 41943040);      // 64 KB
    float* csqb    = (float*)(ws + 42008576);      // 256 B
    float* counts8 = (float*)(ws + 42008832);      // 2 KB
    int*   labels  = (int*)  (ws + 42010880);      // 32 KB
    float* outc    = (float*)(ws + 42043648);      // 64 KB
    float* sums8   = (float*)(ws + 42109184);      // 512 KB -> ends 42633472
    u16*   wr      = (u16*)  (ws + 50331648);
    u16 *wqkvh = wr,          *wqkvl = wr + 196608;   // 768x256 each
    u16 *woh = wr + 393216,   *wol = wr + 458752;
    u16 *w1h = wr + 524288,   *w1l = wr + 786432;
    u16 *w2h = wr + 1048576,  *w2l = wr + 1310720;

    hipMemcpyAsync(xf, x_in, (size_t)BN * DMODEL * sizeof(float), hipMemcpyDeviceToDevice, stream);

    for (int l = 0; l < 4; l++) {
        wconv_all<<<192, 256, 0, stream>>>(Wq + (size_t)l * 65536, Wkv + (size_t)l * 131072,
                                           Wo + (size_t)l * 65536, W1 + (size_t)l * 262144,
                                           W2 + (size_t)l * 262144,
                                           wqkvh, wqkvl, woh, wol, w1h, w1l, w2h, w2l);

        ln_wave<<<BN / 4, 256, 0, stream>>>(xf, ln1_g + l * 256, ln1_b + l * 256, xnh, xnl);
        gemm_t<128, 4><<<dim3(12, 64), 256, 0, stream>>>(xnh, xnl, wqkvh, wqkvl, nullptr, nullptr,
                                                         nullptr, qkvh, qkvl, BN, 768, 256, 0);
        attn9<<<dim3(64, 16), 256, 0, stream>>>(qkvh, qkvl, aoh, aol);
        gemm_t<64, 2><<<dim3(4, 128), 256, 0, stream>>>(aoh, aol, woh, wol, bo + l * 256, xf,
                                                        xf, nullptr, nullptr, BN, 256, 256, 0);
        ln_wave<<<BN / 4, 256, 0, stream>>>(xf, ln2_g + l * 256, ln2_b + l * 256, xnh, xnl);
        gemm_t<128, 4><<<dim3(16, 64), 256, 0, stream>>>(xnh, xnl, w1h, w1l, b1 + l * 1024, nullptr,
                                                         nullptr, hbh, hbl, BN, 1024, 256, 1);
        gemm_t<64, 2><<<dim3(4, 128), 256, 0, stream>>>(hbh, hbl, w2h, w2l, b2 + l * 256, xf,
                                                        xf, nullptr, nullptr, BN, 256, 1024, 0);
    }

    hipMemcpyAsync(centers, xf, NCLUST * DMODEL * sizeof(float), hipMemcpyDeviceToDevice, stream);
    csq_k<<<64, 64, 0, stream>>>(centers, csqb);
    for (int it = 0; it < 10; it++) {
        km_distmin<<<256, 256, 0, stream>>>(xf, centers, csqb, labels);
        km_segsum<<<dim3(8, NCLUST), 256, 0, stream>>>(labels, xf, sums8, counts8);
        km_update<<<64, 256, 0, stream>>>(centers, sums8, counts8, csqb);
    }
    km_distmin<<<256, 256, 0, stream>>>(xf, centers, csqb, labels);
    nproj<<<64, 256, 0, stream>>>(centers, kWp, kbp, outc);
    km_gather<<<BN, 256, 0, stream>>>(labels, outc, out);
}

// Round 4
// 1393.559 us; speedup vs baseline: 1.4068x; 1.1467x over previous
//
#include <hip/hip_runtime.h>
#include <hip/hip_bf16.h>
#include <math.h>

// Problem constants (B=8, N=1024, D=256, L=4, M=1024, H=8, dh=32, K=64 clusters)
#define BN 8192           // B*N rows
#define DMODEL 256
#define FFN 1024
#define NCLUST 64

typedef unsigned short u16;
typedef unsigned int u32;
typedef __attribute__((ext_vector_type(8))) short s16x8;      // 8 bf16 (4 VGPRs) MFMA frag
typedef __attribute__((ext_vector_type(8))) unsigned short u16x8;
typedef __attribute__((ext_vector_type(4))) unsigned short u16x4;
typedef __attribute__((ext_vector_type(4))) float f32x4;

__device__ __forceinline__ float bf2f(u16 v) {
    union { unsigned int u; float f; } w; w.u = ((unsigned int)v) << 16; return w.f;
}
__device__ __forceinline__ u16 f2bf(float f) {
    union { float f; unsigned int u; } w; w.f = f;
    unsigned int r = w.u + 0x7fffu + ((w.u >> 16) & 1u);
    return (u16)(r >> 16);
}

// async global->LDS, 16B per lane. LDS dest = wave-uniform base + lane*16 (linear);
// swizzled layouts are achieved by pre-swizzling the per-lane GLOBAL source column.
__device__ __forceinline__ void gl16(const u16* g, u16* l) {
    __builtin_amdgcn_global_load_lds((const __attribute__((address_space(1))) u32*)g,
                                     (__attribute__((address_space(3))) u32*)l, 16, 0, 0);
}

// barrier that does NOT drain vmcnt: LDS-visibility only. In-flight global loads
// (register-dest) survive; compiler still auto-waits vmcnt before each USE.
#define BARRIER_LGKM() asm volatile("s_waitcnt lgkmcnt(0)\n\ts_barrier" ::: "memory")

// XOR-swizzled LDS index helpers (u16 units).
__device__ __forceinline__ int sw32(int row, int col) { return row * 32 + (col ^ (((row >> 1) & 3) << 3)); }
__device__ __forceinline__ int sw64(int row, int col) { return row * 64 + (col ^ ((row & 7) << 3)); }

// ---------------- LayerNorm: one wave per row, float4 + shuffle reduce; emits bf16 h/l ----------------
__global__ __launch_bounds__(256) void ln_wave(const float* __restrict__ x, const float* __restrict__ g,
                                               const float* __restrict__ b, u16* __restrict__ yh,
                                               u16* __restrict__ yl) {
    int t = threadIdx.x, w = t >> 6, l = t & 63;
    int row = blockIdx.x * 4 + w;
    const float* xr = x + (size_t)row * DMODEL;
    float4 v = *reinterpret_cast<const float4*>(xr + l * 4);
    float s = v.x + v.y + v.z + v.w;
    for (int off = 1; off < 64; off <<= 1) s += __shfl_xor(s, off);
    float mean = s * (1.0f / 256.0f);
    float4 dv = make_float4(v.x - mean, v.y - mean, v.z - mean, v.w - mean);
    float vs = dv.x * dv.x + dv.y * dv.y + dv.z * dv.z + dv.w * dv.w;
    for (int off = 1; off < 64; off <<= 1) vs += __shfl_xor(vs, off);
    float rs = rsqrtf(vs * (1.0f / 256.0f) + 1e-5f);
    float4 gg = *reinterpret_cast<const float4*>(g + l * 4);
    float4 bb = *reinterpret_cast<const float4*>(b + l * 4);
    float os[4] = {dv.x * rs * gg.x + bb.x, dv.y * rs * gg.y + bb.y,
                   dv.z * rs * gg.z + bb.z, dv.w * rs * gg.w + bb.w};
    u16x4 hv, lv;
#pragma unroll
    for (int j = 0; j < 4; j++) { u16 hh = f2bf(os[j]); hv[j] = hh; lv[j] = f2bf(os[j] - bf2f(hh)); }
    size_t o = (size_t)row * DMODEL + l * 4;
    *reinterpret_cast<u16x4*>(yh + o) = hv;
    *reinterpret_cast<u16x4*>(yl + o) = lv;
}

// ---------------- Weight convert: one fused launch per layer (5 weights, 192 blocks) --------------
__device__ __forceinline__ void wconv_body(const float* __restrict__ W, u16* __restrict__ th,
                                           u16* __restrict__ tl, int K, int N, int bx, int by) {
    __shared__ float T[64][65];
    int k0 = by * 64, n0 = bx * 64;
    int t = threadIdx.x;
    int r = t >> 4, c4 = (t & 15) * 4;
#pragma unroll
    for (int i = 0; i < 4; i++) {
        float4 x = *reinterpret_cast<const float4*>(W + (size_t)(k0 + r + 16 * i) * N + n0 + c4);
        T[r + 16 * i][c4] = x.x; T[r + 16 * i][c4 + 1] = x.y;
        T[r + 16 * i][c4 + 2] = x.z; T[r + 16 * i][c4 + 3] = x.w;
    }
    __syncthreads();
#pragma unroll
    for (int i = 0; i < 4; i++) {
        int n = r + 16 * i;
        u16x4 h4, l4;
#pragma unroll
        for (int j = 0; j < 4; j++) {
            float v = T[c4 + j][n];
            u16 h = f2bf(v);
            h4[j] = h; l4[j] = f2bf(v - bf2f(h));
        }
        *reinterpret_cast<u16x4*>(th + (size_t)(n0 + n) * K + k0 + c4) = h4;
        *reinterpret_cast<u16x4*>(tl + (size_t)(n0 + n) * K + k0 + c4) = l4;
    }
}

__global__ __launch_bounds__(256) void wconv_all(const float* __restrict__ Wq, const float* __restrict__ Wkv,
                                                 const float* __restrict__ Wo, const float* __restrict__ W1,
                                                 const float* __restrict__ W2,
                                                 u16* __restrict__ wqkvh, u16* __restrict__ wqkvl,
                                                 u16* __restrict__ woh, u16* __restrict__ wol,
                                                 u16* __restrict__ w1h, u16* __restrict__ w1l,
                                                 u16* __restrict__ w2h, u16* __restrict__ w2l) {
    int f = blockIdx.x;
    if (f < 16)       wconv_body(Wq,  wqkvh,               wqkvl,               256, 256,  f & 3,  f >> 2);
    else if (f < 48)  { int g = f - 16;  wconv_body(Wkv, wqkvh + 65536,       wqkvl + 65536,       256, 512,  g & 7,  g >> 3); }
    else if (f < 64)  { int g = f - 48;  wconv_body(Wo,  woh,                 wol,                 256, 256,  g & 3,  g >> 2); }
    else if (f < 128) { int g = f - 64;  wconv_body(W1,  w1h,                 w1l,                 256, 1024, g & 15, g >> 4); }
    else              { int g = f - 128; wconv_body(W2,  w2h,                 w2l,                 1024, 256, g & 3,  g >> 2); }
}

// ---------------- MFMA GEMM (bf16x2): 2-phase double-buffered global_load_lds staging -------------
// T3-minimum schedule: STAGE(buf^1, t+1) issued BEFORE compute(buf), one barrier per K-step.
template<int BM, int NI>
__global__ __launch_bounds__(256) void gemm_t(const u16* __restrict__ Ath, const u16* __restrict__ Atl,
                                              const u16* __restrict__ Bth, const u16* __restrict__ Btl,
                                              const float* __restrict__ bias, const float* __restrict__ resid,
                                              float* __restrict__ Cf, u16* __restrict__ Ch, u16* __restrict__ Cl,
                                              int M, int N, int K, int fuse_gelu) {
    __shared__ u16 Ah[2][BM * 32], Al[2][BM * 32];
    __shared__ u16 Bh[2][64 * 32], Bl[2][64 * 32];
    constexpr int SEGS = (BM == 128) ? 6 : 4;   // 1KB segments per wave per K-step
    int t = threadIdx.x;
    int m0 = blockIdx.y * BM, n0 = blockIdx.x * 64;
    int L = t & 63, w = t >> 6, fr = L & 15, quad = L >> 4;
    int wm, wn;
    if constexpr (BM == 128) { wm = w; wn = 0; } else { wm = w & 1; wn = w >> 1; }

    // per-seg global source (pre-swizzled col) + buf0 LDS dest + buf1 element delta
    const u16* gsrc[SEGS];
    u16* ldst[SEGS];
    u32 dlt[SEGS];
    {
        int lr = L >> 2, lc = (L & 3) * 8;
#pragma unroll
        for (int i = 0; i < SEGS; i++) {
            int s = w * SEGS + i;
            const u16* gb; u16* lb; int r; u32 d;
            if constexpr (BM == 128) {
                if (s < 8)       { gb = Ath + (size_t)m0 * K; lb = &Ah[0][0]; r = s * 16;        d = BM * 32; }
                else if (s < 16) { gb = Atl + (size_t)m0 * K; lb = &Al[0][0]; r = (s - 8) * 16;  d = BM * 32; }
                else if (s < 20) { gb = Bth + (size_t)n0 * K; lb = &Bh[0][0]; r = (s - 16) * 16; d = 64 * 32; }
                else             { gb = Btl + (size_t)n0 * K; lb = &Bl[0][0]; r = (s - 20) * 16; d = 64 * 32; }
            } else {
                if (s < 4)       { gb = Ath + (size_t)m0 * K; lb = &Ah[0][0]; r = s * 16;        d = BM * 32; }
                else if (s < 8)  { gb = Atl + (size_t)m0 * K; lb = &Al[0][0]; r = (s - 4) * 16;  d = BM * 32; }
                else if (s < 12) { gb = Bth + (size_t)n0 * K; lb = &Bh[0][0]; r = (s - 8) * 16;  d = 64 * 32; }
                else             { gb = Btl + (size_t)n0 * K; lb = &Bl[0][0]; r = (s - 12) * 16; d = 64 * 32; }
            }
            int row = r + lr;
            int scol = lc ^ (((row >> 1) & 3) << 3);
            gsrc[i] = gb + (size_t)row * K + scol;
            ldst[i] = lb + r * 32;
            dlt[i] = d;
        }
    }

    f32x4 acc[2][NI];
#pragma unroll
    for (int i = 0; i < 2; i++)
#pragma unroll
        for (int j = 0; j < NI; j++) acc[i][j] = (f32x4){0.0f, 0.0f, 0.0f, 0.0f};

    const int NT = K >> 5;
    // prologue: stage tile 0 into buf0
#pragma unroll
    for (int i = 0; i < SEGS; i++) gl16(gsrc[i], ldst[i]);
    __syncthreads();

    for (int tt = 0; tt < NT; tt++) {
        if (tt + 1 < NT) {           // issue next tile into other buffer (flies during MFMA)
            int k0n = (tt + 1) * 32;
            u32 sel = (u32)((tt + 1) & 1);
#pragma unroll
            for (int i = 0; i < SEGS; i++) gl16(gsrc[i] + k0n, ldst[i] + sel * dlt[i]);
        }
        int cb = tt & 1;
        const u16* AhB = &Ah[cb][0]; const u16* AlB = &Al[cb][0];
        const u16* BhB = &Bh[cb][0]; const u16* BlB = &Bl[cb][0];
        s16x8 ah[2], al[2];
#pragma unroll
        for (int mi = 0; mi < 2; mi++) {
            int row = wm * 32 + mi * 16 + fr;
            ah[mi] = *reinterpret_cast<const s16x8*>(&AhB[sw32(row, quad * 8)]);
            al[mi] = *reinterpret_cast<const s16x8*>(&AlB[sw32(row, quad * 8)]);
        }
#pragma unroll
        for (int ni = 0; ni < NI; ni++) {
            int rn = wn * 32 + ni * 16 + fr;
            s16x8 bhf = *reinterpret_cast<const s16x8*>(&BhB[sw32(rn, quad * 8)]);
            s16x8 blf = *reinterpret_cast<const s16x8*>(&BlB[sw32(rn, quad * 8)]);
#pragma unroll
            for (int mi = 0; mi < 2; mi++) {
                acc[mi][ni] = __builtin_amdgcn_mfma_f32_16x16x32_bf16(ah[mi], bhf, acc[mi][ni], 0, 0, 0);
                acc[mi][ni] = __builtin_amdgcn_mfma_f32_16x16x32_bf16(ah[mi], blf, acc[mi][ni], 0, 0, 0);
                acc[mi][ni] = __builtin_amdgcn_mfma_f32_16x16x32_bf16(al[mi], bhf, acc[mi][ni], 0, 0, 0);
            }
        }
        if (tt + 1 < NT) __syncthreads();   // drains prefetch (flew during compute) + sync swap
    }
#pragma unroll
    for (int mi = 0; mi < 2; mi++) {
#pragma unroll
        for (int ni = 0; ni < NI; ni++) {
#pragma unroll
            for (int r = 0; r < 4; r++) {
                int row = m0 + wm * 32 + mi * 16 + quad * 4 + r;
                int col = n0 + wn * 32 + ni * 16 + fr;
                float v = acc[mi][ni][r];
                if (bias) v += bias[col];
                if (fuse_gelu) v = 0.5f * v * (1.0f + erff(v * 0.70710678118654752f));
                if (resid) v += resid[(size_t)row * N + col];
                size_t o = (size_t)row * N + col;
                if (Cf) Cf[o] = v;
                if (Ch) { u16 hh = f2bf(v); Ch[o] = hh; Cl[o] = f2bf(v - bf2f(hh)); }
            }
        }
    }
}

// ---------------- Attention v10: Q/K direct-from-global (L1/L2-served), VT double-buffered --------
// 1 non-draining barrier per kt; K(kt+1)/V(kt+1) register prefetch survives the barrier.
// qkv row layout: [q(256) | k(256) | v(256)]; per head h the slice h*32..h*32+31 of each.
__global__ __launch_bounds__(256) void attn10(const u16* __restrict__ qkvh, const u16* __restrict__ qkvl,
                                              u16* __restrict__ aoh, u16* __restrict__ aol) {
    int bh = blockIdx.x, b = bh >> 3, h = bh & 7;
    int qt = blockIdx.y;
    int t = threadIdx.x, L = t & 63, w = t >> 6;
    int fr = L & 15, quad = L >> 4;
    __shared__ u16 VTH[2][32 * 64], VTL[2][32 * 64];     // V^T[d][kc], sw64 layout, dbuf
    __shared__ u16 PH[4 * 16 * 64], PL[4 * 16 * 64];     // per-wave P tile, sw64 layout
    const float scale = 0.17677669529663687f;  // 1/sqrt(32)
    const int ROWS = 768;

    // Q fragments: direct global load (same values LDS staging produced)
    size_t qoff = (size_t)(b * 1024 + qt * 64 + w * 16 + fr) * ROWS + h * 32 + quad * 8;
    s16x8 aqh = *reinterpret_cast<const s16x8*>(qkvh + qoff);
    s16x8 aql = *reinterpret_cast<const s16x8*>(qkvl + qoff);

    // K fragment base (row ni*16+fr of K-tile kt): + (kt*64 + ni*16)*ROWS
    const u16* kh_ptr = qkvh + (size_t)(b * 1024 + fr) * ROWS + 256 + h * 32 + quad * 8;
    const u16* kl_ptr = qkvl + (size_t)(b * 1024 + fr) * ROWS + 256 + h * 32 + quad * 8;
    // V loads: thread -> kc pair 2vp,2vp+1, dims vd0..+3
    int vp = t >> 3, vd0 = (t & 7) * 4;
    const u16* vh_ptr = qkvh + (size_t)(b * 1024 + 2 * vp) * ROWS + 512 + h * 32 + vd0;
    const u16* vl_ptr = qkvl + (size_t)(b * 1024 + 2 * vp) * ROWS + 512 + h * 32 + vd0;

    s16x8 kh[4], kl[4];
    u16x4 vh0, vh1, vl0, vl1;
#define LOADK(kt_) do { size_t o_ = (size_t)((kt_) * 64) * ROWS;                                  \
        kh[0] = *reinterpret_cast<const s16x8*>(kh_ptr + o_);                                     \
        kh[1] = *reinterpret_cast<const s16x8*>(kh_ptr + o_ + 16 * ROWS);                         \
        kh[2] = *reinterpret_cast<const s16x8*>(kh_ptr + o_ + 32 * ROWS);                         \
        kh[3] = *reinterpret_cast<const s16x8*>(kh_ptr + o_ + 48 * ROWS);                         \
        kl[0] = *reinterpret_cast<const s16x8*>(kl_ptr + o_);                                     \
        kl[1] = *reinterpret_cast<const s16x8*>(kl_ptr + o_ + 16 * ROWS);                         \
        kl[2] = *reinterpret_cast<const s16x8*>(kl_ptr + o_ + 32 * ROWS);                         \
        kl[3] = *reinterpret_cast<const s16x8*>(kl_ptr + o_ + 48 * ROWS); } while (0)
#define LOADV(kt_) do { size_t o_ = (size_t)((kt_) * 64) * ROWS;                                  \
        vh0 = *reinterpret_cast<const u16x4*>(vh_ptr + o_);                                       \
        vh1 = *reinterpret_cast<const u16x4*>(vh_ptr + o_ + ROWS);                                \
        vl0 = *reinterpret_cast<const u16x4*>(vl_ptr + o_);                                       \
        vl1 = *reinterpret_cast<const u16x4*>(vl_ptr + o_ + ROWS); } while (0)

    LOADV(0);
    LOADK(0);

    float m_i[4], l_i[4];
    f32x4 acc_o[2];
#pragma unroll
    for (int r = 0; r < 4; r++) { m_i[r] = -1e30f; l_i[r] = 0.0f; }
    acc_o[0] = (f32x4){0.0f, 0.0f, 0.0f, 0.0f};
    acc_o[1] = (f32x4){0.0f, 0.0f, 0.0f, 0.0f};

#pragma unroll 2
    for (int kt = 0; kt < 16; kt++) {
        int cur = kt & 1;
        u16* vth = &VTH[cur][0];
        u16* vtl = &VTL[cur][0];
        {   // VT write from prefetched regs (pack-only)
#pragma unroll
            for (int i = 0; i < 4; i++) {
                int idx = sw64(vd0 + i, 2 * vp);
                *reinterpret_cast<u32*>(&vth[idx]) = (u32)vh0[i] | ((u32)vh1[i] << 16);
                *reinterpret_cast<u32*>(&vtl[idx]) = (u32)vl0[i] | ((u32)vl1[i] << 16);
            }
        }
        BARRIER_LGKM();   // VT visible to all waves; in-flight prefetches NOT drained
        // S = Q K^T from register K-frags: 4 n-subtiles, bf16x2 (3 MFMA each)
        f32x4 s[4];
#pragma unroll
        for (int ni = 0; ni < 4; ni++) {
            f32x4 c = (f32x4){0.0f, 0.0f, 0.0f, 0.0f};
            c = __builtin_amdgcn_mfma_f32_16x16x32_bf16(aqh, kh[ni], c, 0, 0, 0);
            c = __builtin_amdgcn_mfma_f32_16x16x32_bf16(aqh, kl[ni], c, 0, 0, 0);
            c = __builtin_amdgcn_mfma_f32_16x16x32_bf16(aql, kh[ni], c, 0, 0, 0);
            s[ni] = c;
        }
        if (kt < 15) LOADK(kt + 1);   // K regs free after QK; loads fly through SM+PV+barrier
        // online softmax: lane owns rows quad*4+r, cols ni*16+fr
        float alpha[4];
#pragma unroll
        for (int r = 0; r < 4; r++) {
            float s0 = s[0][r] * scale, s1 = s[1][r] * scale;
            float s2 = s[2][r] * scale, s3 = s[3][r] * scale;
            float ml = fmaxf(fmaxf(s0, s1), fmaxf(s2, s3));
            for (int off = 1; off < 16; off <<= 1) ml = fmaxf(ml, __shfl_xor(ml, off));
            float mnew = fmaxf(m_i[r], ml);
            alpha[r] = __expf(m_i[r] - mnew);
            m_i[r] = mnew;
            float p0 = __expf(s0 - mnew), p1 = __expf(s1 - mnew);
            float p2 = __expf(s2 - mnew), p3 = __expf(s3 - mnew);
            float rs = p0 + p1 + p2 + p3;
            for (int off = 1; off < 16; off <<= 1) rs += __shfl_xor(rs, off);
            l_i[r] = l_i[r] * alpha[r] + rs;
            int row = quad * 4 + r;
            float ps[4] = {p0, p1, p2, p3};
#pragma unroll
            for (int ni = 0; ni < 4; ni++) {
                u16 ph = f2bf(ps[ni]);
                int idx = w * 1024 + sw64(row, ni * 16 + fr);
                PH[idx] = ph;
                PL[idx] = f2bf(ps[ni] - bf2f(ph));
            }
        }
        if (kt < 15) LOADV(kt + 1);   // V regs free after VT write
        acc_o[0][0] *= alpha[0]; acc_o[0][1] *= alpha[1]; acc_o[0][2] *= alpha[2]; acc_o[0][3] *= alpha[3];
        acc_o[1][0] *= alpha[0]; acc_o[1][1] *= alpha[1]; acc_o[1][2] *= alpha[2]; acc_o[1][3] *= alpha[3];
        // PV: O += P V ; P wave-private (same-wave LDS write->read ordering)
#pragma unroll
        for (int ks = 0; ks < 2; ks++) {
            s16x8 aph = *reinterpret_cast<s16x8*>(&PH[w * 1024 + sw64(fr, ks * 32 + quad * 8)]);
            s16x8 apl = *reinterpret_cast<s16x8*>(&PL[w * 1024 + sw64(fr, ks * 32 + quad * 8)]);
#pragma unroll
            for (int ns = 0; ns < 2; ns++) {
                s16x8 bvh = *reinterpret_cast<s16x8*>(&vth[sw64(ns * 16 + fr, ks * 32 + quad * 8)]);
                s16x8 bvl = *reinterpret_cast<s16x8*>(&vtl[sw64(ns * 16 + fr, ks * 32 + quad * 8)]);
                acc_o[ns] = __builtin_amdgcn_mfma_f32_16x16x32_bf16(aph, bvh, acc_o[ns], 0, 0, 0);
                acc_o[ns] = __builtin_amdgcn_mfma_f32_16x16x32_bf16(aph, bvl, acc_o[ns], 0, 0, 0);
                acc_o[ns] = __builtin_amdgcn_mfma_f32_16x16x32_bf16(apl, bvh, acc_o[ns], 0, 0, 0);
            }
        }
    }
#undef LOADK
#undef LOADV
    // write O as bf16 h/l (row stride DMODEL): row = quad*4+r of wave tile, col = ns*16+fr
#pragma unroll
    for (int r = 0; r < 4; r++) {
        float invl = 1.0f / l_i[r];
        size_t rowbase = ((size_t)(b * 1024 + qt * 64 + w * 16 + quad * 4 + r)) * DMODEL + h * 32;
        float v0 = acc_o[0][r] * invl, v1 = acc_o[1][r] * invl;
        u16 h0 = f2bf(v0); aoh[rowbase + fr] = h0;      aol[rowbase + fr] = f2bf(v0 - bf2f(h0));
        u16 h1 = f2bf(v1); aoh[rowbase + 16 + fr] = h1; aol[rowbase + 16 + fr] = f2bf(v1 - bf2f(h1));
    }
}

// ---------------- K-means: fused dist+argmin (256 blocks), chunked atomic-free segsum ------------
__global__ __launch_bounds__(64) void csq_k(const float* __restrict__ centers, float* __restrict__ csq) {
    int j = blockIdx.x, l = threadIdx.x;
    float4 c4 = *reinterpret_cast<const float4*>(centers + j * DMODEL + l * 4);
    float s = c4.x * c4.x + c4.y * c4.y + c4.z * c4.z + c4.w * c4.w;
    for (int off = 1; off < 64; off <<= 1) s += __shfl_xor(s, off);
    if (l == 0) csq[j] = s;
}

__global__ __launch_bounds__(256) void km_distmin(const float* __restrict__ A, const float* __restrict__ Cn,
                                                  const float* __restrict__ csq, int* __restrict__ labels) {
    __shared__ float As[16][34];
    __shared__ float Bs[16][64];
    int t = threadIdx.x, tx = t & 15, ty = t >> 4;
    int m0 = blockIdx.x * 32;
    int mr = t & 31, kq = (t >> 5) * 2;
    int jb = t & 63, kb = (t >> 6) * 4;
    float acc[2][4] = {};
    for (int k0 = 0; k0 < 256; k0 += 16) {
        __syncthreads();
        {
            float2 a2 = *reinterpret_cast<const float2*>(A + (size_t)(m0 + mr) * DMODEL + k0 + kq);
            As[kq][mr] = a2.x; As[kq + 1][mr] = a2.y;
        }
        {
            float4 c4 = *reinterpret_cast<const float4*>(Cn + (size_t)jb * DMODEL + k0 + kb);
            Bs[kb][jb] = c4.x; Bs[kb + 1][jb] = c4.y; Bs[kb + 2][jb] = c4.z; Bs[kb + 3][jb] = c4.w;
        }
        __syncthreads();
#pragma unroll
        for (int kk = 0; kk < 16; kk++) {
            float2 a2v = *reinterpret_cast<float2*>(&As[kk][ty * 2]);
            float4 b4 = *reinterpret_cast<float4*>(&Bs[kk][tx * 4]);
            float a[2] = {a2v.x, a2v.y};
            float bf[4] = {b4.x, b4.y, b4.z, b4.w};
#pragma unroll
            for (int i = 0; i < 2; i++)
#pragma unroll
                for (int j = 0; j < 4; j++) acc[i][j] += a[i] * bf[j];
        }
    }
    float4 cs4 = *reinterpret_cast<const float4*>(csq + tx * 4);
    float csv[4] = {cs4.x, cs4.y, cs4.z, cs4.w};
#pragma unroll
    for (int i = 0; i < 2; i++) {
        float best = csv[0] - 2.0f * acc[i][0]; int bi = tx * 4;
#pragma unroll
        for (int j = 1; j < 4; j++) {
            float v = csv[j] - 2.0f * acc[i][j];
            if (v < best) { best = v; bi = tx * 4 + j; }
        }
        for (int off = 1; off < 16; off <<= 1) {
            float ov = __shfl_xor(best, off);
            int oi = __shfl_xor(bi, off);
            if (ov < best || (ov == best && oi < bi)) { best = ov; bi = oi; }
        }
        if (tx == 0) labels[m0 + ty * 2 + i] = bi;
    }
}

// block (c, j): scan chunk c's 512 labels, accumulate rows with lab==j. Uniform branch, no atomics.
__global__ __launch_bounds__(256) void km_segsum(const int* __restrict__ labels, const float* __restrict__ xf,
                                                 float* __restrict__ sums16, float* __restrict__ counts16) {
    int c = blockIdx.x, j = blockIdx.y, t = threadIdx.x;
    __shared__ int labs[512];
    if (t < 128) {
        int4 l4 = *reinterpret_cast<const int4*>(labels + c * 512 + t * 4);
        labs[t * 4] = l4.x; labs[t * 4 + 1] = l4.y; labs[t * 4 + 2] = l4.z; labs[t * 4 + 3] = l4.w;
    }
    __syncthreads();
    float acc = 0.0f, cnt = 0.0f;
    const float* xb = xf + (size_t)c * 512 * DMODEL;
    for (int i = 0; i < 512; i++) {
        if (labs[i] == j) { acc += xb[(size_t)i * DMODEL + t]; cnt += 1.0f; }
    }
    sums16[((size_t)c * NCLUST + j) * DMODEL + t] = acc;
    if (t == 0) counts16[c * NCLUST + j] = cnt;
}

__global__ __launch_bounds__(256) void km_update(float* __restrict__ centers, const float* __restrict__ sums16,
                                                 const float* __restrict__ counts16, float* __restrict__ csq) {
    __shared__ float red[256];
    int j = blockIdx.x, d = threadIdx.x;
    float c = 0.0f;
#pragma unroll
    for (int cc = 0; cc < 16; cc++) c += counts16[cc * NCLUST + j];
    float sv = 0.0f;
#pragma unroll
    for (int cc = 0; cc < 16; cc++) sv += sums16[((size_t)cc * NCLUST + j) * DMODEL + d];
    float cv = centers[j * DMODEL + d];
    if (c > 0.0f) cv = sv / fmaxf(c, 1.0f);
    centers[j * DMODEL + d] = cv;
    red[d] = cv * cv;
    __syncthreads();
    for (int off = 128; off; off >>= 1) { if (d < off) red[d] += red[d + off]; __syncthreads(); }
    if (d == 0) csq[j] = red[0];
}

__global__ __launch_bounds__(256) void nproj(const float* __restrict__ centers, const float* __restrict__ kW,
                                             const float* __restrict__ kb2, float* __restrict__ outc) {
    int idx = blockIdx.x * 256 + threadIdx.x;
    if (idx >= NCLUST * DMODEL) return;
    int row = idx >> 8, col = idx & 255;
    const float* cr = centers + row * DMODEL;
    float acc = 0.0f;
    for (int d = 0; d < DMODEL; d++) acc += cr[d] * kW[(size_t)d * DMODEL + col];
    outc[idx] = acc + kb2[col];
}

__global__ __launch_bounds__(256) void km_gather(const int* __restrict__ labels, const float* __restrict__ outc,
                                                 float* __restrict__ out) {
    int i = blockIdx.x, t = threadIdx.x;
    int lab = labels[i];
    out[(size_t)i * DMODEL + t] = outc[lab * DMODEL + t];
}

extern "C" void kernel_launch(void* const* d_in, const int* in_sizes, int n_in,
                              void* d_out, int out_size, void* d_ws, size_t ws_size,
                              hipStream_t stream) {
    const float* x_in  = (const float*)d_in[0];
    const float* ln1_g = (const float*)d_in[1];
    const float* ln1_b = (const float*)d_in[2];
    const float* Wq    = (const float*)d_in[3];
    const float* Wkv   = (const float*)d_in[4];
    const float* Wo    = (const float*)d_in[5];
    const float* bo    = (const float*)d_in[6];
    const float* ln2_g = (const float*)d_in[7];
    const float* ln2_b = (const float*)d_in[8];
    const float* W1    = (const float*)d_in[9];
    const float* b1    = (const float*)d_in[10];
    const float* W2    = (const float*)d_in[11];
    const float* b2    = (const float*)d_in[12];
    const float* kWp   = (const float*)d_in[13];
    const float* kbp   = (const float*)d_in[14];
    float* out = (float*)d_out;

    const size_t NEEDED = 53477376;
    if (ws_size < NEEDED) {
        hipMemsetAsync(d_out, 0, (size_t)out_size * sizeof(float), stream);
        return;   // signature: absmax ~0.707 => workspace too small
    }

    char* ws = (char*)d_ws;
    float* xf      = (float*)(ws);                 // 8 MB fp32 residual stream
    u16*   xnh     = (u16*)  (ws + 8388608);       // 4 MB  ln out h
    u16*   xnl     = (u16*)  (ws + 12582912);      // 4 MB  ln out l
    u16*   aoh     = xnh;                          // attn out aliases xn (xn dead after QKV gemm)
    u16*   aol     = xnl;
    u16*   qkvh    = (u16*)  (ws + 16777216);      // 12 MB (8192x768 u16) -> ends 29360128
    u16*   qkvl    = (u16*)  (ws + 29360128);      // 12 MB -> ends 41943040
    u16*   hbh     = (u16*)  (ws + 16777216);      // 16 MB (qkv dead during FFN)
    u16*   hbl     = (u16*)  (ws + 33554432);      // 16 MB -> ends 50331648
    float* centers = (float*)(ws + 41943040);      // 64 KB -> 42008576
    float* csqb    = (float*)(ws + 42008576);      // 256 B -> 42008832
    float* counts16= (float*)(ws + 42008832);      // 4 KB  -> 42012928
    int*   labels  = (int*)  (ws + 42012928);      // 32 KB -> 42045696
    float* outc    = (float*)(ws + 42045696);      // 64 KB -> 42111232
    float* sums16  = (float*)(ws + 42111232);      // 1 MB  -> 43159808
    u16*   wr      = (u16*)  (ws + 50331648);
    u16 *wqkvh = wr,          *wqkvl = wr + 196608;   // 768x256 each
    u16 *woh = wr + 393216,   *wol = wr + 458752;
    u16 *w1h = wr + 524288,   *w1l = wr + 786432;
    u16 *w2h = wr + 1048576,  *w2l = wr + 1310720;

    hipMemcpyAsync(xf, x_in, (size_t)BN * DMODEL * sizeof(float), hipMemcpyDeviceToDevice, stream);

    for (int l = 0; l < 4; l++) {
        wconv_all<<<192, 256, 0, stream>>>(Wq + (size_t)l * 65536, Wkv + (size_t)l * 131072,
                                           Wo + (size_t)l * 65536, W1 + (size_t)l * 262144,
                                           W2 + (size_t)l * 262144,
                                           wqkvh, wqkvl, woh, wol, w1h, w1l, w2h, w2l);

        ln_wave<<<BN / 4, 256, 0, stream>>>(xf, ln1_g + l * 256, ln1_b + l * 256, xnh, xnl);
        gemm_t<128, 4><<<dim3(12, 64), 256, 0, stream>>>(xnh, xnl, wqkvh, wqkvl, nullptr, nullptr,
                                                         nullptr, qkvh, qkvl, BN, 768, 256, 0);
        attn10<<<dim3(64, 16), 256, 0, stream>>>(qkvh, qkvl, aoh, aol);
        gemm_t<64, 2><<<dim3(4, 128), 256, 0, stream>>>(aoh, aol, woh, wol, bo + l * 256, xf,
                                                        xf, nullptr, nullptr, BN, 256, 256, 0);
        ln_wave<<<BN / 4, 256, 0, stream>>>(xf, ln2_g + l * 256, ln2_b + l * 256, xnh, xnl);
        gemm_t<128, 4><<<dim3(16, 64), 256, 0, stream>>>(xnh, xnl, w1h, w1l, b1 + l * 1024, nullptr,
                                                         nullptr, hbh, hbl, BN, 1024, 256, 1);
        gemm_t<64, 2><<<dim3(4, 128), 256, 0, stream>>>(hbh, hbl, w2h, w2l, b2 + l * 256, xf,
                                                        xf, nullptr, nullptr, BN, 256, 1024, 0);
    }

    hipMemcpyAsync(centers, xf, NCLUST * DMODEL * sizeof(float), hipMemcpyDeviceToDevice, stream);
    csq_k<<<64, 64, 0, stream>>>(centers, csqb);
    for (int it = 0; it < 10; it++) {
        km_distmin<<<256, 256, 0, stream>>>(xf, centers, csqb, labels);
        km_segsum<<<dim3(16, NCLUST), 256, 0, stream>>>(labels, xf, sums16, counts16);
        km_update<<<64, 256, 0, stream>>>(centers, sums16, counts16, csqb);
    }
    km_distmin<<<256, 256, 0, stream>>>(xf, centers, csqb, labels);
    nproj<<<64, 256, 0, stream>>>(centers, kWp, kbp, outc);
    km_gather<<<BN, 256, 0, stream>>>(labels, outc, out);
}

// Round 5
// 1385.525 us; speedup vs baseline: 1.4150x; 1.0058x over previous
//
#include <hip/hip_runtime.h>
#include <hip/hip_bf16.h>
#include <math.h>

// Problem constants (B=8, N=1024, D=256, L=4, M=1024, H=8, dh=32, K=64 clusters)
#define BN 8192           // B*N rows
#define DMODEL 256
#define FFN 1024
#define NCLUST 64

typedef unsigned short u16;
typedef unsigned int u32;
typedef __attribute__((ext_vector_type(8))) short s16x8;      // 8 bf16 (4 VGPRs) MFMA frag
typedef __attribute__((ext_vector_type(8))) unsigned short u16x8;
typedef __attribute__((ext_vector_type(4))) unsigned short u16x4;
typedef __attribute__((ext_vector_type(4))) float f32x4;

__device__ __forceinline__ float bf2f(u16 v) {
    union { unsigned int u; float f; } w; w.u = ((unsigned int)v) << 16; return w.f;
}
__device__ __forceinline__ u16 f2bf(float f) {
    union { float f; unsigned int u; } w; w.f = f;
    unsigned int r = w.u + 0x7fffu + ((w.u >> 16) & 1u);
    return (u16)(r >> 16);
}

// async global->LDS, 16B per lane. LDS dest = wave-uniform base + lane*16 (linear);
// swizzled layouts are achieved by pre-swizzling the per-lane GLOBAL source column.
__device__ __forceinline__ void gl16(const u16* g, u16* l) {
    __builtin_amdgcn_global_load_lds((const __attribute__((address_space(1))) u32*)g,
                                     (__attribute__((address_space(3))) u32*)l, 16, 0, 0);
}

// XOR-swizzled LDS index helpers (u16 units).
__device__ __forceinline__ int sw32(int row, int col) { return row * 32 + (col ^ (((row >> 1) & 3) << 3)); }
__device__ __forceinline__ int sw64(int row, int col) { return row * 64 + (col ^ ((row & 7) << 3)); }

// ---------------- LayerNorm: one wave per row, float4 + shuffle reduce; emits bf16 h/l ----------------
__global__ __launch_bounds__(256) void ln_wave(const float* __restrict__ x, const float* __restrict__ g,
                                               const float* __restrict__ b, u16* __restrict__ yh,
                                               u16* __restrict__ yl) {
    int t = threadIdx.x, w = t >> 6, l = t & 63;
    int row = blockIdx.x * 4 + w;
    const float* xr = x + (size_t)row * DMODEL;
    float4 v = *reinterpret_cast<const float4*>(xr + l * 4);
    float s = v.x + v.y + v.z + v.w;
    for (int off = 1; off < 64; off <<= 1) s += __shfl_xor(s, off);
    float mean = s * (1.0f / 256.0f);
    float4 dv = make_float4(v.x - mean, v.y - mean, v.z - mean, v.w - mean);
    float vs = dv.x * dv.x + dv.y * dv.y + dv.z * dv.z + dv.w * dv.w;
    for (int off = 1; off < 64; off <<= 1) vs += __shfl_xor(vs, off);
    float rs = rsqrtf(vs * (1.0f / 256.0f) + 1e-5f);
    float4 gg = *reinterpret_cast<const float4*>(g + l * 4);
    float4 bb = *reinterpret_cast<const float4*>(b + l * 4);
    float os[4] = {dv.x * rs * gg.x + bb.x, dv.y * rs * gg.y + bb.y,
                   dv.z * rs * gg.z + bb.z, dv.w * rs * gg.w + bb.w};
    u16x4 hv, lv;
#pragma unroll
    for (int j = 0; j < 4; j++) { u16 hh = f2bf(os[j]); hv[j] = hh; lv[j] = f2bf(os[j] - bf2f(hh)); }
    size_t o = (size_t)row * DMODEL + l * 4;
    *reinterpret_cast<u16x4*>(yh + o) = hv;
    *reinterpret_cast<u16x4*>(yl + o) = lv;
}

// ---------------- Weight convert: one fused launch per layer (5 weights, 192 blocks) --------------
__device__ __forceinline__ void wconv_body(const float* __restrict__ W, u16* __restrict__ th,
                                           u16* __restrict__ tl, int K, int N, int bx, int by) {
    __shared__ float T[64][65];
    int k0 = by * 64, n0 = bx * 64;
    int t = threadIdx.x;
    int r = t >> 4, c4 = (t & 15) * 4;
#pragma unroll
    for (int i = 0; i < 4; i++) {
        float4 x = *reinterpret_cast<const float4*>(W + (size_t)(k0 + r + 16 * i) * N + n0 + c4);
        T[r + 16 * i][c4] = x.x; T[r + 16 * i][c4 + 1] = x.y;
        T[r + 16 * i][c4 + 2] = x.z; T[r + 16 * i][c4 + 3] = x.w;
    }
    __syncthreads();
#pragma unroll
    for (int i = 0; i < 4; i++) {
        int n = r + 16 * i;
        u16x4 h4, l4;
#pragma unroll
        for (int j = 0; j < 4; j++) {
            float v = T[c4 + j][n];
            u16 h = f2bf(v);
            h4[j] = h; l4[j] = f2bf(v - bf2f(h));
        }
        *reinterpret_cast<u16x4*>(th + (size_t)(n0 + n) * K + k0 + c4) = h4;
        *reinterpret_cast<u16x4*>(tl + (size_t)(n0 + n) * K + k0 + c4) = l4;
    }
}

__global__ __launch_bounds__(256) void wconv_all(const float* __restrict__ Wq, const float* __restrict__ Wkv,
                                                 const float* __restrict__ Wo, const float* __restrict__ W1,
                                                 const float* __restrict__ W2,
                                                 u16* __restrict__ wqkvh, u16* __restrict__ wqkvl,
                                                 u16* __restrict__ woh, u16* __restrict__ wol,
                                                 u16* __restrict__ w1h, u16* __restrict__ w1l,
                                                 u16* __restrict__ w2h, u16* __restrict__ w2l) {
    int f = blockIdx.x;
    if (f < 16)       wconv_body(Wq,  wqkvh,               wqkvl,               256, 256,  f & 3,  f >> 2);
    else if (f < 48)  { int g = f - 16;  wconv_body(Wkv, wqkvh + 65536,       wqkvl + 65536,       256, 512,  g & 7,  g >> 3); }
    else if (f < 64)  { int g = f - 48;  wconv_body(Wo,  woh,                 wol,                 256, 256,  g & 3,  g >> 2); }
    else if (f < 128) { int g = f - 64;  wconv_body(W1,  w1h,                 w1l,                 256, 1024, g & 15, g >> 4); }
    else              { int g = f - 128; wconv_body(W2,  w2h,                 w2l,                 1024, 256, g & 3,  g >> 2); }
}

// ---------------- MFMA GEMM (bf16x2): dbuf gl16 staging, counted-vmcnt no-drain schedule ----------
// Per K-step: [lgkm+barrier A (buf^1 free)] [issue gl16 t+1 -> buf^1] [vmcnt(SEGS): tile t landed]
// [barrier B] [compute buf t]. Prefetch survives both barriers; vmcnt never drained mid-loop.
template<int BM, int NI>
__global__ __launch_bounds__(256) void gemm_t(const u16* __restrict__ Ath, const u16* __restrict__ Atl,
                                              const u16* __restrict__ Bth, const u16* __restrict__ Btl,
                                              const float* __restrict__ bias, const float* __restrict__ resid,
                                              float* __restrict__ Cf, u16* __restrict__ Ch, u16* __restrict__ Cl,
                                              int M, int N, int K, int fuse_gelu) {
    __shared__ u16 Ah[2][BM * 32], Al[2][BM * 32];
    __shared__ u16 Bh[2][64 * 32], Bl[2][64 * 32];
    constexpr int SEGS = (BM == 128) ? 6 : 4;   // 1KB segments per wave per K-step
    int t = threadIdx.x;
    int m0 = blockIdx.y * BM, n0 = blockIdx.x * 64;
    int L = t & 63, w = t >> 6, fr = L & 15, quad = L >> 4;
    int wm, wn;
    if constexpr (BM == 128) { wm = w; wn = 0; } else { wm = w & 1; wn = w >> 1; }

    // per-seg global source (pre-swizzled col) + buf0 LDS dest + buf1 element delta
    const u16* gsrc[SEGS];
    u16* ldst[SEGS];
    u32 dlt[SEGS];
    {
        int lr = L >> 2, lc = (L & 3) * 8;
#pragma unroll
        for (int i = 0; i < SEGS; i++) {
            int s = w * SEGS + i;
            const u16* gb; u16* lb; int r; u32 d;
            if constexpr (BM == 128) {
                if (s < 8)       { gb = Ath + (size_t)m0 * K; lb = &Ah[0][0]; r = s * 16;        d = BM * 32; }
                else if (s < 16) { gb = Atl + (size_t)m0 * K; lb = &Al[0][0]; r = (s - 8) * 16;  d = BM * 32; }
                else if (s < 20) { gb = Bth + (size_t)n0 * K; lb = &Bh[0][0]; r = (s - 16) * 16; d = 64 * 32; }
                else             { gb = Btl + (size_t)n0 * K; lb = &Bl[0][0]; r = (s - 20) * 16; d = 64 * 32; }
            } else {
                if (s < 4)       { gb = Ath + (size_t)m0 * K; lb = &Ah[0][0]; r = s * 16;        d = BM * 32; }
                else if (s < 8)  { gb = Atl + (size_t)m0 * K; lb = &Al[0][0]; r = (s - 4) * 16;  d = BM * 32; }
                else if (s < 12) { gb = Bth + (size_t)n0 * K; lb = &Bh[0][0]; r = (s - 8) * 16;  d = 64 * 32; }
                else             { gb = Btl + (size_t)n0 * K; lb = &Bl[0][0]; r = (s - 12) * 16; d = 64 * 32; }
            }
            int row = r + lr;
            int scol = lc ^ (((row >> 1) & 3) << 3);
            gsrc[i] = gb + (size_t)row * K + scol;
            ldst[i] = lb + r * 32;
            dlt[i] = d;
        }
    }

    f32x4 acc[2][NI];
#pragma unroll
    for (int i = 0; i < 2; i++)
#pragma unroll
        for (int j = 0; j < NI; j++) acc[i][j] = (f32x4){0.0f, 0.0f, 0.0f, 0.0f};

    const int NT = K >> 5;
    // prologue: stage tile 0 into buf0
#pragma unroll
    for (int i = 0; i < SEGS; i++) gl16(gsrc[i], ldst[i]);

    for (int tt = 0; tt < NT; tt++) {
        asm volatile("s_waitcnt lgkmcnt(0)" ::: "memory");
        __builtin_amdgcn_s_barrier();            // A: buf^1 readers (tt-1) all done
        if (tt + 1 < NT) {
            int k0n = (tt + 1) * 32;
            u32 sel = (u32)((tt + 1) & 1);
#pragma unroll
            for (int i = 0; i < SEGS; i++) gl16(gsrc[i] + k0n, ldst[i] + sel * dlt[i]);
            asm volatile("s_waitcnt vmcnt(%0)" :: "n"(SEGS) : "memory");   // own tile tt landed
        } else {
            asm volatile("s_waitcnt vmcnt(0)" ::: "memory");
        }
        __builtin_amdgcn_s_barrier();            // B: everyone's tile tt landed
        __builtin_amdgcn_sched_barrier(0);
        int cb = tt & 1;
        const u16* AhB = &Ah[cb][0]; const u16* AlB = &Al[cb][0];
        const u16* BhB = &Bh[cb][0]; const u16* BlB = &Bl[cb][0];
        s16x8 ah[2], al[2];
#pragma unroll
        for (int mi = 0; mi < 2; mi++) {
            int row = wm * 32 + mi * 16 + fr;
            ah[mi] = *reinterpret_cast<const s16x8*>(&AhB[sw32(row, quad * 8)]);
            al[mi] = *reinterpret_cast<const s16x8*>(&AlB[sw32(row, quad * 8)]);
        }
        __builtin_amdgcn_s_setprio(1);
#pragma unroll
        for (int ni = 0; ni < NI; ni++) {
            int rn = wn * 32 + ni * 16 + fr;
            s16x8 bhf = *reinterpret_cast<const s16x8*>(&BhB[sw32(rn, quad * 8)]);
            s16x8 blf = *reinterpret_cast<const s16x8*>(&BlB[sw32(rn, quad * 8)]);
#pragma unroll
            for (int mi = 0; mi < 2; mi++) {
                acc[mi][ni] = __builtin_amdgcn_mfma_f32_16x16x32_bf16(ah[mi], bhf, acc[mi][ni], 0, 0, 0);
                acc[mi][ni] = __builtin_amdgcn_mfma_f32_16x16x32_bf16(ah[mi], blf, acc[mi][ni], 0, 0, 0);
                acc[mi][ni] = __builtin_amdgcn_mfma_f32_16x16x32_bf16(al[mi], bhf, acc[mi][ni], 0, 0, 0);
            }
        }
        __builtin_amdgcn_s_setprio(0);
    }
#pragma unroll
    for (int mi = 0; mi < 2; mi++) {
#pragma unroll
        for (int ni = 0; ni < NI; ni++) {
#pragma unroll
            for (int r = 0; r < 4; r++) {
                int row = m0 + wm * 32 + mi * 16 + quad * 4 + r;
                int col = n0 + wn * 32 + ni * 16 + fr;
                float v = acc[mi][ni][r];
                if (bias) v += bias[col];
                if (fuse_gelu) v = 0.5f * v * (1.0f + erff(v * 0.70710678118654752f));
                if (resid) v += resid[(size_t)row * N + col];
                size_t o = (size_t)row * N + col;
                if (Cf) Cf[o] = v;
                if (Ch) { u16 hh = f2bf(v); Ch[o] = hh; Cl[o] = f2bf(v - bf2f(hh)); }
            }
        }
    }
}

// ---------------- Attention v11: Q direct-global, K gl16-dbuf LDS, V reg->VT, no vmcnt drains -----
// qkv row layout: [q(256) | k(256) | v(256)]; per head h the slice h*32..h*32+31 of each.
__global__ __launch_bounds__(256) void attn11(const u16* __restrict__ qkvh, const u16* __restrict__ qkvl,
                                              u16* __restrict__ aoh, u16* __restrict__ aol) {
    int bh = blockIdx.x, b = bh >> 3, h = bh & 7;
    int qt = blockIdx.y;
    int t = threadIdx.x, L = t & 63, w = t >> 6;
    int fr = L & 15, quad = L >> 4;
    __shared__ u16 KH[2][64 * 32], KL[2][64 * 32];    // 16KB dbuf, sw32 layout
    __shared__ u16 VTH[32 * 64], VTL[32 * 64];        // 8KB  V^T[d][kc], sw64 layout
    __shared__ u16 PH[4][16 * 64], PL[4][16 * 64];    // 16KB per-wave P tile, sw64 layout
    const float scale = 0.17677669529663687f;  // 1/sqrt(32)
    const int ROWS = 768;

    // K staging via gl16: 8 segs (KH 4, KL 4), 2 per wave, precomputed addresses
    const u16* ksrc[2];
    u16* kdst[2];
    {
        int lr = L >> 2, lc = (L & 3) * 8;
#pragma unroll
        for (int i = 0; i < 2; i++) {
            int s = w * 2 + i;
            const u16* gb = (s < 4) ? qkvh : qkvl;
            u16* lb = (s < 4) ? &KH[0][0] : &KL[0][0];
            int r = (s & 3) * 16;
            int row = r + lr;
            int scol = lc ^ (((row >> 1) & 3) << 3);
            ksrc[i] = gb + ((size_t)(b * 1024) + row) * ROWS + 256 + h * 32 + scol;
            kdst[i] = lb + r * 32;
        }
    }

    // Q fragments: direct global load (same values LDS staging produced)
    size_t qoff = (size_t)(b * 1024 + qt * 64 + w * 16 + fr) * ROWS + h * 32 + quad * 8;
    s16x8 aqh = *reinterpret_cast<const s16x8*>(qkvh + qoff);
    s16x8 aql = *reinterpret_cast<const s16x8*>(qkvl + qoff);

    // V loads: thread -> kc pair 2vp,2vp+1, dims vd0..+3
    int vp = t >> 3, vd0 = (t & 7) * 4;
    const u16* vh_ptr = qkvh + (size_t)(b * 1024 + 2 * vp) * ROWS + 512 + h * 32 + vd0;
    const u16* vl_ptr = qkvl + (size_t)(b * 1024 + 2 * vp) * ROWS + 512 + h * 32 + vd0;
    u16x4 vh0, vh1, vl0, vl1;
#define LOADV(kt_) do { size_t o_ = (size_t)((kt_) * 64) * ROWS;                                  \
        vh0 = *reinterpret_cast<const u16x4*>(vh_ptr + o_);                                       \
        vh1 = *reinterpret_cast<const u16x4*>(vh_ptr + o_ + ROWS);                                \
        vl0 = *reinterpret_cast<const u16x4*>(vl_ptr + o_);                                       \
        vl1 = *reinterpret_cast<const u16x4*>(vl_ptr + o_ + ROWS); } while (0)

    LOADV(0);
    gl16(ksrc[0], kdst[0]);    // K(0) -> buf0
    gl16(ksrc[1], kdst[1]);

    float m_i[4], l_i[4];
    f32x4 acc_o[2];
#pragma unroll
    for (int r = 0; r < 4; r++) { m_i[r] = -1e30f; l_i[r] = 0.0f; }
    acc_o[0] = (f32x4){0.0f, 0.0f, 0.0f, 0.0f};
    acc_o[1] = (f32x4){0.0f, 0.0f, 0.0f, 0.0f};

#pragma unroll 2
    for (int kt = 0; kt < 16; kt++) {
        int cur = kt & 1;
        asm volatile("s_waitcnt lgkmcnt(0)" ::: "memory");
        __builtin_amdgcn_s_barrier();      // A: K buf^1 + VT readers (kt-1) all done
        if (kt < 15) {                     // prefetch K(kt+1) -> buf^1 (flies through everything)
            size_t koff = (size_t)((kt + 1) * 64) * ROWS;
            u32 sel = (u32)((kt + 1) & 1) * (64 * 32);
            gl16(ksrc[0] + koff, kdst[0] + sel);
            gl16(ksrc[1] + koff, kdst[1] + sel);
        }
        {   // VT write from prefetched V regs (pack-only)
#pragma unroll
            for (int i = 0; i < 4; i++) {
                int idx = sw64(vd0 + i, 2 * vp);
                *reinterpret_cast<u32*>(&VTH[idx]) = (u32)vh0[i] | ((u32)vh1[i] << 16);
                *reinterpret_cast<u32*>(&VTL[idx]) = (u32)vl0[i] | ((u32)vl1[i] << 16);
            }
        }
        if (kt < 15) { asm volatile("s_waitcnt vmcnt(2)" ::: "memory"); }   // own K(kt) landed
        else         { asm volatile("s_waitcnt vmcnt(0)" ::: "memory"); }
        asm volatile("s_waitcnt lgkmcnt(0)" ::: "memory");                  // VT visible
        __builtin_amdgcn_s_barrier();      // B: everyone's K(kt) + VT(kt) ready
        __builtin_amdgcn_sched_barrier(0);
        // S = Q K^T : 4 n-subtiles, bf16x2 (3 MFMA each)
        f32x4 s[4];
        __builtin_amdgcn_s_setprio(1);
#pragma unroll
        for (int ni = 0; ni < 4; ni++) {
            s16x8 bkh = *reinterpret_cast<s16x8*>(&KH[cur][sw32(ni * 16 + fr, quad * 8)]);
            s16x8 bkl = *reinterpret_cast<s16x8*>(&KL[cur][sw32(ni * 16 + fr, quad * 8)]);
            f32x4 c = (f32x4){0.0f, 0.0f, 0.0f, 0.0f};
            c = __builtin_amdgcn_mfma_f32_16x16x32_bf16(aqh, bkh, c, 0, 0, 0);
            c = __builtin_amdgcn_mfma_f32_16x16x32_bf16(aqh, bkl, c, 0, 0, 0);
            c = __builtin_amdgcn_mfma_f32_16x16x32_bf16(aql, bkh, c, 0, 0, 0);
            s[ni] = c;
        }
        __builtin_amdgcn_s_setprio(0);
        if (kt < 15) LOADV(kt + 1);   // V regs free after VT write; loads fly through softmax+PV
        // online softmax: lane owns rows quad*4+r, cols ni*16+fr
        float alpha[4];
#pragma unroll
        for (int r = 0; r < 4; r++) {
            float s0 = s[0][r] * scale, s1 = s[1][r] * scale;
            float s2 = s[2][r] * scale, s3 = s[3][r] * scale;
            float ml = fmaxf(fmaxf(s0, s1), fmaxf(s2, s3));
            for (int off = 1; off < 16; off <<= 1) ml = fmaxf(ml, __shfl_xor(ml, off));
            float mnew = fmaxf(m_i[r], ml);
            alpha[r] = __expf(m_i[r] - mnew);
            m_i[r] = mnew;
            float p0 = __expf(s0 - mnew), p1 = __expf(s1 - mnew);
            float p2 = __expf(s2 - mnew), p3 = __expf(s3 - mnew);
            float rs = p0 + p1 + p2 + p3;
            for (int off = 1; off < 16; off <<= 1) rs += __shfl_xor(rs, off);
            l_i[r] = l_i[r] * alpha[r] + rs;
            int row = quad * 4 + r;
            float ps[4] = {p0, p1, p2, p3};
#pragma unroll
            for (int ni = 0; ni < 4; ni++) {
                u16 ph = f2bf(ps[ni]);
                int idx = sw64(row, ni * 16 + fr);
                PH[w][idx] = ph;
                PL[w][idx] = f2bf(ps[ni] - bf2f(ph));
            }
        }
        acc_o[0][0] *= alpha[0]; acc_o[0][1] *= alpha[1]; acc_o[0][2] *= alpha[2]; acc_o[0][3] *= alpha[3];
        acc_o[1][0] *= alpha[0]; acc_o[1][1] *= alpha[1]; acc_o[1][2] *= alpha[2]; acc_o[1][3] *= alpha[3];
        // PV: O += P V ; P wave-private (same-wave LDS write->read ordering)
        __builtin_amdgcn_s_setprio(1);
#pragma unroll
        for (int ks = 0; ks < 2; ks++) {
            s16x8 aph = *reinterpret_cast<s16x8*>(&PH[w][sw64(fr, ks * 32 + quad * 8)]);
            s16x8 apl = *reinterpret_cast<s16x8*>(&PL[w][sw64(fr, ks * 32 + quad * 8)]);
#pragma unroll
            for (int ns = 0; ns < 2; ns++) {
                s16x8 bvh = *reinterpret_cast<s16x8*>(&VTH[sw64(ns * 16 + fr, ks * 32 + quad * 8)]);
                s16x8 bvl = *reinterpret_cast<s16x8*>(&VTL[sw64(ns * 16 + fr, ks * 32 + quad * 8)]);
                acc_o[ns] = __builtin_amdgcn_mfma_f32_16x16x32_bf16(aph, bvh, acc_o[ns], 0, 0, 0);
                acc_o[ns] = __builtin_amdgcn_mfma_f32_16x16x32_bf16(aph, bvl, acc_o[ns], 0, 0, 0);
                acc_o[ns] = __builtin_amdgcn_mfma_f32_16x16x32_bf16(apl, bvh, acc_o[ns], 0, 0, 0);
            }
        }
        __builtin_amdgcn_s_setprio(0);
    }
#undef LOADV
    // write O as bf16 h/l (row stride DMODEL): row = quad*4+r of wave tile, col = ns*16+fr
#pragma unroll
    for (int r = 0; r < 4; r++) {
        float invl = 1.0f / l_i[r];
        size_t rowbase = ((size_t)(b * 1024 + qt * 64 + w * 16 + quad * 4 + r)) * DMODEL + h * 32;
        float v0 = acc_o[0][r] * invl, v1 = acc_o[1][r] * invl;
        u16 h0 = f2bf(v0); aoh[rowbase + fr] = h0;      aol[rowbase + fr] = f2bf(v0 - bf2f(h0));
        u16 h1 = f2bf(v1); aoh[rowbase + 16 + fr] = h1; aol[rowbase + 16 + fr] = f2bf(v1 - bf2f(h1));
    }
}

// ---------------- K-means: fused dist+argmin (256 blocks), chunked atomic-free segsum ------------
__global__ __launch_bounds__(64) void csq_k(const float* __restrict__ centers, float* __restrict__ csq) {
    int j = blockIdx.x, l = threadIdx.x;
    float4 c4 = *reinterpret_cast<const float4*>(centers + j * DMODEL + l * 4);
    float s = c4.x * c4.x + c4.y * c4.y + c4.z * c4.z + c4.w * c4.w;
    for (int off = 1; off < 64; off <<= 1) s += __shfl_xor(s, off);
    if (l == 0) csq[j] = s;
}

__global__ __launch_bounds__(256) void km_distmin(const float* __restrict__ A, const float* __restrict__ Cn,
                                                  const float* __restrict__ csq, int* __restrict__ labels) {
    __shared__ float As[16][34];
    __shared__ float Bs[16][64];
    int t = threadIdx.x, tx = t & 15, ty = t >> 4;
    int m0 = blockIdx.x * 32;
    int mr = t & 31, kq = (t >> 5) * 2;
    int jb = t & 63, kb = (t >> 6) * 4;
    float acc[2][4] = {};
    for (int k0 = 0; k0 < 256; k0 += 16) {
        __syncthreads();
        {
            float2 a2 = *reinterpret_cast<const float2*>(A + (size_t)(m0 + mr) * DMODEL + k0 + kq);
            As[kq][mr] = a2.x; As[kq + 1][mr] = a2.y;
        }
        {
            float4 c4 = *reinterpret_cast<const float4*>(Cn + (size_t)jb * DMODEL + k0 + kb);
            Bs[kb][jb] = c4.x; Bs[kb + 1][jb] = c4.y; Bs[kb + 2][jb] = c4.z; Bs[kb + 3][jb] = c4.w;
        }
        __syncthreads();
#pragma unroll
        for (int kk = 0; kk < 16; kk++) {
            float2 a2v = *reinterpret_cast<float2*>(&As[kk][ty * 2]);
            float4 b4 = *reinterpret_cast<float4*>(&Bs[kk][tx * 4]);
            float a[2] = {a2v.x, a2v.y};
            float bf[4] = {b4.x, b4.y, b4.z, b4.w};
#pragma unroll
            for (int i = 0; i < 2; i++)
#pragma unroll
                for (int j = 0; j < 4; j++) acc[i][j] += a[i] * bf[j];
        }
    }
    float4 cs4 = *reinterpret_cast<const float4*>(csq + tx * 4);
    float csv[4] = {cs4.x, cs4.y, cs4.z, cs4.w};
#pragma unroll
    for (int i = 0; i < 2; i++) {
        float best = csv[0] - 2.0f * acc[i][0]; int bi = tx * 4;
#pragma unroll
        for (int j = 1; j < 4; j++) {
            float v = csv[j] - 2.0f * acc[i][j];
            if (v < best) { best = v; bi = tx * 4 + j; }
        }
        for (int off = 1; off < 16; off <<= 1) {
            float ov = __shfl_xor(best, off);
            int oi = __shfl_xor(bi, off);
            if (ov < best || (ov == best && oi < bi)) { best = ov; bi = oi; }
        }
        if (tx == 0) labels[m0 + ty * 2 + i] = bi;
    }
}

// block (c, j): scan chunk c's 512 labels, accumulate rows with lab==j. Uniform branch, no atomics.
__global__ __launch_bounds__(256) void km_segsum(const int* __restrict__ labels, const float* __restrict__ xf,
                                                 float* __restrict__ sums16, float* __restrict__ counts16) {
    int c = blockIdx.x, j = blockIdx.y, t = threadIdx.x;
    __shared__ int labs[512];
    if (t < 128) {
        int4 l4 = *reinterpret_cast<const int4*>(labels + c * 512 + t * 4);
        labs[t * 4] = l4.x; labs[t * 4 + 1] = l4.y; labs[t * 4 + 2] = l4.z; labs[t * 4 + 3] = l4.w;
    }
    __syncthreads();
    float acc = 0.0f, cnt = 0.0f;
    const float* xb = xf + (size_t)c * 512 * DMODEL;
    for (int i = 0; i < 512; i++) {
        if (labs[i] == j) { acc += xb[(size_t)i * DMODEL + t]; cnt += 1.0f; }
    }
    sums16[((size_t)c * NCLUST + j) * DMODEL + t] = acc;
    if (t == 0) counts16[c * NCLUST + j] = cnt;
}

__global__ __launch_bounds__(256) void km_update(float* __restrict__ centers, const float* __restrict__ sums16,
                                                 const float* __restrict__ counts16, float* __restrict__ csq) {
    __shared__ float red[256];
    int j = blockIdx.x, d = threadIdx.x;
    float c = 0.0f;
#pragma unroll
    for (int cc = 0; cc < 16; cc++) c += counts16[cc * NCLUST + j];
    float sv = 0.0f;
#pragma unroll
    for (int cc = 0; cc < 16; cc++) sv += sums16[((size_t)cc * NCLUST + j) * DMODEL + d];
    float cv = centers[j * DMODEL + d];
    if (c > 0.0f) cv = sv / fmaxf(c, 1.0f);
    centers[j * DMODEL + d] = cv;
    red[d] = cv * cv;
    __syncthreads();
    for (int off = 128; off; off >>= 1) { if (d < off) red[d] += red[d + off]; __syncthreads(); }
    if (d == 0) csq[j] = red[0];
}

__global__ __launch_bounds__(256) void nproj(const float* __restrict__ centers, const float* __restrict__ kW,
                                             const float* __restrict__ kb2, float* __restrict__ outc) {
    int idx = blockIdx.x * 256 + threadIdx.x;
    if (idx >= NCLUST * DMODEL) return;
    int row = idx >> 8, col = idx & 255;
    const float* cr = centers + row * DMODEL;
    float acc = 0.0f;
    for (int d = 0; d < DMODEL; d++) acc += cr[d] * kW[(size_t)d * DMODEL + col];
    outc[idx] = acc + kb2[col];
}

__global__ __launch_bounds__(256) void km_gather(const int* __restrict__ labels, const float* __restrict__ outc,
                                                 float* __restrict__ out) {
    int i = blockIdx.x, t = threadIdx.x;
    int lab = labels[i];
    out[(size_t)i * DMODEL + t] = outc[lab * DMODEL + t];
}

extern "C" void kernel_launch(void* const* d_in, const int* in_sizes, int n_in,
                              void* d_out, int out_size, void* d_ws, size_t ws_size,
                              hipStream_t stream) {
    const float* x_in  = (const float*)d_in[0];
    const float* ln1_g = (const float*)d_in[1];
    const float* ln1_b = (const float*)d_in[2];
    const float* Wq    = (const float*)d_in[3];
    const float* Wkv   = (const float*)d_in[4];
    const float* Wo    = (const float*)d_in[5];
    const float* bo    = (const float*)d_in[6];
    const float* ln2_g = (const float*)d_in[7];
    const float* ln2_b = (const float*)d_in[8];
    const float* W1    = (const float*)d_in[9];
    const float* b1    = (const float*)d_in[10];
    const float* W2    = (const float*)d_in[11];
    const float* b2    = (const float*)d_in[12];
    const float* kWp   = (const float*)d_in[13];
    const float* kbp   = (const float*)d_in[14];
    float* out = (float*)d_out;

    const size_t NEEDED = 53477376;
    if (ws_size < NEEDED) {
        hipMemsetAsync(d_out, 0, (size_t)out_size * sizeof(float), stream);
        return;   // signature: absmax ~0.707 => workspace too small
    }

    char* ws = (char*)d_ws;
    float* xf      = (float*)(ws);                 // 8 MB fp32 residual stream
    u16*   xnh     = (u16*)  (ws + 8388608);       // 4 MB  ln out h
    u16*   xnl     = (u16*)  (ws + 12582912);      // 4 MB  ln out l
    u16*   aoh     = xnh;                          // attn out aliases xn (xn dead after QKV gemm)
    u16*   aol     = xnl;
    u16*   qkvh    = (u16*)  (ws + 16777216);      // 12 MB (8192x768 u16) -> ends 29360128
    u16*   qkvl    = (u16*)  (ws + 29360128);      // 12 MB -> ends 41943040
    u16*   hbh     = (u16*)  (ws + 16777216);      // 16 MB (qkv dead during FFN)
    u16*   hbl     = (u16*)  (ws + 33554432);      // 16 MB -> ends 50331648
    float* centers = (float*)(ws + 41943040);      // 64 KB -> 42008576
    float* csqb    = (float*)(ws + 42008576);      // 256 B -> 42008832
    float* counts16= (float*)(ws + 42008832);      // 4 KB  -> 42012928
    int*   labels  = (int*)  (ws + 42012928);      // 32 KB -> 42045696
    float* outc    = (float*)(ws + 42045696);      // 64 KB -> 42111232
    float* sums16  = (float*)(ws + 42111232);      // 1 MB  -> 43159808
    u16*   wr      = (u16*)  (ws + 50331648);
    u16 *wqkvh = wr,          *wqkvl = wr + 196608;   // 768x256 each
    u16 *woh = wr + 393216,   *wol = wr + 458752;
    u16 *w1h = wr + 524288,   *w1l = wr + 786432;
    u16 *w2h = wr + 1048576,  *w2l = wr + 1310720;

    hipMemcpyAsync(xf, x_in, (size_t)BN * DMODEL * sizeof(float), hipMemcpyDeviceToDevice, stream);

    for (int l = 0; l < 4; l++) {
        wconv_all<<<192, 256, 0, stream>>>(Wq + (size_t)l * 65536, Wkv + (size_t)l * 131072,
                                           Wo + (size_t)l * 65536, W1 + (size_t)l * 262144,
                                           W2 + (size_t)l * 262144,
                                           wqkvh, wqkvl, woh, wol, w1h, w1l, w2h, w2l);

        ln_wave<<<BN / 4, 256, 0, stream>>>(xf, ln1_g + l * 256, ln1_b + l * 256, xnh, xnl);
        gemm_t<128, 4><<<dim3(12, 64), 256, 0, stream>>>(xnh, xnl, wqkvh, wqkvl, nullptr, nullptr,
                                                         nullptr, qkvh, qkvl, BN, 768, 256, 0);
        attn11<<<dim3(64, 16), 256, 0, stream>>>(qkvh, qkvl, aoh, aol);
        gemm_t<64, 2><<<dim3(4, 128), 256, 0, stream>>>(aoh, aol, woh, wol, bo + l * 256, xf,
                                                        xf, nullptr, nullptr, BN, 256, 256, 0);
        ln_wave<<<BN / 4, 256, 0, stream>>>(xf, ln2_g + l * 256, ln2_b + l * 256, xnh, xnl);
        gemm_t<128, 4><<<dim3(16, 64), 256, 0, stream>>>(xnh, xnl, w1h, w1l, b1 + l * 1024, nullptr,
                                                         nullptr, hbh, hbl, BN, 1024, 256, 1);
        gemm_t<64, 2><<<dim3(4, 128), 256, 0, stream>>>(hbh, hbl, w2h, w2l, b2 + l * 256, xf,
                                                        xf, nullptr, nullptr, BN, 256, 1024, 0);
    }

    hipMemcpyAsync(centers, xf, NCLUST * DMODEL * sizeof(float), hipMemcpyDeviceToDevice, stream);
    csq_k<<<64, 64, 0, stream>>>(centers, csqb);
    for (int it = 0; it < 10; it++) {
        km_distmin<<<256, 256, 0, stream>>>(xf, centers, csqb, labels);
        km_segsum<<<dim3(16, NCLUST), 256, 0, stream>>>(labels, xf, sums16, counts16);
        km_update<<<64, 256, 0, stream>>>(centers, sums16, counts16, csqb);
    }
    km_distmin<<<256, 256, 0, stream>>>(xf, centers, csqb, labels);
    nproj<<<64, 256, 0, stream>>>(centers, kWp, kbp, outc);
    km_gather<<<BN, 256, 0, stream>>>(labels, outc, out);
}

// Round 6
// 1332.136 us; speedup vs baseline: 1.4717x; 1.0401x over previous
//
#include <hip/hip_runtime.h>
#include <hip/hip_bf16.h>
#include <math.h>

// Problem constants (B=8, N=1024, D=256, L=4, M=1024, H=8, dh=32, K=64 clusters)
#define BN 8192           // B*N rows
#define DMODEL 256
#define FFN 1024
#define NCLUST 64

typedef unsigned short u16;
typedef unsigned int u32;
typedef __attribute__((ext_vector_type(8))) short s16x8;      // 8 bf16 (4 VGPRs) MFMA frag
typedef __attribute__((ext_vector_type(8))) unsigned short u16x8;
typedef __attribute__((ext_vector_type(4))) unsigned short u16x4;
typedef __attribute__((ext_vector_type(4))) float f32x4;

__device__ __forceinline__ float bf2f(u16 v) {
    union { unsigned int u; float f; } w; w.u = ((unsigned int)v) << 16; return w.f;
}
__device__ __forceinline__ u16 f2bf(float f) {
    union { float f; unsigned int u; } w; w.f = f;
    unsigned int r = w.u + 0x7fffu + ((w.u >> 16) & 1u);
    return (u16)(r >> 16);
}

// async global->LDS, 16B per lane. LDS dest = wave-uniform base + lane*16 (linear);
// swizzled layouts are achieved by pre-swizzling the per-lane GLOBAL source column.
__device__ __forceinline__ void gl16(const u16* g, u16* l) {
    __builtin_amdgcn_global_load_lds((const __attribute__((address_space(1))) u32*)g,
                                     (__attribute__((address_space(3))) u32*)l, 16, 0, 0);
}

// barrier that does NOT drain vmcnt: LDS-visibility only. In-flight global/gl16 loads survive.
#define BARRIER_LGKM() asm volatile("s_waitcnt lgkmcnt(0)\n\ts_barrier" ::: "memory")
#define MEMFENCE_ORDER() asm volatile("" ::: "memory")

// XOR-swizzled LDS index helpers (u16 units).
__device__ __forceinline__ int sw32(int row, int col) { return row * 32 + (col ^ (((row >> 1) & 3) << 3)); }
__device__ __forceinline__ int sw64(int row, int col) { return row * 64 + (col ^ ((row & 7) << 3)); }

// ---------------- LayerNorm: one wave per row, float4 + shuffle reduce; emits bf16 h/l ----------------
__global__ __launch_bounds__(256) void ln_wave(const float* __restrict__ x, const float* __restrict__ g,
                                               const float* __restrict__ b, u16* __restrict__ yh,
                                               u16* __restrict__ yl) {
    int t = threadIdx.x, w = t >> 6, l = t & 63;
    int row = blockIdx.x * 4 + w;
    const float* xr = x + (size_t)row * DMODEL;
    float4 v = *reinterpret_cast<const float4*>(xr + l * 4);
    float s = v.x + v.y + v.z + v.w;
    for (int off = 1; off < 64; off <<= 1) s += __shfl_xor(s, off);
    float mean = s * (1.0f / 256.0f);
    float4 dv = make_float4(v.x - mean, v.y - mean, v.z - mean, v.w - mean);
    float vs = dv.x * dv.x + dv.y * dv.y + dv.z * dv.z + dv.w * dv.w;
    for (int off = 1; off < 64; off <<= 1) vs += __shfl_xor(vs, off);
    float rs = rsqrtf(vs * (1.0f / 256.0f) + 1e-5f);
    float4 gg = *reinterpret_cast<const float4*>(g + l * 4);
    float4 bb = *reinterpret_cast<const float4*>(b + l * 4);
    float os[4] = {dv.x * rs * gg.x + bb.x, dv.y * rs * gg.y + bb.y,
                   dv.z * rs * gg.z + bb.z, dv.w * rs * gg.w + bb.w};
    u16x4 hv, lv;
#pragma unroll
    for (int j = 0; j < 4; j++) { u16 hh = f2bf(os[j]); hv[j] = hh; lv[j] = f2bf(os[j] - bf2f(hh)); }
    size_t o = (size_t)row * DMODEL + l * 4;
    *reinterpret_cast<u16x4*>(yh + o) = hv;
    *reinterpret_cast<u16x4*>(yl + o) = lv;
}

// ---------------- Weight convert: one fused launch per layer (5 weights, 192 blocks) --------------
__device__ __forceinline__ void wconv_body(const float* __restrict__ W, u16* __restrict__ th,
                                           u16* __restrict__ tl, int K, int N, int bx, int by) {
    __shared__ float T[64][65];
    int k0 = by * 64, n0 = bx * 64;
    int t = threadIdx.x;
    int r = t >> 4, c4 = (t & 15) * 4;
#pragma unroll
    for (int i = 0; i < 4; i++) {
        float4 x = *reinterpret_cast<const float4*>(W + (size_t)(k0 + r + 16 * i) * N + n0 + c4);
        T[r + 16 * i][c4] = x.x; T[r + 16 * i][c4 + 1] = x.y;
        T[r + 16 * i][c4 + 2] = x.z; T[r + 16 * i][c4 + 3] = x.w;
    }
    __syncthreads();
#pragma unroll
    for (int i = 0; i < 4; i++) {
        int n = r + 16 * i;
        u16x4 h4, l4;
#pragma unroll
        for (int j = 0; j < 4; j++) {
            float v = T[c4 + j][n];
            u16 h = f2bf(v);
            h4[j] = h; l4[j] = f2bf(v - bf2f(h));
        }
        *reinterpret_cast<u16x4*>(th + (size_t)(n0 + n) * K + k0 + c4) = h4;
        *reinterpret_cast<u16x4*>(tl + (size_t)(n0 + n) * K + k0 + c4) = l4;
    }
}

__global__ __launch_bounds__(256) void wconv_all(const float* __restrict__ Wq, const float* __restrict__ Wkv,
                                                 const float* __restrict__ Wo, const float* __restrict__ W1,
                                                 const float* __restrict__ W2,
                                                 u16* __restrict__ wqkvh, u16* __restrict__ wqkvl,
                                                 u16* __restrict__ woh, u16* __restrict__ wol,
                                                 u16* __restrict__ w1h, u16* __restrict__ w1l,
                                                 u16* __restrict__ w2h, u16* __restrict__ w2l) {
    int f = blockIdx.x;
    if (f < 16)       wconv_body(Wq,  wqkvh,               wqkvl,               256, 256,  f & 3,  f >> 2);
    else if (f < 48)  { int g = f - 16;  wconv_body(Wkv, wqkvh + 65536,       wqkvl + 65536,       256, 512,  g & 7,  g >> 3); }
    else if (f < 64)  { int g = f - 48;  wconv_body(Wo,  woh,                 wol,                 256, 256,  g & 3,  g >> 2); }
    else if (f < 128) { int g = f - 64;  wconv_body(W1,  w1h,                 w1l,                 256, 1024, g & 15, g >> 4); }
    else              { int g = f - 128; wconv_body(W2,  w2h,                 w2l,                 1024, 256, g & 3,  g >> 2); }
}

// ---------------- MFMA GEMM (bf16x2): dbuf gl16 staging, counted-vmcnt no-drain schedule ----------
// Tiles: <128,128> 2x2 waves x 64x64; <128,64> 4x1 waves x 32x64; <64,64> 2x2 waves x 32x32.
template<int BM, int BNT>
__global__ __launch_bounds__(256) void gemm_t(const u16* __restrict__ Ath, const u16* __restrict__ Atl,
                                              const u16* __restrict__ Bth, const u16* __restrict__ Btl,
                                              const float* __restrict__ bias, const float* __restrict__ resid,
                                              float* __restrict__ Cf, u16* __restrict__ Ch, u16* __restrict__ Cl,
                                              int M, int N, int K, int fuse_gelu) {
    __shared__ u16 Ah[2][BM * 32], Al[2][BM * 32];
    __shared__ u16 Bh[2][BNT * 32], Bl[2][BNT * 32];
    constexpr int WAVES_N = (BM == 128 && BNT == 64) ? 1 : 2;
    constexpr int WAVES_M = 4 / WAVES_N;
    constexpr int MI = BM / (16 * WAVES_M);
    constexpr int NI = BNT / (16 * WAVES_N);
    constexpr int SEGS = (BM + BNT) / 32;       // 1KB segments per wave per K-step
    constexpr int ASEG = BM / 16, BSEG = BNT / 16;
    int t = threadIdx.x;
    int m0 = blockIdx.y * BM, n0 = blockIdx.x * BNT;
    int L = t & 63, w = t >> 6, fr = L & 15, quad = L >> 4;
    int wm = (WAVES_N == 1) ? w : (w & 1);
    int wn = (WAVES_N == 1) ? 0 : (w >> 1);

    // per-seg global source (pre-swizzled col) + buf0 LDS dest + buf1 element delta
    const u16* gsrc[SEGS];
    u16* ldst[SEGS];
    u32 dlt[SEGS];
    {
        int lr = L >> 2, lc = (L & 3) * 8;
#pragma unroll
        for (int i = 0; i < SEGS; i++) {
            int s = w * SEGS + i;
            const u16* gb; u16* lb; int r; u32 d;
            if (s < ASEG)                 { gb = Ath + (size_t)m0 * K; lb = &Ah[0][0]; r = s * 16;                 d = BM * 32; }
            else if (s < 2 * ASEG)        { gb = Atl + (size_t)m0 * K; lb = &Al[0][0]; r = (s - ASEG) * 16;        d = BM * 32; }
            else if (s < 2 * ASEG + BSEG) { gb = Bth + (size_t)n0 * K; lb = &Bh[0][0]; r = (s - 2 * ASEG) * 16;    d = BNT * 32; }
            else                          { gb = Btl + (size_t)n0 * K; lb = &Bl[0][0]; r = (s - 2 * ASEG - BSEG) * 16; d = BNT * 32; }
            int row = r + lr;
            int scol = lc ^ (((row >> 1) & 3) << 3);
            gsrc[i] = gb + (size_t)row * K + scol;
            ldst[i] = lb + r * 32;
            dlt[i] = d;
        }
    }

    f32x4 acc[MI][NI];
#pragma unroll
    for (int i = 0; i < MI; i++)
#pragma unroll
        for (int j = 0; j < NI; j++) acc[i][j] = (f32x4){0.0f, 0.0f, 0.0f, 0.0f};

    const int NT = K >> 5;
    // prologue: stage tile 0 into buf0
#pragma unroll
    for (int i = 0; i < SEGS; i++) gl16(gsrc[i], ldst[i]);

    for (int tt = 0; tt < NT; tt++) {
        asm volatile("s_waitcnt lgkmcnt(0)" ::: "memory");
        __builtin_amdgcn_s_barrier();            // A: buf^1 readers (tt-1) all done
        if (tt + 1 < NT) {
            int k0n = (tt + 1) * 32;
            u32 sel = (u32)((tt + 1) & 1);
#pragma unroll
            for (int i = 0; i < SEGS; i++) gl16(gsrc[i] + k0n, ldst[i] + sel * dlt[i]);
            asm volatile("s_waitcnt vmcnt(%0)" :: "n"(SEGS) : "memory");   // own tile tt landed
        } else {
            asm volatile("s_waitcnt vmcnt(0)" ::: "memory");
        }
        __builtin_amdgcn_s_barrier();            // B: everyone's tile tt landed
        __builtin_amdgcn_sched_barrier(0);
        int cb = tt & 1;
        const u16* AhB = &Ah[cb][0]; const u16* AlB = &Al[cb][0];
        const u16* BhB = &Bh[cb][0]; const u16* BlB = &Bl[cb][0];
        s16x8 ah[MI], al[MI];
#pragma unroll
        for (int mi = 0; mi < MI; mi++) {
            int row = wm * (MI * 16) + mi * 16 + fr;
            ah[mi] = *reinterpret_cast<const s16x8*>(&AhB[sw32(row, quad * 8)]);
            al[mi] = *reinterpret_cast<const s16x8*>(&AlB[sw32(row, quad * 8)]);
        }
        __builtin_amdgcn_s_setprio(1);
#pragma unroll
        for (int ni = 0; ni < NI; ni++) {
            int rn = wn * (NI * 16) + ni * 16 + fr;
            s16x8 bhf = *reinterpret_cast<const s16x8*>(&BhB[sw32(rn, quad * 8)]);
            s16x8 blf = *reinterpret_cast<const s16x8*>(&BlB[sw32(rn, quad * 8)]);
#pragma unroll
            for (int mi = 0; mi < MI; mi++) {
                acc[mi][ni] = __builtin_amdgcn_mfma_f32_16x16x32_bf16(ah[mi], bhf, acc[mi][ni], 0, 0, 0);
                acc[mi][ni] = __builtin_amdgcn_mfma_f32_16x16x32_bf16(ah[mi], blf, acc[mi][ni], 0, 0, 0);
                acc[mi][ni] = __builtin_amdgcn_mfma_f32_16x16x32_bf16(al[mi], bhf, acc[mi][ni], 0, 0, 0);
            }
        }
        __builtin_amdgcn_s_setprio(0);
    }
#pragma unroll
    for (int mi = 0; mi < MI; mi++) {
#pragma unroll
        for (int ni = 0; ni < NI; ni++) {
#pragma unroll
            for (int r = 0; r < 4; r++) {
                int row = m0 + wm * (MI * 16) + mi * 16 + quad * 4 + r;
                int col = n0 + wn * (NI * 16) + ni * 16 + fr;
                float v = acc[mi][ni][r];
                if (bias) v += bias[col];
                if (fuse_gelu) v = 0.5f * v * (1.0f + erff(v * 0.70710678118654752f));
                if (resid) v += resid[(size_t)row * N + col];
                size_t o = (size_t)row * N + col;
                if (Cf) Cf[o] = v;
                if (Ch) { u16 hh = f2bf(v); Ch[o] = hh; Cl[o] = f2bf(v - bf2f(hh)); }
            }
        }
    }
}

// ---------------- Attention v12: swapped QK^T -> in-lane softmax; K gl16-dbuf LDS; Q in regs -----
// mfma(K,Q) = S^T bitwise -> lane (fr,quad) holds S[q=w*16+fr][k=ni*16+quad*4+r].
// qkv row layout: [q(256) | k(256) | v(256)]; per head h the slice h*32..h*32+31 of each.
__global__ __launch_bounds__(256) void attn12(const u16* __restrict__ qkvh, const u16* __restrict__ qkvl,
                                              u16* __restrict__ aoh, u16* __restrict__ aol) {
    int bh = blockIdx.x, b = bh >> 3, h = bh & 7;
    int qt = blockIdx.y;
    int t = threadIdx.x, L = t & 63, w = t >> 6;
    int fr = L & 15, quad = L >> 4;
    __shared__ u16 KH[2][64 * 32], KL[2][64 * 32];    // 16KB dbuf, sw32 layout
    __shared__ u16 VTH[32 * 64], VTL[32 * 64];        // 8KB  V^T[d][kc], sw64 layout
    __shared__ u16 PH[4][16 * 64], PL[4][16 * 64];    // 16KB per-wave P tile, sw64 layout
    const float scale = 0.17677669529663687f;  // 1/sqrt(32)
    const int ROWS = 768;

    // K staging via gl16: 8 segs (KH 4, KL 4), 2 per wave, precomputed addresses
    const u16* ksrc[2];
    u16* kdst[2];
    {
        int lr = L >> 2, lc = (L & 3) * 8;
#pragma unroll
        for (int i = 0; i < 2; i++) {
            int s = w * 2 + i;
            const u16* gb = (s < 4) ? qkvh : qkvl;
            u16* lb = (s < 4) ? &KH[0][0] : &KL[0][0];
            int r = (s & 3) * 16;
            int row = r + lr;
            int scol = lc ^ (((row >> 1) & 3) << 3);
            ksrc[i] = gb + ((size_t)(b * 1024) + row) * ROWS + 256 + h * 32 + scol;
            kdst[i] = lb + r * 32;
        }
    }

    // Q fragments: direct global load (same values LDS staging produced)
    size_t qoff = (size_t)(b * 1024 + qt * 64 + w * 16 + fr) * ROWS + h * 32 + quad * 8;
    s16x8 aqh = *reinterpret_cast<const s16x8*>(qkvh + qoff);
    s16x8 aql = *reinterpret_cast<const s16x8*>(qkvl + qoff);

    // V loads: thread -> kc pair 2vp,2vp+1, dims vd0..+3
    int vp = t >> 3, vd0 = (t & 7) * 4;
    const u16* vh_ptr = qkvh + (size_t)(b * 1024 + 2 * vp) * ROWS + 512 + h * 32 + vd0;
    const u16* vl_ptr = qkvl + (size_t)(b * 1024 + 2 * vp) * ROWS + 512 + h * 32 + vd0;
    u16x4 vh0, vh1, vl0, vl1;
#define LOADV(kt_) do { size_t o_ = (size_t)((kt_) * 64) * ROWS;                                  \
        vh0 = *reinterpret_cast<const u16x4*>(vh_ptr + o_);                                       \
        vh1 = *reinterpret_cast<const u16x4*>(vh_ptr + o_ + ROWS);                                \
        vl0 = *reinterpret_cast<const u16x4*>(vl_ptr + o_);                                       \
        vl1 = *reinterpret_cast<const u16x4*>(vl_ptr + o_ + ROWS); } while (0)

    gl16(ksrc[0], kdst[0]);    // K(0) -> buf0 (must precede V(0) loads: FIFO drain invariant)
    gl16(ksrc[1], kdst[1]);
    MEMFENCE_ORDER();
    LOADV(0);

    float m_i = -1e30f, l_i = 0.0f;   // scalars: lane owns one q-row (fr)
    f32x4 acc_o[2];
    acc_o[0] = (f32x4){0.0f, 0.0f, 0.0f, 0.0f};
    acc_o[1] = (f32x4){0.0f, 0.0f, 0.0f, 0.0f};

#pragma unroll 2
    for (int kt = 0; kt < 16; kt++) {
        int cur = kt & 1;
        BARRIER_LGKM();                // A: K buf^1 + VT readers (kt-1) all done
        if (kt < 15) {                 // prefetch K(kt+1) -> buf^1 (survives both barriers)
            size_t koff = (size_t)((kt + 1) * 64) * ROWS;
            u32 sel = (u32)((kt + 1) & 1) * (64 * 32);
            gl16(ksrc[0] + koff, kdst[0] + sel);
            gl16(ksrc[1] + koff, kdst[1] + sel);
        }
        {   // VT write from prefetched V regs; the implicit V-wait also drains K(kt) (landed long ago)
#pragma unroll
            for (int i = 0; i < 4; i++) {
                int idx = sw64(vd0 + i, 2 * vp);
                *reinterpret_cast<u32*>(&VTH[idx]) = (u32)vh0[i] | ((u32)vh1[i] << 16);
                *reinterpret_cast<u32*>(&VTL[idx]) = (u32)vl0[i] | ((u32)vl1[i] << 16);
            }
        }
        BARRIER_LGKM();                // B: K(kt) + VT(kt) ready for all waves
        // S^T = K Q^T (bitwise transpose of Q K^T): 4 k-subtiles, bf16x2 (3 MFMA each)
        f32x4 sv[4];
        __builtin_amdgcn_s_setprio(1);
#pragma unroll
        for (int ni = 0; ni < 4; ni++) {
            s16x8 bkh = *reinterpret_cast<s16x8*>(&KH[cur][sw32(ni * 16 + fr, quad * 8)]);
            s16x8 bkl = *reinterpret_cast<s16x8*>(&KL[cur][sw32(ni * 16 + fr, quad * 8)]);
            f32x4 c = (f32x4){0.0f, 0.0f, 0.0f, 0.0f};
            c = __builtin_amdgcn_mfma_f32_16x16x32_bf16(bkh, aqh, c, 0, 0, 0);
            c = __builtin_amdgcn_mfma_f32_16x16x32_bf16(bkl, aqh, c, 0, 0, 0);
            c = __builtin_amdgcn_mfma_f32_16x16x32_bf16(bkh, aql, c, 0, 0, 0);
            sv[ni] = c;
        }
        __builtin_amdgcn_s_setprio(0);
        if (kt < 15) LOADV(kt + 1);    // V(kt+1) regs; consumed at next iter's VT write
        // in-lane softmax over the lane's 16 k-values of row q=fr; quads reduce via 2 shfl steps
        float p[16];
        float ml = -1e30f;
#pragma unroll
        for (int ni = 0; ni < 4; ni++)
#pragma unroll
            for (int r = 0; r < 4; r++) { float v = sv[ni][r] * scale; p[ni * 4 + r] = v; ml = fmaxf(ml, v); }
        ml = fmaxf(ml, __shfl_xor(ml, 16));
        ml = fmaxf(ml, __shfl_xor(ml, 32));
        float mnew = fmaxf(m_i, ml);
        float alpha = __expf(m_i - mnew);
        m_i = mnew;
        float rs = 0.0f;
#pragma unroll
        for (int i = 0; i < 16; i++) { float e = __expf(p[i] - mnew); p[i] = e; rs += e; }
        rs += __shfl_xor(rs, 16);
        rs += __shfl_xor(rs, 32);
        l_i = l_i * alpha + rs;
        // P write: packed u32 pairs into row fr (cols ni*16+quad*4 .. +3), sw64 layout
#pragma unroll
        for (int ni = 0; ni < 4; ni++) {
            float p0 = p[ni * 4], p1 = p[ni * 4 + 1], p2 = p[ni * 4 + 2], p3 = p[ni * 4 + 3];
            u16 h0 = f2bf(p0), h1 = f2bf(p1), h2 = f2bf(p2), h3 = f2bf(p3);
            u16 e0 = f2bf(p0 - bf2f(h0)), e1 = f2bf(p1 - bf2f(h1));
            u16 e2 = f2bf(p2 - bf2f(h2)), e3 = f2bf(p3 - bf2f(h3));
            int c0 = sw64(fr, ni * 16 + quad * 4);
            int c1 = sw64(fr, ni * 16 + quad * 4 + 2);
            *reinterpret_cast<u32*>(&PH[w][c0]) = (u32)h0 | ((u32)h1 << 16);
            *reinterpret_cast<u32*>(&PH[w][c1]) = (u32)h2 | ((u32)h3 << 16);
            *reinterpret_cast<u32*>(&PL[w][c0]) = (u32)e0 | ((u32)e1 << 16);
            *reinterpret_cast<u32*>(&PL[w][c1]) = (u32)e2 | ((u32)e3 << 16);
        }
        // rescale O rows (row space = quad*4+r): fetch alpha of that row from quad-0 lanes
        float a4[4];
#pragma unroll
        for (int r = 0; r < 4; r++) a4[r] = __shfl(alpha, quad * 4 + r);
        acc_o[0][0] *= a4[0]; acc_o[0][1] *= a4[1]; acc_o[0][2] *= a4[2]; acc_o[0][3] *= a4[3];
        acc_o[1][0] *= a4[0]; acc_o[1][1] *= a4[1]; acc_o[1][2] *= a4[2]; acc_o[1][3] *= a4[3];
        // PV: O += P V ; P wave-private (same-wave LDS write->read ordering)
        __builtin_amdgcn_s_setprio(1);
#pragma unroll
        for (int ks = 0; ks < 2; ks++) {
            s16x8 aph = *reinterpret_cast<s16x8*>(&PH[w][sw64(fr, ks * 32 + quad * 8)]);
            s16x8 apl = *reinterpret_cast<s16x8*>(&PL[w][sw64(fr, ks * 32 + quad * 8)]);
#pragma unroll
            for (int ns = 0; ns < 2; ns++) {
                s16x8 bvh = *reinterpret_cast<s16x8*>(&VTH[sw64(ns * 16 + fr, ks * 32 + quad * 8)]);
                s16x8 bvl = *reinterpret_cast<s16x8*>(&VTL[sw64(ns * 16 + fr, ks * 32 + quad * 8)]);
                acc_o[ns] = __builtin_amdgcn_mfma_f32_16x16x32_bf16(aph, bvh, acc_o[ns], 0, 0, 0);
                acc_o[ns] = __builtin_amdgcn_mfma_f32_16x16x32_bf16(aph, bvl, acc_o[ns], 0, 0, 0);
                acc_o[ns] = __builtin_amdgcn_mfma_f32_16x16x32_bf16(apl, bvh, acc_o[ns], 0, 0, 0);
            }
        }
        __builtin_amdgcn_s_setprio(0);
    }
#undef LOADV
    // write O as bf16 h/l: row = quad*4+r of wave tile, col = ns*16+fr; 1/l fetched per row
    float invl = 1.0f / l_i;
#pragma unroll
    for (int r = 0; r < 4; r++) {
        float iv = __shfl(invl, quad * 4 + r);
        size_t rowbase = ((size_t)(b * 1024 + qt * 64 + w * 16 + quad * 4 + r)) * DMODEL + h * 32;
        float v0 = acc_o[0][r] * iv, v1 = acc_o[1][r] * iv;
        u16 h0 = f2bf(v0); aoh[rowbase + fr] = h0;      aol[rowbase + fr] = f2bf(v0 - bf2f(h0));
        u16 h1 = f2bf(v1); aoh[rowbase + 16 + fr] = h1; aol[rowbase + 16 + fr] = f2bf(v1 - bf2f(h1));
    }
}

// ---------------- K-means: fused dist+argmin (256 blocks), chunked atomic-free segsum ------------
__global__ __launch_bounds__(64) void csq_k(const float* __restrict__ centers, float* __restrict__ csq) {
    int j = blockIdx.x, l = threadIdx.x;
    float4 c4 = *reinterpret_cast<const float4*>(centers + j * DMODEL + l * 4);
    float s = c4.x * c4.x + c4.y * c4.y + c4.z * c4.z + c4.w * c4.w;
    for (int off = 1; off < 64; off <<= 1) s += __shfl_xor(s, off);
    if (l == 0) csq[j] = s;
}

__global__ __launch_bounds__(256) void km_distmin(const float* __restrict__ A, const float* __restrict__ Cn,
                                                  const float* __restrict__ csq, int* __restrict__ labels) {
    __shared__ float As[16][34];
    __shared__ float Bs[16][64];
    int t = threadIdx.x, tx = t & 15, ty = t >> 4;
    int m0 = blockIdx.x * 32;
    int mr = t & 31, kq = (t >> 5) * 2;
    int jb = t & 63, kb = (t >> 6) * 4;
    float acc[2][4] = {};
    for (int k0 = 0; k0 < 256; k0 += 16) {
        __syncthreads();
        {
            float2 a2 = *reinterpret_cast<const float2*>(A + (size_t)(m0 + mr) * DMODEL + k0 + kq);
            As[kq][mr] = a2.x; As[kq + 1][mr] = a2.y;
        }
        {
            float4 c4 = *reinterpret_cast<const float4*>(Cn + (size_t)jb * DMODEL + k0 + kb);
            Bs[kb][jb] = c4.x; Bs[kb + 1][jb] = c4.y; Bs[kb + 2][jb] = c4.z; Bs[kb + 3][jb] = c4.w;
        }
        __syncthreads();
#pragma unroll
        for (int kk = 0; kk < 16; kk++) {
            float2 a2v = *reinterpret_cast<float2*>(&As[kk][ty * 2]);
            float4 b4 = *reinterpret_cast<float4*>(&Bs[kk][tx * 4]);
            float a[2] = {a2v.x, a2v.y};
            float bf[4] = {b4.x, b4.y, b4.z, b4.w};
#pragma unroll
            for (int i = 0; i < 2; i++)
#pragma unroll
                for (int j = 0; j < 4; j++) acc[i][j] += a[i] * bf[j];
        }
    }
    float4 cs4 = *reinterpret_cast<const float4*>(csq + tx * 4);
    float csv[4] = {cs4.x, cs4.y, cs4.z, cs4.w};
#pragma unroll
    for (int i = 0; i < 2; i++) {
        float best = csv[0] - 2.0f * acc[i][0]; int bi = tx * 4;
#pragma unroll
        for (int j = 1; j < 4; j++) {
            float v = csv[j] - 2.0f * acc[i][j];
            if (v < best) { best = v; bi = tx * 4 + j; }
        }
        for (int off = 1; off < 16; off <<= 1) {
            float ov = __shfl_xor(best, off);
            int oi = __shfl_xor(bi, off);
            if (ov < best || (ov == best && oi < bi)) { best = ov; bi = oi; }
        }
        if (tx == 0) labels[m0 + ty * 2 + i] = bi;
    }
}

// block (c, j): scan chunk c's 512 labels, accumulate rows with lab==j. Uniform branch, no atomics.
__global__ __launch_bounds__(256) void km_segsum(const int* __restrict__ labels, const float* __restrict__ xf,
                                                 float* __restrict__ sums16, float* __restrict__ counts16) {
    int c = blockIdx.x, j = blockIdx.y, t = threadIdx.x;
    __shared__ int labs[512];
    if (t < 128) {
        int4 l4 = *reinterpret_cast<const int4*>(labels + c * 512 + t * 4);
        labs[t * 4] = l4.x; labs[t * 4 + 1] = l4.y; labs[t * 4 + 2] = l4.z; labs[t * 4 + 3] = l4.w;
    }
    __syncthreads();
    float acc = 0.0f, cnt = 0.0f;
    const float* xb = xf + (size_t)c * 512 * DMODEL;
    for (int i = 0; i < 512; i++) {
        if (labs[i] == j) { acc += xb[(size_t)i * DMODEL + t]; cnt += 1.0f; }
    }
    sums16[((size_t)c * NCLUST + j) * DMODEL + t] = acc;
    if (t == 0) counts16[c * NCLUST + j] = cnt;
}

__global__ __launch_bounds__(256) void km_update(float* __restrict__ centers, const float* __restrict__ sums16,
                                                 const float* __restrict__ counts16, float* __restrict__ csq) {
    __shared__ float red[256];
    int j = blockIdx.x, d = threadIdx.x;
    float c = 0.0f;
#pragma unroll
    for (int cc = 0; cc < 16; cc++) c += counts16[cc * NCLUST + j];
    float sv = 0.0f;
#pragma unroll
    for (int cc = 0; cc < 16; cc++) sv += sums16[((size_t)cc * NCLUST + j) * DMODEL + d];
    float cv = centers[j * DMODEL + d];
    if (c > 0.0f) cv = sv / fmaxf(c, 1.0f);
    centers[j * DMODEL + d] = cv;
    red[d] = cv * cv;
    __syncthreads();
    for (int off = 128; off; off >>= 1) { if (d < off) red[d] += red[d + off]; __syncthreads(); }
    if (d == 0) csq[j] = red[0];
}

__global__ __launch_bounds__(256) void nproj(const float* __restrict__ centers, const float* __restrict__ kW,
                                             const float* __restrict__ kb2, float* __restrict__ outc) {
    int idx = blockIdx.x * 256 + threadIdx.x;
    if (idx >= NCLUST * DMODEL) return;
    int row = idx >> 8, col = idx & 255;
    const float* cr = centers + row * DMODEL;
    float acc = 0.0f;
    for (int d = 0; d < DMODEL; d++) acc += cr[d] * kW[(size_t)d * DMODEL + col];
    outc[idx] = acc + kb2[col];
}

__global__ __launch_bounds__(256) void km_gather(const int* __restrict__ labels, const float* __restrict__ outc,
                                                 float* __restrict__ out) {
    int i = blockIdx.x, t = threadIdx.x;
    int lab = labels[i];
    out[(size_t)i * DMODEL + t] = outc[lab * DMODEL + t];
}

extern "C" void kernel_launch(void* const* d_in, const int* in_sizes, int n_in,
                              void* d_out, int out_size, void* d_ws, size_t ws_size,
                              hipStream_t stream) {
    const float* x_in  = (const float*)d_in[0];
    const float* ln1_g = (const float*)d_in[1];
    const float* ln1_b = (const float*)d_in[2];
    const float* Wq    = (const float*)d_in[3];
    const float* Wkv   = (const float*)d_in[4];
    const float* Wo    = (const float*)d_in[5];
    const float* bo    = (const float*)d_in[6];
    const float* ln2_g = (const float*)d_in[7];
    const float* ln2_b = (const float*)d_in[8];
    const float* W1    = (const float*)d_in[9];
    const float* b1    = (const float*)d_in[10];
    const float* W2    = (const float*)d_in[11];
    const float* b2    = (const float*)d_in[12];
    const float* kWp   = (const float*)d_in[13];
    const float* kbp   = (const float*)d_in[14];
    float* out = (float*)d_out;

    const size_t NEEDED = 53477376;
    if (ws_size < NEEDED) {
        hipMemsetAsync(d_out, 0, (size_t)out_size * sizeof(float), stream);
        return;   // signature: absmax ~0.707 => workspace too small
    }

    char* ws = (char*)d_ws;
    float* xf      = (float*)(ws);                 // 8 MB fp32 residual stream
    u16*   xnh     = (u16*)  (ws + 8388608);       // 4 MB  ln out h
    u16*   xnl     = (u16*)  (ws + 12582912);      // 4 MB  ln out l
    u16*   aoh     = xnh;                          // attn out aliases xn (xn dead after QKV gemm)
    u16*   aol     = xnl;
    u16*   qkvh    = (u16*)  (ws + 16777216);      // 12 MB (8192x768 u16) -> ends 29360128
    u16*   qkvl    = (u16*)  (ws + 29360128);      // 12 MB -> ends 41943040
    u16*   hbh     = (u16*)  (ws + 16777216);      // 16 MB (qkv dead during FFN)
    u16*   hbl     = (u16*)  (ws + 33554432);      // 16 MB -> ends 50331648
    float* centers = (float*)(ws + 41943040);      // 64 KB -> 42008576
    float* csqb    = (float*)(ws + 42008576);      // 256 B -> 42008832
    float* counts16= (float*)(ws + 42008832);      // 4 KB  -> 42012928
    int*   labels  = (int*)  (ws + 42012928);      // 32 KB -> 42045696
    float* outc    = (float*)(ws + 42045696);      // 64 KB -> 42111232
    float* sums16  = (float*)(ws + 42111232);      // 1 MB  -> 43159808
    u16*   wr      = (u16*)  (ws + 50331648);
    u16 *wqkvh = wr,          *wqkvl = wr + 196608;   // 768x256 each
    u16 *woh = wr + 393216,   *wol = wr + 458752;
    u16 *w1h = wr + 524288,   *w1l = wr + 786432;
    u16 *w2h = wr + 1048576,  *w2l = wr + 1310720;

    hipMemcpyAsync(xf, x_in, (size_t)BN * DMODEL * sizeof(float), hipMemcpyDeviceToDevice, stream);

    for (int l = 0; l < 4; l++) {
        wconv_all<<<192, 256, 0, stream>>>(Wq + (size_t)l * 65536, Wkv + (size_t)l * 131072,
                                           Wo + (size_t)l * 65536, W1 + (size_t)l * 262144,
                                           W2 + (size_t)l * 262144,
                                           wqkvh, wqkvl, woh, wol, w1h, w1l, w2h, w2l);

        ln_wave<<<BN / 4, 256, 0, stream>>>(xf, ln1_g + l * 256, ln1_b + l * 256, xnh, xnl);
        gemm_t<128, 128><<<dim3(6, 64), 256, 0, stream>>>(xnh, xnl, wqkvh, wqkvl, nullptr, nullptr,
                                                          nullptr, qkvh, qkvl, BN, 768, 256, 0);
        attn12<<<dim3(64, 16), 256, 0, stream>>>(qkvh, qkvl, aoh, aol);
        gemm_t<64, 64><<<dim3(4, 128), 256, 0, stream>>>(aoh, aol, woh, wol, bo + l * 256, xf,
                                                         xf, nullptr, nullptr, BN, 256, 256, 0);
        ln_wave<<<BN / 4, 256, 0, stream>>>(xf, ln2_g + l * 256, ln2_b + l * 256, xnh, xnl);
        gemm_t<128, 128><<<dim3(8, 64), 256, 0, stream>>>(xnh, xnl, w1h, w1l, b1 + l * 1024, nullptr,
                                                          nullptr, hbh, hbl, BN, 1024, 256, 1);
        gemm_t<64, 64><<<dim3(4, 128), 256, 0, stream>>>(hbh, hbl, w2h, w2l, b2 + l * 256, xf,
                                                         xf, nullptr, nullptr, BN, 256, 1024, 0);
    }

    hipMemcpyAsync(centers, xf, NCLUST * DMODEL * sizeof(float), hipMemcpyDeviceToDevice, stream);
    csq_k<<<64, 64, 0, stream>>>(centers, csqb);
    for (int it = 0; it < 10; it++) {
        km_distmin<<<256, 256, 0, stream>>>(xf, centers, csqb, labels);
        km_segsum<<<dim3(16, NCLUST), 256, 0, stream>>>(labels, xf, sums16, counts16);
        km_update<<<64, 256, 0, stream>>>(centers, sums16, counts16, csqb);
    }
    km_distmin<<<256, 256, 0, stream>>>(xf, centers, csqb, labels);
    nproj<<<64, 256, 0, stream>>>(centers, kWp, kbp, outc);
    km_gather<<<BN, 256, 0, stream>>>(labels, outc, out);
}